// Round 1
// baseline (7419.567 us; speedup 1.0000x reference)
//
#include <hip/hip_runtime.h>
#include <hip/hip_bf16.h>
#include <math.h>

// RULPredictionModel: B=16 S=1024 D=384 H=8 DH=48 L=3 E=8 FF=768 TOP_K=2
#define TOKENS 16384
#define DMODEL 384
#define SEQ 1024
#define NHEAD 8
#define DHEAD 48
#define NEXP 8
#define FFDIM 768
#define NL 3

// ---------------- tiny kernels ----------------
__global__ void init_kernel(float* total_moe) { *total_moe = 0.f; }

__global__ void zero_cnt_kernel(int* counts, float* sum_probs) {
  int t = threadIdx.x;
  if (t < NEXP) { counts[t] = 0; sum_probs[t] = 0.f; }
}

__global__ void finalize_kernel(const float* total_moe, float* out) { out[16] = *total_moe; }

__global__ __launch_bounds__(256) void proj_kernel(const float* __restrict__ x,
    const float* __restrict__ pw, const float* __restrict__ pb, float* __restrict__ h) {
  int i = blockIdx.x * 256 + threadIdx.x;          // 0 .. 16384*384-1
  int t = i / DMODEL;
  int d = i - t * DMODEL;
  h[i] = x[t] * pw[d] + pb[d];
}

// one block (384 threads) per row
__global__ __launch_bounds__(384) void ln_kernel(const float* __restrict__ src,
    float* __restrict__ dst, const float* __restrict__ gs, const float* __restrict__ gb) {
  int row = blockIdx.x, tid = threadIdx.x;
  float v = src[(size_t)row * DMODEL + tid];
  float sum = v, sq = v * v;
#pragma unroll
  for (int off = 32; off; off >>= 1) { sum += __shfl_xor(sum, off); sq += __shfl_xor(sq, off); }
  __shared__ float rs[6], rq[6];
  __shared__ float smean, sinv;
  int wid = tid >> 6;
  if ((tid & 63) == 0) { rs[wid] = sum; rq[wid] = sq; }
  __syncthreads();
  if (tid == 0) {
    float S = 0.f, Q = 0.f;
    for (int w = 0; w < 6; w++) { S += rs[w]; Q += rq[w]; }
    float mean = S / (float)DMODEL;
    float var = Q / (float)DMODEL - mean * mean;
    smean = mean; sinv = rsqrtf(var + 1e-5f);
  }
  __syncthreads();
  dst[(size_t)row * DMODEL + tid] = (v - smean) * sinv * gs[tid] + gb[tid];
}

// ---------------- generic fp32 tiled GEMM: C = [res +] A@W + bias, 64x64x16 ----------------
template<bool RES, bool RELU>
__global__ __launch_bounds__(256) void gemm_kernel(const float* __restrict__ A,
    const float* __restrict__ W, const float* __restrict__ bias,
    const float* __restrict__ res, float* __restrict__ C, int M, int N, int K) {
  __shared__ float As[16][72];
  __shared__ float Bs[16][72];
  int tid = threadIdx.x;
  int tx = tid & 15, ty = tid >> 4;
  int m0 = blockIdx.y * 64, n0 = blockIdx.x * 64;
  int arow = tid >> 4, akk = tid & 15;
  int bcol = tid & 63, bk0 = tid >> 6;
  float acc[4][4] = {};
  for (int k0 = 0; k0 < K; k0 += 16) {
#pragma unroll
    for (int i = 0; i < 4; i++)
      As[akk][arow + 16 * i] = A[(size_t)(m0 + arow + 16 * i) * K + k0 + akk];
#pragma unroll
    for (int i = 0; i < 4; i++)
      Bs[bk0 + 4 * i][bcol] = W[(size_t)(k0 + bk0 + 4 * i) * N + n0 + bcol];
    __syncthreads();
#pragma unroll
    for (int kk = 0; kk < 16; kk++) {
      float a[4], b[4];
#pragma unroll
      for (int i = 0; i < 4; i++) a[i] = As[kk][ty * 4 + i];
#pragma unroll
      for (int j = 0; j < 4; j++) b[j] = Bs[kk][tx * 4 + j];
#pragma unroll
      for (int i = 0; i < 4; i++)
#pragma unroll
        for (int j = 0; j < 4; j++) acc[i][j] += a[i] * b[j];
    }
    __syncthreads();
  }
#pragma unroll
  for (int i = 0; i < 4; i++) {
    size_t m = (size_t)m0 + ty * 4 + i;
#pragma unroll
    for (int j = 0; j < 4; j++) {
      int n = n0 + tx * 4 + j;
      float v = acc[i][j] + bias[n];
      if constexpr (RES) v += res[m * N + n];
      if constexpr (RELU) v = fmaxf(v, 0.f);
      C[m * N + n] = v;
    }
  }
}

// ---------------- flash attention (fp32): block = (b, head, 64 q rows) ----------------
__global__ __launch_bounds__(256) void attn_kernel(const float* __restrict__ qkv,
                                                   float* __restrict__ ao) {
  __shared__ __align__(16) float Ks[64][52];
  __shared__ __align__(16) float Vs[64][52];
  __shared__ __align__(16) float Ss[64][68];   // also stages Q
  int q0 = blockIdx.x * 64;
  int hh = blockIdx.y;
  int b  = blockIdx.z;
  int tid = threadIdx.x;
  int r = tid >> 2, c = tid & 3;               // 4 threads per q-row (same wave)
  const float scale = 0.14433756729740643f;    // 1/sqrt(48)
  // stage Q tile through Ss, then hoist to registers
  for (int e = tid; e < 64 * 48; e += 256) {
    int rr = e / 48, d = e - rr * 48;
    Ss[rr][d] = qkv[((size_t)(b * SEQ + q0 + rr)) * 1152 + hh * 48 + d];
  }
  __syncthreads();
  float4 qreg[12];
#pragma unroll
  for (int i = 0; i < 12; i++) qreg[i] = *(const float4*)&Ss[r][4 * i];
  float m = -INFINITY, lsum = 0.f;
  float acc[12] = {};                          // output dims c*12 .. c*12+11
  for (int kt = 0; kt < 16; kt++) {
    __syncthreads();                            // prev-iter reads done (also covers qreg reads)
    for (int e = tid; e < 64 * 48; e += 256) {
      int rr = e / 48, d = e - rr * 48;
      size_t base = ((size_t)(b * SEQ + kt * 64 + rr)) * 1152 + hh * 48 + d;
      Ks[rr][d] = qkv[base + 384];
      Vs[rr][d] = qkv[base + 768];
    }
    __syncthreads();
    float sc[16];
    float tmax = -INFINITY;
#pragma unroll
    for (int j = 0; j < 16; j++) {
      int kl = c * 16 + j;
      float s = 0.f;
#pragma unroll
      for (int i = 0; i < 12; i++) {
        float4 kv = *(const float4*)&Ks[kl][4 * i];
        s += qreg[i].x * kv.x + qreg[i].y * kv.y + qreg[i].z * kv.z + qreg[i].w * kv.w;
      }
      s *= scale;
      sc[j] = s;
      tmax = fmaxf(tmax, s);
    }
    tmax = fmaxf(tmax, __shfl_xor(tmax, 1));
    tmax = fmaxf(tmax, __shfl_xor(tmax, 2));
    float mnew = fmaxf(m, tmax);
    float alpha = expf(m - mnew);
    float ps = 0.f;
#pragma unroll
    for (int j = 0; j < 16; j++) {
      float p = expf(sc[j] - mnew);
      Ss[r][c * 16 + j] = p;                   // same-wave lanes write/read row r
      ps += p;
    }
    ps += __shfl_xor(ps, 1);
    ps += __shfl_xor(ps, 2);
    lsum = lsum * alpha + ps;
    m = mnew;
#pragma unroll
    for (int i = 0; i < 12; i++) acc[i] *= alpha;
#pragma unroll
    for (int k4 = 0; k4 < 16; k4++) {
      float4 pp = *(const float4*)&Ss[r][4 * k4];
#pragma unroll
      for (int q = 0; q < 3; q++) {
        float4 v0 = *(const float4*)&Vs[4 * k4 + 0][c * 12 + 4 * q];
        float4 v1 = *(const float4*)&Vs[4 * k4 + 1][c * 12 + 4 * q];
        float4 v2 = *(const float4*)&Vs[4 * k4 + 2][c * 12 + 4 * q];
        float4 v3 = *(const float4*)&Vs[4 * k4 + 3][c * 12 + 4 * q];
        acc[4 * q + 0] += pp.x * v0.x + pp.y * v1.x + pp.z * v2.x + pp.w * v3.x;
        acc[4 * q + 1] += pp.x * v0.y + pp.y * v1.y + pp.z * v2.y + pp.w * v3.y;
        acc[4 * q + 2] += pp.x * v0.z + pp.y * v1.z + pp.z * v2.z + pp.w * v3.z;
        acc[4 * q + 3] += pp.x * v0.w + pp.y * v1.w + pp.z * v2.w + pp.w * v3.w;
      }
    }
  }
  float invl = 1.f / lsum;
  float* aorow = ao + ((size_t)(b * SEQ + q0 + r)) * DMODEL + hh * 48 + c * 12;
#pragma unroll
  for (int i = 0; i < 12; i++) aorow[i] = acc[i] * invl;
}

// ---------------- gating: one wave per token ----------------
__global__ __launch_bounds__(256) void gate_kernel(const float* __restrict__ xn,
    const float* __restrict__ gw, int* __restrict__ counts, float* __restrict__ sum_probs,
    int* __restrict__ tok_list, float* __restrict__ gate_list) {
  __shared__ float simp[NEXP];
  int tid = threadIdx.x;
  if (tid < NEXP) simp[tid] = 0.f;
  __syncthreads();
  int w = tid >> 6, lane = tid & 63;
  int t = blockIdx.x * 4 + w;
  float p[NEXP];
#pragma unroll
  for (int e = 0; e < NEXP; e++) p[e] = 0.f;
#pragma unroll
  for (int j = 0; j < 6; j++) {
    int d = lane + 64 * j;
    float xv = xn[(size_t)t * DMODEL + d];
#pragma unroll
    for (int e = 0; e < NEXP; e++) p[e] += xv * gw[d * NEXP + e];
  }
#pragma unroll
  for (int off = 32; off; off >>= 1)
#pragma unroll
    for (int e = 0; e < NEXP; e++) p[e] += __shfl_xor(p[e], off);
  if (lane == 0) {
    float mx = p[0];
#pragma unroll
    for (int e = 1; e < NEXP; e++) mx = fmaxf(mx, p[e]);
    float s = 0.f;
#pragma unroll
    for (int e = 0; e < NEXP; e++) { p[e] = expf(p[e] - mx); s += p[e]; }
    float inv = 1.f / s;
#pragma unroll
    for (int e = 0; e < NEXP; e++) p[e] *= inv;
    // top-2, ties -> lower index (match lax.top_k)
    int i0 = 0; float v0 = p[0];
#pragma unroll
    for (int e = 1; e < NEXP; e++) if (p[e] > v0) { v0 = p[e]; i0 = e; }
    int i1 = -1; float v1 = -INFINITY;
#pragma unroll
    for (int e = 0; e < NEXP; e++) if (e != i0 && p[e] > v1) { v1 = p[e]; i1 = e; }
    float gsum = v0 + v1;
    int s0 = atomicAdd(&counts[i0], 1);
    tok_list[i0 * TOKENS + s0] = t;
    gate_list[i0 * TOKENS + s0] = v0 / gsum;
    int s1 = atomicAdd(&counts[i1], 1);
    tok_list[i1 * TOKENS + s1] = t;
    gate_list[i1 * TOKENS + s1] = v1 / gsum;
#pragma unroll
    for (int e = 0; e < NEXP; e++) atomicAdd(&simp[e], p[e]);
  }
  __syncthreads();
  if (tid < NEXP) atomicAdd(&sum_probs[tid], simp[tid]);
}

// prefix offsets (64-padded) + aux loss contribution
__global__ void aux_kernel(const int* __restrict__ counts, int* __restrict__ offs,
                           const float* __restrict__ sum_probs, float* __restrict__ total_moe) {
  int off = 0;
  float tm = 0.f;
  for (int e = 0; e < NEXP; e++) {
    offs[e] = off;
    off += ((counts[e] + 63) >> 6) << 6;
    tm += sum_probs[e] * (float)counts[e];
  }
  offs[NEXP] = off;
  *total_moe += (float)NEXP * tm / ((float)TOKENS * (float)TOKENS);
}

// ---------------- MoE grouped GEMMs ----------------
__global__ __launch_bounds__(256) void moe1_kernel(const float* __restrict__ X,
    const float* __restrict__ W1b, const float* __restrict__ b1b, float* __restrict__ a1,
    const int* __restrict__ counts, const int* __restrict__ offs,
    const int* __restrict__ tok_list, int l) {
  int e = blockIdx.z;
  int cnt = counts[e];
  int m0 = blockIdx.y * 64;
  if (m0 >= cnt) return;
  const float* W  = W1b + (size_t)(l * NEXP + e) * DMODEL * FFDIM;
  const float* b1 = b1b + (size_t)(l * NEXP + e) * FFDIM;
  const int* tl = tok_list + e * TOKENS + m0;
  int base = offs[e] + m0;
  __shared__ float As[16][72];
  __shared__ float Bs[16][72];
  int tid = threadIdx.x;
  int tx = tid & 15, ty = tid >> 4;
  int n0 = blockIdx.x * 64;
  int arow = tid >> 4, akk = tid & 15;
  int bcol = tid & 63, bk0 = tid >> 6;
  int tok[4];
#pragma unroll
  for (int i = 0; i < 4; i++) {
    int r = arow + 16 * i;
    tok[i] = (m0 + r < cnt) ? tl[r] : -1;
  }
  float acc[4][4] = {};
  for (int k0 = 0; k0 < DMODEL; k0 += 16) {
#pragma unroll
    for (int i = 0; i < 4; i++)
      As[akk][arow + 16 * i] = (tok[i] >= 0) ? X[(size_t)tok[i] * DMODEL + k0 + akk] : 0.f;
#pragma unroll
    for (int i = 0; i < 4; i++)
      Bs[bk0 + 4 * i][bcol] = W[(size_t)(k0 + bk0 + 4 * i) * FFDIM + n0 + bcol];
    __syncthreads();
#pragma unroll
    for (int kk = 0; kk < 16; kk++) {
      float a[4], b[4];
#pragma unroll
      for (int i = 0; i < 4; i++) a[i] = As[kk][ty * 4 + i];
#pragma unroll
      for (int j = 0; j < 4; j++) b[j] = Bs[kk][tx * 4 + j];
#pragma unroll
      for (int i = 0; i < 4; i++)
#pragma unroll
        for (int j = 0; j < 4; j++) acc[i][j] += a[i] * b[j];
    }
    __syncthreads();
  }
#pragma unroll
  for (int i = 0; i < 4; i++) {
    int r = ty * 4 + i;
    if (m0 + r < cnt) {
#pragma unroll
      for (int j = 0; j < 4; j++) {
        int n = n0 + tx * 4 + j;
        a1[(size_t)(base + r) * FFDIM + n] = fmaxf(acc[i][j] + b1[n], 0.f);
      }
    }
  }
}

__global__ __launch_bounds__(256) void moe2_kernel(const float* __restrict__ a1,
    const float* __restrict__ W2b, const float* __restrict__ b2b, float* __restrict__ h,
    const int* __restrict__ counts, const int* __restrict__ offs,
    const int* __restrict__ tok_list, const float* __restrict__ gate_list, int l) {
  int e = blockIdx.z;
  int cnt = counts[e];
  int m0 = blockIdx.y * 64;
  if (m0 >= cnt) return;
  const float* W  = W2b + (size_t)(l * NEXP + e) * FFDIM * DMODEL;
  const float* b2 = b2b + (size_t)(l * NEXP + e) * DMODEL;
  int base = offs[e] + m0;
  __shared__ float As[16][72];
  __shared__ float Bs[16][72];
  int tid = threadIdx.x;
  int tx = tid & 15, ty = tid >> 4;
  int n0 = blockIdx.x * 64;
  int arow = tid >> 4, akk = tid & 15;
  int bcol = tid & 63, bk0 = tid >> 6;
  float acc[4][4] = {};
  for (int k0 = 0; k0 < FFDIM; k0 += 16) {
#pragma unroll
    for (int i = 0; i < 4; i++) {
      int r = arow + 16 * i;
      As[akk][r] = (m0 + r < cnt) ? a1[(size_t)(base + r) * FFDIM + k0 + akk] : 0.f;
    }
#pragma unroll
    for (int i = 0; i < 4; i++)
      Bs[bk0 + 4 * i][bcol] = W[(size_t)(k0 + bk0 + 4 * i) * DMODEL + n0 + bcol];
    __syncthreads();
#pragma unroll
    for (int kk = 0; kk < 16; kk++) {
      float a[4], b[4];
#pragma unroll
      for (int i = 0; i < 4; i++) a[i] = As[kk][ty * 4 + i];
#pragma unroll
      for (int j = 0; j < 4; j++) b[j] = Bs[kk][tx * 4 + j];
#pragma unroll
      for (int i = 0; i < 4; i++)
#pragma unroll
        for (int j = 0; j < 4; j++) acc[i][j] += a[i] * b[j];
    }
    __syncthreads();
  }
#pragma unroll
  for (int i = 0; i < 4; i++) {
    int r = ty * 4 + i;
    if (m0 + r < cnt) {
      int t = tok_list[e * TOKENS + m0 + r];
      float g = gate_list[e * TOKENS + m0 + r];
#pragma unroll
      for (int j = 0; j < 4; j++) {
        int n = n0 + tx * 4 + j;
        atomicAdd(&h[(size_t)t * DMODEL + n], g * (acc[i][j] + b2[n]));
      }
    }
  }
}

// ---------------- attention-pool head: one block per batch ----------------
__global__ __launch_bounds__(256) void head_kernel(const float* __restrict__ h,
    const float* __restrict__ att_w, const float* __restrict__ att_b,
    const float* __restrict__ head_w, const float* __restrict__ head_b,
    float* __restrict__ out) {
  int b = blockIdx.x, tid = threadIdx.x;
  __shared__ float wl[SEQ];
  __shared__ float red[4];
  __shared__ float pooled[DMODEL];
  float ab = att_b[0];
  float lv[4];
  float lmax = -INFINITY;
#pragma unroll
  for (int i = 0; i < 4; i++) {
    int s = tid + 256 * i;
    const float* hr = h + (size_t)(b * SEQ + s) * DMODEL;
    float acc = 0.f;
    for (int d = 0; d < DMODEL; d++) acc += hr[d] * att_w[d];
    lv[i] = acc + ab;
    lmax = fmaxf(lmax, lv[i]);
  }
#pragma unroll
  for (int off = 32; off; off >>= 1) lmax = fmaxf(lmax, __shfl_xor(lmax, off));
  int wid = tid >> 6;
  if ((tid & 63) == 0) red[wid] = lmax;
  __syncthreads();
  lmax = fmaxf(fmaxf(red[0], red[1]), fmaxf(red[2], red[3]));
  __syncthreads();
  float ls = 0.f;
#pragma unroll
  for (int i = 0; i < 4; i++) {
    float p = expf(lv[i] - lmax);
    wl[tid + 256 * i] = p;
    ls += p;
  }
#pragma unroll
  for (int off = 32; off; off >>= 1) ls += __shfl_xor(ls, off);
  if ((tid & 63) == 0) red[wid] = ls;
  __syncthreads();
  float invs = 1.f / (red[0] + red[1] + red[2] + red[3]);
  for (int d = tid; d < DMODEL; d += 256) {
    float acc = 0.f;
    for (int s = 0; s < SEQ; s++) acc += wl[s] * h[(size_t)(b * SEQ + s) * DMODEL + d];
    pooled[d] = acc * invs;
  }
  __syncthreads();
  float part = 0.f;
  for (int d = tid; d < DMODEL; d += 256) part += pooled[d] * head_w[d];
#pragma unroll
  for (int off = 32; off; off >>= 1) part += __shfl_xor(part, off);
  __syncthreads();
  if ((tid & 63) == 0) red[wid] = part;
  __syncthreads();
  if (tid == 0) out[b] = red[0] + red[1] + red[2] + red[3] + head_b[0];
}

// ---------------- launch ----------------
extern "C" void kernel_launch(void* const* d_in, const int* in_sizes, int n_in,
                              void* d_out, int out_size, void* d_ws, size_t ws_size,
                              hipStream_t stream) {
  (void)in_sizes; (void)n_in; (void)out_size; (void)ws_size;
  const float* x      = (const float*)d_in[0];
  const float* proj_w = (const float*)d_in[1];
  const float* proj_b = (const float*)d_in[2];
  const float* qkv_w  = (const float*)d_in[3];
  const float* qkv_b  = (const float*)d_in[4];
  const float* out_w  = (const float*)d_in[5];
  const float* out_b  = (const float*)d_in[6];
  const float* n1_s   = (const float*)d_in[7];
  const float* n1_b   = (const float*)d_in[8];
  const float* n2_s   = (const float*)d_in[9];
  const float* n2_b   = (const float*)d_in[10];
  const float* gate_w = (const float*)d_in[11];
  const float* e_w1   = (const float*)d_in[12];
  const float* e_b1   = (const float*)d_in[13];
  const float* e_w2   = (const float*)d_in[14];
  const float* e_b2   = (const float*)d_in[15];
  const float* att_w  = (const float*)d_in[16];
  const float* att_b  = (const float*)d_in[17];
  const float* head_w = (const float*)d_in[18];
  const float* head_b = (const float*)d_in[19];
  float* out = (float*)d_out;

  // workspace layout (bytes):
  // h: 0 .. 25165824 | xn/ao: 25165824 .. 50331648 | union(qkv 75.5MB | a1 102.2MB)
  char* wsb = (char*)d_ws;
  float* h   = (float*)(wsb);
  float* xn  = (float*)(wsb + 25165824);
  float* uni = (float*)(wsb + 50331648);       // qkv during attention, a1 during MoE
  char* sm   = wsb + 152567808;
  int*   counts    = (int*)(sm);
  int*   offs      = (int*)(sm + 64);
  float* sum_probs = (float*)(sm + 128);
  float* total_moe = (float*)(sm + 192);
  int*   tok_list  = (int*)(sm + 256);
  float* gate_list = (float*)(sm + 256 + 524288);

  init_kernel<<<1, 1, 0, stream>>>(total_moe);
  proj_kernel<<<TOKENS * DMODEL / 256, 256, 0, stream>>>(x, proj_w, proj_b, h);

  for (int l = 0; l < NL; l++) {
    ln_kernel<<<TOKENS, 384, 0, stream>>>(h, xn, n1_s + l * DMODEL, n1_b + l * DMODEL);
    gemm_kernel<false, false><<<dim3(18, 256), 256, 0, stream>>>(
        xn, qkv_w + (size_t)l * DMODEL * 1152, qkv_b + l * 1152, nullptr, uni,
        TOKENS, 1152, DMODEL);
    attn_kernel<<<dim3(16, NHEAD, 16), 256, 0, stream>>>(uni, xn);  // ao aliases xn
    gemm_kernel<true, false><<<dim3(6, 256), 256, 0, stream>>>(
        xn, out_w + (size_t)l * DMODEL * DMODEL, out_b + l * DMODEL, h, h,
        TOKENS, DMODEL, DMODEL);
    ln_kernel<<<TOKENS, 384, 0, stream>>>(h, xn, n2_s + l * DMODEL, n2_b + l * DMODEL);
    zero_cnt_kernel<<<1, 64, 0, stream>>>(counts, sum_probs);
    gate_kernel<<<TOKENS / 4, 256, 0, stream>>>(xn, gate_w + (size_t)l * DMODEL * NEXP,
                                                counts, sum_probs, tok_list, gate_list);
    aux_kernel<<<1, 1, 0, stream>>>(counts, offs, sum_probs, total_moe);
    moe1_kernel<<<dim3(12, 256, 8), 256, 0, stream>>>(xn, e_w1, e_b1, uni,
                                                      counts, offs, tok_list, l);
    moe2_kernel<<<dim3(6, 256, 8), 256, 0, stream>>>(uni, e_w2, e_b2, h,
                                                     counts, offs, tok_list, gate_list, l);
  }

  head_kernel<<<16, 256, 0, stream>>>(h, att_w, att_b, head_w, head_b, out);
  finalize_kernel<<<1, 1, 0, stream>>>(total_moe, out);
}

// Round 2
// 4530.999 us; speedup vs baseline: 1.6375x; 1.6375x over previous
//
#include <hip/hip_runtime.h>
#include <hip/hip_bf16.h>
#include <math.h>

// RULPredictionModel: B=16 S=1024 D=384 H=8 DH=48 L=3 E=8 FF=768 TOP_K=2
#define TOKENS 16384
#define DMODEL 384
#define SEQ 1024
#define NHEAD 8
#define DHEAD 48
#define NEXP 8
#define FFDIM 768
#define NL 3

typedef __bf16 bf16x8 __attribute__((ext_vector_type(8)));
typedef __bf16 bf16x4 __attribute__((ext_vector_type(4)));
typedef float f32x4 __attribute__((ext_vector_type(4)));

// ---------------- tiny kernels ----------------
__global__ void init_kernel(float* total_moe) { *total_moe = 0.f; }

__global__ void zero_cnt_kernel(int* counts, float* sum_probs) {
  int t = threadIdx.x;
  if (t < NEXP) { counts[t] = 0; sum_probs[t] = 0.f; }
}

__global__ void finalize_kernel(const float* total_moe, float* out) { out[16] = *total_moe; }

__global__ __launch_bounds__(256) void proj_kernel(const float* __restrict__ x,
    const float* __restrict__ pw, const float* __restrict__ pb, float* __restrict__ h) {
  int i = blockIdx.x * 256 + threadIdx.x;          // 0 .. 16384*384-1
  int t = i / DMODEL;
  int d = i - t * DMODEL;
  h[i] = x[t] * pw[d] + pb[d];
}

// one block (384 threads) per row
__global__ __launch_bounds__(384) void ln_kernel(const float* __restrict__ src,
    float* __restrict__ dst, const float* __restrict__ gs, const float* __restrict__ gb) {
  int row = blockIdx.x, tid = threadIdx.x;
  float v = src[(size_t)row * DMODEL + tid];
  float sum = v, sq = v * v;
#pragma unroll
  for (int off = 32; off; off >>= 1) { sum += __shfl_xor(sum, off); sq += __shfl_xor(sq, off); }
  __shared__ float rs[6], rq[6];
  __shared__ float smean, sinv;
  int wid = tid >> 6;
  if ((tid & 63) == 0) { rs[wid] = sum; rq[wid] = sq; }
  __syncthreads();
  if (tid == 0) {
    float S = 0.f, Q = 0.f;
    for (int w = 0; w < 6; w++) { S += rs[w]; Q += rq[w]; }
    float mean = S / (float)DMODEL;
    float var = Q / (float)DMODEL - mean * mean;
    smean = mean; sinv = rsqrtf(var + 1e-5f);
  }
  __syncthreads();
  dst[(size_t)row * DMODEL + tid] = (v - smean) * sinv * gs[tid] + gb[tid];
}

// ---------------- generic fp32 tiled GEMM: C = [res +] A@W + bias, 64x64x16 ----------------
template<bool RES, bool RELU>
__global__ __launch_bounds__(256) void gemm_kernel(const float* __restrict__ A,
    const float* __restrict__ W, const float* __restrict__ bias,
    const float* __restrict__ res, float* __restrict__ C, int M, int N, int K) {
  __shared__ float As[16][72];
  __shared__ float Bs[16][72];
  int tid = threadIdx.x;
  int tx = tid & 15, ty = tid >> 4;
  int m0 = blockIdx.y * 64, n0 = blockIdx.x * 64;
  int arow = tid >> 4, akk = tid & 15;
  int bcol = tid & 63, bk0 = tid >> 6;
  float acc[4][4] = {};
  for (int k0 = 0; k0 < K; k0 += 16) {
#pragma unroll
    for (int i = 0; i < 4; i++)
      As[akk][arow + 16 * i] = A[(size_t)(m0 + arow + 16 * i) * K + k0 + akk];
#pragma unroll
    for (int i = 0; i < 4; i++)
      Bs[bk0 + 4 * i][bcol] = W[(size_t)(k0 + bk0 + 4 * i) * N + n0 + bcol];
    __syncthreads();
#pragma unroll
    for (int kk = 0; kk < 16; kk++) {
      float a[4], b[4];
#pragma unroll
      for (int i = 0; i < 4; i++) a[i] = As[kk][ty * 4 + i];
#pragma unroll
      for (int j = 0; j < 4; j++) b[j] = Bs[kk][tx * 4 + j];
#pragma unroll
      for (int i = 0; i < 4; i++)
#pragma unroll
        for (int j = 0; j < 4; j++) acc[i][j] += a[i] * b[j];
    }
    __syncthreads();
  }
#pragma unroll
  for (int i = 0; i < 4; i++) {
    size_t m = (size_t)m0 + ty * 4 + i;
#pragma unroll
    for (int j = 0; j < 4; j++) {
      int n = n0 + tx * 4 + j;
      float v = acc[i][j] + bias[n];
      if constexpr (RES) v += res[m * N + n];
      if constexpr (RELU) v = fmaxf(v, 0.f);
      C[m * N + n] = v;
    }
  }
}

// ---------------- bf16 MFMA flash attention ----------------
// block = 4 waves = 64 q rows of one (b,h); wave wq owns q rows wq*16..wq*16+15.
// LDS strides 88 bf16 = 176B = 11*16B: 16B-aligned b128 reads, even bank slots.
__global__ __launch_bounds__(256) void attn_kernel(const float* __restrict__ qkv,
                                                   float* __restrict__ ao) {
  __shared__ __align__(16) __bf16 Qs[64][88];
  __shared__ __align__(16) __bf16 Ks[64][88];
  __shared__ __align__(16) __bf16 Vt[48][88];   // V transposed: [dh][kv]
  __shared__ __align__(16) __bf16 Ps[64][88];   // P probs: [q][kv]
  int hh = blockIdx.x;
  int b  = blockIdx.y;
  int q0 = blockIdx.z * 64;
  int tid = threadIdx.x;
  int wq = tid >> 6;
  int lane = tid & 63;
  int c = lane & 15, g = lane >> 4;
  const float scale = 0.14433756729740643f;     // 1/sqrt(48)

  // zero dh-pad cols 48..63 of Qs/Ks (K-dim padded 48 -> 64)
  for (int e = tid; e < 64 * 16; e += 256) {
    int r = e >> 4, col = 48 + (e & 15);
    Qs[r][col] = (__bf16)0.f;
    Ks[r][col] = (__bf16)0.f;
  }
  // stage Q tile (64 rows x 48 dh), fp32 -> bf16
  {
    int r = tid >> 2, p = tid & 3;
    const float* src = qkv + ((size_t)(b * SEQ + q0 + r)) * 1152 + hh * 48 + p * 12;
#pragma unroll
    for (int i = 0; i < 3; i++) {
      float4 f = *(const float4*)(src + 4 * i);
      bf16x4 o = { (__bf16)f.x, (__bf16)f.y, (__bf16)f.z, (__bf16)f.w };
      *(bf16x4*)&Qs[r][p * 12 + 4 * i] = o;
    }
  }
  __syncthreads();
  bf16x8 qa0 = *(const bf16x8*)&Qs[wq * 16 + c][g * 8];
  bf16x8 qa1 = *(const bf16x8*)&Qs[wq * 16 + c][32 + g * 8];

  f32x4 acc[3];
  float m[4], l[4];
#pragma unroll
  for (int t = 0; t < 3; t++) { acc[t][0] = 0.f; acc[t][1] = 0.f; acc[t][2] = 0.f; acc[t][3] = 0.f; }
#pragma unroll
  for (int r = 0; r < 4; r++) { m[r] = -INFINITY; l[r] = 0.f; }

  for (int kt = 0; kt < 16; kt++) {
    __syncthreads();                            // prior tile fully consumed
    {   // stage K (natural) and V (transposed), fp32 -> bf16
      int r = tid >> 2, p = tid & 3;
      const float* srcK = qkv + ((size_t)(b * SEQ + kt * 64 + r)) * 1152 + hh * 48 + 384 + p * 12;
#pragma unroll
      for (int i = 0; i < 3; i++) {
        float4 f = *(const float4*)(srcK + 4 * i);
        bf16x4 o = { (__bf16)f.x, (__bf16)f.y, (__bf16)f.z, (__bf16)f.w };
        *(bf16x4*)&Ks[r][p * 12 + 4 * i] = o;
      }
      const float* srcV = srcK + 384;
#pragma unroll
      for (int i = 0; i < 3; i++) {
        float4 f = *(const float4*)(srcV + 4 * i);
        int dh = p * 12 + 4 * i;
        Vt[dh + 0][r] = (__bf16)f.x;
        Vt[dh + 1][r] = (__bf16)f.y;
        Vt[dh + 2][r] = (__bf16)f.z;
        Vt[dh + 3][r] = (__bf16)f.w;
      }
    }
    __syncthreads();

    // S = Q K^T : 4 kv-subtiles of 16, K-dim 64 (2 mfma each)
    f32x4 s[4];
#pragma unroll
    for (int f = 0; f < 4; f++) {
      s[f][0] = 0.f; s[f][1] = 0.f; s[f][2] = 0.f; s[f][3] = 0.f;
      bf16x8 kb0 = *(const bf16x8*)&Ks[f * 16 + c][g * 8];
      bf16x8 kb1 = *(const bf16x8*)&Ks[f * 16 + c][32 + g * 8];
      s[f] = __builtin_amdgcn_mfma_f32_16x16x32_bf16(qa0, kb0, s[f], 0, 0, 0);
      s[f] = __builtin_amdgcn_mfma_f32_16x16x32_bf16(qa1, kb1, s[f], 0, 0, 0);
    }
    // online softmax: lane holds q rows 4g+r (r=reg), kv col 16f+c
    float sv[4][4];
#pragma unroll
    for (int f = 0; f < 4; f++)
#pragma unroll
      for (int r = 0; r < 4; r++) sv[f][r] = s[f][r] * scale;
    float alpha[4];
#pragma unroll
    for (int r = 0; r < 4; r++) {
      float t0 = fmaxf(fmaxf(sv[0][r], sv[1][r]), fmaxf(sv[2][r], sv[3][r]));
      t0 = fmaxf(t0, __shfl_xor(t0, 1));
      t0 = fmaxf(t0, __shfl_xor(t0, 2));
      t0 = fmaxf(t0, __shfl_xor(t0, 4));
      t0 = fmaxf(t0, __shfl_xor(t0, 8));
      float mnew = fmaxf(m[r], t0);
      alpha[r] = __expf(m[r] - mnew);
      m[r] = mnew;
    }
    float p[4][4], ps[4];
#pragma unroll
    for (int r = 0; r < 4; r++) ps[r] = 0.f;
#pragma unroll
    for (int f = 0; f < 4; f++)
#pragma unroll
      for (int r = 0; r < 4; r++) { p[f][r] = __expf(sv[f][r] - m[r]); ps[r] += p[f][r]; }
#pragma unroll
    for (int r = 0; r < 4; r++) {
      float t0 = ps[r];
      t0 += __shfl_xor(t0, 1);
      t0 += __shfl_xor(t0, 2);
      t0 += __shfl_xor(t0, 4);
      t0 += __shfl_xor(t0, 8);
      l[r] = l[r] * alpha[r] + t0;
    }
#pragma unroll
    for (int t = 0; t < 3; t++)
#pragma unroll
      for (int r = 0; r < 4; r++) acc[t][r] *= alpha[r];
    // P -> LDS (bf16) to re-layout for PV A-operand (within-wave, no barrier)
#pragma unroll
    for (int f = 0; f < 4; f++)
#pragma unroll
      for (int r = 0; r < 4; r++)
        Ps[wq * 16 + 4 * g + r][f * 16 + c] = (__bf16)p[f][r];
    bf16x8 pa0 = *(const bf16x8*)&Ps[wq * 16 + c][g * 8];
    bf16x8 pa1 = *(const bf16x8*)&Ps[wq * 16 + c][32 + g * 8];
    // O += P V : 3 dh-subtiles of 16, K-dim = kv 64 (2 mfma each)
#pragma unroll
    for (int t = 0; t < 3; t++) {
      bf16x8 vb0 = *(const bf16x8*)&Vt[t * 16 + c][g * 8];
      bf16x8 vb1 = *(const bf16x8*)&Vt[t * 16 + c][32 + g * 8];
      acc[t] = __builtin_amdgcn_mfma_f32_16x16x32_bf16(pa0, vb0, acc[t], 0, 0, 0);
      acc[t] = __builtin_amdgcn_mfma_f32_16x16x32_bf16(pa1, vb1, acc[t], 0, 0, 0);
    }
  }
  float invl[4];
#pragma unroll
  for (int r = 0; r < 4; r++) invl[r] = 1.f / l[r];
#pragma unroll
  for (int t = 0; t < 3; t++)
#pragma unroll
    for (int r = 0; r < 4; r++)
      ao[((size_t)(b * SEQ + q0 + wq * 16 + 4 * g + r)) * DMODEL + hh * 48 + t * 16 + c] =
          acc[t][r] * invl[r];
}

// ---------------- gating: one wave per token ----------------
__global__ __launch_bounds__(256) void gate_kernel(const float* __restrict__ xn,
    const float* __restrict__ gw, int* __restrict__ counts, float* __restrict__ sum_probs,
    int* __restrict__ tok_list, float* __restrict__ gate_list) {
  __shared__ float simp[NEXP];
  int tid = threadIdx.x;
  if (tid < NEXP) simp[tid] = 0.f;
  __syncthreads();
  int w = tid >> 6, lane = tid & 63;
  int t = blockIdx.x * 4 + w;
  float p[NEXP];
#pragma unroll
  for (int e = 0; e < NEXP; e++) p[e] = 0.f;
#pragma unroll
  for (int j = 0; j < 6; j++) {
    int d = lane + 64 * j;
    float xv = xn[(size_t)t * DMODEL + d];
#pragma unroll
    for (int e = 0; e < NEXP; e++) p[e] += xv * gw[d * NEXP + e];
  }
#pragma unroll
  for (int off = 32; off; off >>= 1)
#pragma unroll
    for (int e = 0; e < NEXP; e++) p[e] += __shfl_xor(p[e], off);
  if (lane == 0) {
    float mx = p[0];
#pragma unroll
    for (int e = 1; e < NEXP; e++) mx = fmaxf(mx, p[e]);
    float s = 0.f;
#pragma unroll
    for (int e = 0; e < NEXP; e++) { p[e] = expf(p[e] - mx); s += p[e]; }
    float inv = 1.f / s;
#pragma unroll
    for (int e = 0; e < NEXP; e++) p[e] *= inv;
    // top-2, ties -> lower index (match lax.top_k)
    int i0 = 0; float v0 = p[0];
#pragma unroll
    for (int e = 1; e < NEXP; e++) if (p[e] > v0) { v0 = p[e]; i0 = e; }
    int i1 = -1; float v1 = -INFINITY;
#pragma unroll
    for (int e = 0; e < NEXP; e++) if (e != i0 && p[e] > v1) { v1 = p[e]; i1 = e; }
    float gsum = v0 + v1;
    int s0 = atomicAdd(&counts[i0], 1);
    tok_list[i0 * TOKENS + s0] = t;
    gate_list[i0 * TOKENS + s0] = v0 / gsum;
    int s1 = atomicAdd(&counts[i1], 1);
    tok_list[i1 * TOKENS + s1] = t;
    gate_list[i1 * TOKENS + s1] = v1 / gsum;
#pragma unroll
    for (int e = 0; e < NEXP; e++) atomicAdd(&simp[e], p[e]);
  }
  __syncthreads();
  if (tid < NEXP) atomicAdd(&sum_probs[tid], simp[tid]);
}

// prefix offsets (64-padded) + aux loss contribution
__global__ void aux_kernel(const int* __restrict__ counts, int* __restrict__ offs,
                           const float* __restrict__ sum_probs, float* __restrict__ total_moe) {
  int off = 0;
  float tm = 0.f;
  for (int e = 0; e < NEXP; e++) {
    offs[e] = off;
    off += ((counts[e] + 63) >> 6) << 6;
    tm += sum_probs[e] * (float)counts[e];
  }
  offs[NEXP] = off;
  *total_moe += (float)NEXP * tm / ((float)TOKENS * (float)TOKENS);
}

// ---------------- MoE grouped GEMMs ----------------
__global__ __launch_bounds__(256) void moe1_kernel(const float* __restrict__ X,
    const float* __restrict__ W1b, const float* __restrict__ b1b, float* __restrict__ a1,
    const int* __restrict__ counts, const int* __restrict__ offs,
    const int* __restrict__ tok_list, int l) {
  int e = blockIdx.z;
  int cnt = counts[e];
  int m0 = blockIdx.y * 64;
  if (m0 >= cnt) return;
  const float* W  = W1b + (size_t)(l * NEXP + e) * DMODEL * FFDIM;
  const float* b1 = b1b + (size_t)(l * NEXP + e) * FFDIM;
  const int* tl = tok_list + e * TOKENS + m0;
  int base = offs[e] + m0;
  __shared__ float As[16][72];
  __shared__ float Bs[16][72];
  int tid = threadIdx.x;
  int tx = tid & 15, ty = tid >> 4;
  int n0 = blockIdx.x * 64;
  int arow = tid >> 4, akk = tid & 15;
  int bcol = tid & 63, bk0 = tid >> 6;
  int tok[4];
#pragma unroll
  for (int i = 0; i < 4; i++) {
    int r = arow + 16 * i;
    tok[i] = (m0 + r < cnt) ? tl[r] : -1;
  }
  float acc[4][4] = {};
  for (int k0 = 0; k0 < DMODEL; k0 += 16) {
#pragma unroll
    for (int i = 0; i < 4; i++)
      As[akk][arow + 16 * i] = (tok[i] >= 0) ? X[(size_t)tok[i] * DMODEL + k0 + akk] : 0.f;
#pragma unroll
    for (int i = 0; i < 4; i++)
      Bs[bk0 + 4 * i][bcol] = W[(size_t)(k0 + bk0 + 4 * i) * FFDIM + n0 + bcol];
    __syncthreads();
#pragma unroll
    for (int kk = 0; kk < 16; kk++) {
      float a[4], b[4];
#pragma unroll
      for (int i = 0; i < 4; i++) a[i] = As[kk][ty * 4 + i];
#pragma unroll
      for (int j = 0; j < 4; j++) b[j] = Bs[kk][tx * 4 + j];
#pragma unroll
      for (int i = 0; i < 4; i++)
#pragma unroll
        for (int j = 0; j < 4; j++) acc[i][j] += a[i] * b[j];
    }
    __syncthreads();
  }
#pragma unroll
  for (int i = 0; i < 4; i++) {
    int r = ty * 4 + i;
    if (m0 + r < cnt) {
#pragma unroll
      for (int j = 0; j < 4; j++) {
        int n = n0 + tx * 4 + j;
        a1[(size_t)(base + r) * FFDIM + n] = fmaxf(acc[i][j] + b1[n], 0.f);
      }
    }
  }
}

__global__ __launch_bounds__(256) void moe2_kernel(const float* __restrict__ a1,
    const float* __restrict__ W2b, const float* __restrict__ b2b, float* __restrict__ h,
    const int* __restrict__ counts, const int* __restrict__ offs,
    const int* __restrict__ tok_list, const float* __restrict__ gate_list, int l) {
  int e = blockIdx.z;
  int cnt = counts[e];
  int m0 = blockIdx.y * 64;
  if (m0 >= cnt) return;
  const float* W  = W2b + (size_t)(l * NEXP + e) * FFDIM * DMODEL;
  const float* b2 = b2b + (size_t)(l * NEXP + e) * DMODEL;
  int base = offs[e] + m0;
  __shared__ float As[16][72];
  __shared__ float Bs[16][72];
  int tid = threadIdx.x;
  int tx = tid & 15, ty = tid >> 4;
  int n0 = blockIdx.x * 64;
  int arow = tid >> 4, akk = tid & 15;
  int bcol = tid & 63, bk0 = tid >> 6;
  float acc[4][4] = {};
  for (int k0 = 0; k0 < FFDIM; k0 += 16) {
#pragma unroll
    for (int i = 0; i < 4; i++) {
      int r = arow + 16 * i;
      As[akk][r] = (m0 + r < cnt) ? a1[(size_t)(base + r) * FFDIM + k0 + akk] : 0.f;
    }
#pragma unroll
    for (int i = 0; i < 4; i++)
      Bs[bk0 + 4 * i][bcol] = W[(size_t)(k0 + bk0 + 4 * i) * DMODEL + n0 + bcol];
    __syncthreads();
#pragma unroll
    for (int kk = 0; kk < 16; kk++) {
      float a[4], b[4];
#pragma unroll
      for (int i = 0; i < 4; i++) a[i] = As[kk][ty * 4 + i];
#pragma unroll
      for (int j = 0; j < 4; j++) b[j] = Bs[kk][tx * 4 + j];
#pragma unroll
      for (int i = 0; i < 4; i++)
#pragma unroll
        for (int j = 0; j < 4; j++) acc[i][j] += a[i] * b[j];
    }
    __syncthreads();
  }
#pragma unroll
  for (int i = 0; i < 4; i++) {
    int r = ty * 4 + i;
    if (m0 + r < cnt) {
      int t = tok_list[e * TOKENS + m0 + r];
      float g = gate_list[e * TOKENS + m0 + r];
#pragma unroll
      for (int j = 0; j < 4; j++) {
        int n = n0 + tx * 4 + j;
        atomicAdd(&h[(size_t)t * DMODEL + n], g * (acc[i][j] + b2[n]));
      }
    }
  }
}

// ---------------- attention-pool head: one block per batch ----------------
__global__ __launch_bounds__(256) void head_kernel(const float* __restrict__ h,
    const float* __restrict__ att_w, const float* __restrict__ att_b,
    const float* __restrict__ head_w, const float* __restrict__ head_b,
    float* __restrict__ out) {
  int b = blockIdx.x, tid = threadIdx.x;
  __shared__ float wl[SEQ];
  __shared__ float red[4];
  __shared__ float pooled[DMODEL];
  float ab = att_b[0];
  float lv[4];
  float lmax = -INFINITY;
#pragma unroll
  for (int i = 0; i < 4; i++) {
    int s = tid + 256 * i;
    const float* hr = h + (size_t)(b * SEQ + s) * DMODEL;
    float acc = 0.f;
    for (int d = 0; d < DMODEL; d++) acc += hr[d] * att_w[d];
    lv[i] = acc + ab;
    lmax = fmaxf(lmax, lv[i]);
  }
#pragma unroll
  for (int off = 32; off; off >>= 1) lmax = fmaxf(lmax, __shfl_xor(lmax, off));
  int wid = tid >> 6;
  if ((tid & 63) == 0) red[wid] = lmax;
  __syncthreads();
  lmax = fmaxf(fmaxf(red[0], red[1]), fmaxf(red[2], red[3]));
  __syncthreads();
  float ls = 0.f;
#pragma unroll
  for (int i = 0; i < 4; i++) {
    float p = expf(lv[i] - lmax);
    wl[tid + 256 * i] = p;
    ls += p;
  }
#pragma unroll
  for (int off = 32; off; off >>= 1) ls += __shfl_xor(ls, off);
  if ((tid & 63) == 0) red[wid] = ls;
  __syncthreads();
  float invs = 1.f / (red[0] + red[1] + red[2] + red[3]);
  for (int d = tid; d < DMODEL; d += 256) {
    float acc = 0.f;
    for (int s = 0; s < SEQ; s++) acc += wl[s] * h[(size_t)(b * SEQ + s) * DMODEL + d];
    pooled[d] = acc * invs;
  }
  __syncthreads();
  float part = 0.f;
  for (int d = tid; d < DMODEL; d += 256) part += pooled[d] * head_w[d];
#pragma unroll
  for (int off = 32; off; off >>= 1) part += __shfl_xor(part, off);
  __syncthreads();
  if ((tid & 63) == 0) red[wid] = part;
  __syncthreads();
  if (tid == 0) out[b] = red[0] + red[1] + red[2] + red[3] + head_b[0];
}

// ---------------- launch ----------------
extern "C" void kernel_launch(void* const* d_in, const int* in_sizes, int n_in,
                              void* d_out, int out_size, void* d_ws, size_t ws_size,
                              hipStream_t stream) {
  (void)in_sizes; (void)n_in; (void)out_size; (void)ws_size;
  const float* x      = (const float*)d_in[0];
  const float* proj_w = (const float*)d_in[1];
  const float* proj_b = (const float*)d_in[2];
  const float* qkv_w  = (const float*)d_in[3];
  const float* qkv_b  = (const float*)d_in[4];
  const float* out_w  = (const float*)d_in[5];
  const float* out_b  = (const float*)d_in[6];
  const float* n1_s   = (const float*)d_in[7];
  const float* n1_b   = (const float*)d_in[8];
  const float* n2_s   = (const float*)d_in[9];
  const float* n2_b   = (const float*)d_in[10];
  const float* gate_w = (const float*)d_in[11];
  const float* e_w1   = (const float*)d_in[12];
  const float* e_b1   = (const float*)d_in[13];
  const float* e_w2   = (const float*)d_in[14];
  const float* e_b2   = (const float*)d_in[15];
  const float* att_w  = (const float*)d_in[16];
  const float* att_b  = (const float*)d_in[17];
  const float* head_w = (const float*)d_in[18];
  const float* head_b = (const float*)d_in[19];
  float* out = (float*)d_out;

  // workspace layout (bytes):
  // h: 0 .. 25165824 | xn/ao: 25165824 .. 50331648 | union(qkv 75.5MB | a1 102.2MB)
  char* wsb = (char*)d_ws;
  float* h   = (float*)(wsb);
  float* xn  = (float*)(wsb + 25165824);
  float* uni = (float*)(wsb + 50331648);       // qkv during attention, a1 during MoE
  char* sm   = wsb + 152567808;
  int*   counts    = (int*)(sm);
  int*   offs      = (int*)(sm + 64);
  float* sum_probs = (float*)(sm + 128);
  float* total_moe = (float*)(sm + 192);
  int*   tok_list  = (int*)(sm + 256);
  float* gate_list = (float*)(sm + 256 + 524288);

  init_kernel<<<1, 1, 0, stream>>>(total_moe);
  proj_kernel<<<TOKENS * DMODEL / 256, 256, 0, stream>>>(x, proj_w, proj_b, h);

  for (int l = 0; l < NL; l++) {
    ln_kernel<<<TOKENS, 384, 0, stream>>>(h, xn, n1_s + l * DMODEL, n1_b + l * DMODEL);
    gemm_kernel<false, false><<<dim3(18, 256), 256, 0, stream>>>(
        xn, qkv_w + (size_t)l * DMODEL * 1152, qkv_b + l * 1152, nullptr, uni,
        TOKENS, 1152, DMODEL);
    // grid (head, batch, qblock): q-blocks of one (b,h) are 128 apart in dispatch
    // order -> same XCD -> K/V L2 reuse.
    attn_kernel<<<dim3(NHEAD, 16, 16), 256, 0, stream>>>(uni, xn);  // ao aliases xn
    gemm_kernel<true, false><<<dim3(6, 256), 256, 0, stream>>>(
        xn, out_w + (size_t)l * DMODEL * DMODEL, out_b + l * DMODEL, h, h,
        TOKENS, DMODEL, DMODEL);
    ln_kernel<<<TOKENS, 384, 0, stream>>>(h, xn, n2_s + l * DMODEL, n2_b + l * DMODEL);
    zero_cnt_kernel<<<1, 64, 0, stream>>>(counts, sum_probs);
    gate_kernel<<<TOKENS / 4, 256, 0, stream>>>(xn, gate_w + (size_t)l * DMODEL * NEXP,
                                                counts, sum_probs, tok_list, gate_list);
    aux_kernel<<<1, 1, 0, stream>>>(counts, offs, sum_probs, total_moe);
    moe1_kernel<<<dim3(12, 256, 8), 256, 0, stream>>>(xn, e_w1, e_b1, uni,
                                                      counts, offs, tok_list, l);
    moe2_kernel<<<dim3(6, 256, 8), 256, 0, stream>>>(uni, e_w2, e_b2, h,
                                                     counts, offs, tok_list, gate_list, l);
  }

  head_kernel<<<16, 256, 0, stream>>>(h, att_w, att_b, head_w, head_b, out);
  finalize_kernel<<<1, 1, 0, stream>>>(total_moe, out);
}

// Round 3
// 1699.778 us; speedup vs baseline: 4.3650x; 2.6656x over previous
//
#include <hip/hip_runtime.h>
#include <hip/hip_bf16.h>
#include <math.h>

// RULPredictionModel: B=16 S=1024 D=384 H=8 DH=48 L=3 E=8 FF=768 TOP_K=2
#define TOKENS 16384
#define DMODEL 384
#define SEQ 1024
#define NHEAD 8
#define DHEAD 48
#define NEXP 8
#define FFDIM 768
#define NL 3

typedef __bf16 bf16x8 __attribute__((ext_vector_type(8)));
typedef __bf16 bf16x4 __attribute__((ext_vector_type(4)));
typedef float f32x4 __attribute__((ext_vector_type(4)));

// ---------------- tiny kernels ----------------
__global__ void init_kernel(float* total_moe) { *total_moe = 0.f; }

__global__ void zero_cnt_kernel(int* counts, float* sum_probs) {
  int t = threadIdx.x;
  if (t < NEXP) { counts[t] = 0; sum_probs[t] = 0.f; }
}

__global__ void finalize_kernel(const float* total_moe, float* out) { out[16] = *total_moe; }

__global__ __launch_bounds__(256) void proj_kernel(const float* __restrict__ x,
    const float* __restrict__ pw, const float* __restrict__ pb, float* __restrict__ h) {
  int i = blockIdx.x * 256 + threadIdx.x;
  int t = i / DMODEL;
  int d = i - t * DMODEL;
  h[i] = x[t] * pw[d] + pb[d];
}

// weight transpose + cast: src fp32 [K][N] (batched) -> dst bf16 [N][K]
__global__ __launch_bounds__(256) void convw_kernel(const float* __restrict__ src,
    __bf16* __restrict__ dst, int K, int N) {
  __shared__ float t[32][33];
  size_t boff = (size_t)blockIdx.z * K * N;
  src += boff; dst += boff;
  int k0 = blockIdx.y * 32, n0 = blockIdx.x * 32;
  int tx = threadIdx.x & 31, ty = threadIdx.x >> 5;   // 32 x 8
#pragma unroll
  for (int i = 0; i < 32; i += 8) t[ty + i][tx] = src[(size_t)(k0 + ty + i) * N + n0 + tx];
  __syncthreads();
#pragma unroll
  for (int i = 0; i < 32; i += 8)
    dst[(size_t)(n0 + ty + i) * K + k0 + tx] = (__bf16)t[tx][ty + i];
}

// one block (384 threads) per row; bf16 output
__global__ __launch_bounds__(384) void ln_kernel(const float* __restrict__ src,
    __bf16* __restrict__ dst, const float* __restrict__ gs, const float* __restrict__ gb) {
  int row = blockIdx.x, tid = threadIdx.x;
  float v = src[(size_t)row * DMODEL + tid];
  float sum = v, sq = v * v;
#pragma unroll
  for (int off = 32; off; off >>= 1) { sum += __shfl_xor(sum, off); sq += __shfl_xor(sq, off); }
  __shared__ float rs[6], rq[6];
  __shared__ float smean, sinv;
  int wid = tid >> 6;
  if ((tid & 63) == 0) { rs[wid] = sum; rq[wid] = sq; }
  __syncthreads();
  if (tid == 0) {
    float S = 0.f, Q = 0.f;
    for (int w = 0; w < 6; w++) { S += rs[w]; Q += rq[w]; }
    float mean = S / (float)DMODEL;
    float var = Q / (float)DMODEL - mean * mean;
    smean = mean; sinv = rsqrtf(var + 1e-5f);
  }
  __syncthreads();
  dst[(size_t)row * DMODEL + tid] = (__bf16)((v - smean) * sinv * gs[tid] + gb[tid]);
}

// ---------------- bf16 MFMA GEMM: C = A @ Wt^T + bias, tile 128x64x64 ----------------
// MODE 0: qkv   (A=xnb,  out bf16 Cb)
// MODE 1: out   (A=aob,  Cf += acc+bias)   [residual]
// MODE 2: moe1  (A=gather(xnb) via tok_list, relu, out bf16 a1)
// MODE 3: moe2  (A=a1b rows base+m, atomicAdd gate*(acc+bias) into Cf)
template<int MODE>
__global__ __launch_bounds__(256) void mgemm_kernel(
    const __bf16* __restrict__ Abf, const __bf16* __restrict__ Wt,
    const float* __restrict__ bias, float* __restrict__ Cf, __bf16* __restrict__ Cb,
    const int* __restrict__ counts, const int* __restrict__ offs,
    const int* __restrict__ tok_list, const float* __restrict__ gate_list,
    int N, int K) {
  int e = 0, cnt = 0, base = 0;
  const int* tl = nullptr;
  int m0 = blockIdx.y * 128;
  if constexpr (MODE == 2 || MODE == 3) {
    e = blockIdx.z;
    cnt = counts[e];
    if (m0 >= cnt) return;
    base = offs[e];
    tl = tok_list + e * TOKENS;
    Wt += (size_t)e * N * K;
    bias += (size_t)e * N;
  }
  __shared__ __align__(16) __bf16 As[128][72];
  __shared__ __align__(16) __bf16 Bs[64][72];
  int tid = threadIdx.x;
  int n0 = blockIdx.x * 64;
  int w = tid >> 6, lane = tid & 63, c = lane & 15, g = lane >> 4;
  int arow[4], acol[4];
  long tok[4];
#pragma unroll
  for (int i = 0; i < 4; i++) {
    int chunk = tid + 256 * i;
    arow[i] = chunk >> 3;
    acol[i] = (chunk & 7) * 8;
    int mr = m0 + arow[i];
    if constexpr (MODE == 2)      tok[i] = (mr < cnt) ? (long)tl[mr] : -1;
    else if constexpr (MODE == 3) tok[i] = (mr < cnt) ? (long)(base + mr) : -1;
    else                          tok[i] = mr;
  }
  f32x4 acc[2][4];
#pragma unroll
  for (int m = 0; m < 2; m++)
#pragma unroll
    for (int n = 0; n < 4; n++) { acc[m][n][0] = 0.f; acc[m][n][1] = 0.f; acc[m][n][2] = 0.f; acc[m][n][3] = 0.f; }

  for (int k0 = 0; k0 < K; k0 += 64) {
#pragma unroll
    for (int i = 0; i < 4; i++) {
      bf16x8 v = {};
      if (tok[i] >= 0) v = *(const bf16x8*)&Abf[(size_t)tok[i] * K + k0 + acol[i]];
      *(bf16x8*)&As[arow[i]][acol[i]] = v;
    }
#pragma unroll
    for (int i = 0; i < 2; i++) {
      int chunk = tid + 256 * i;
      int br = chunk >> 3, bc = (chunk & 7) * 8;
      *(bf16x8*)&Bs[br][bc] = *(const bf16x8*)&Wt[(size_t)(n0 + br) * K + k0 + bc];
    }
    __syncthreads();
#pragma unroll
    for (int kk = 0; kk < 2; kk++) {
      bf16x8 a0 = *(const bf16x8*)&As[w * 32 + c][kk * 32 + g * 8];
      bf16x8 a1 = *(const bf16x8*)&As[w * 32 + 16 + c][kk * 32 + g * 8];
#pragma unroll
      for (int n = 0; n < 4; n++) {
        bf16x8 b = *(const bf16x8*)&Bs[n * 16 + c][kk * 32 + g * 8];
        acc[0][n] = __builtin_amdgcn_mfma_f32_16x16x32_bf16(a0, b, acc[0][n], 0, 0, 0);
        acc[1][n] = __builtin_amdgcn_mfma_f32_16x16x32_bf16(a1, b, acc[1][n], 0, 0, 0);
      }
    }
    __syncthreads();
  }
#pragma unroll
  for (int m = 0; m < 2; m++) {
    int row = w * 32 + m * 16 + 4 * g;                // local row (+r)
#pragma unroll
    for (int n = 0; n < 4; n++) {
      int col = n0 + n * 16 + c;
      float bv = bias[col];
#pragma unroll
      for (int r = 0; r < 4; r++) {
        float v = acc[m][n][r] + bv;
        int lr = row + r;
        if constexpr (MODE == 0) {
          Cb[(size_t)(m0 + lr) * N + col] = (__bf16)v;
        } else if constexpr (MODE == 1) {
          Cf[(size_t)(m0 + lr) * N + col] += v;
        } else if constexpr (MODE == 2) {
          if (m0 + lr < cnt) Cb[(size_t)(base + m0 + lr) * N + col] = (__bf16)fmaxf(v, 0.f);
        } else {
          if (m0 + lr < cnt) {
            int t = tl[m0 + lr];
            float gv = gate_list[e * TOKENS + m0 + lr];
            atomicAdd(&Cf[(size_t)t * DMODEL + col], gv * v);
          }
        }
      }
    }
  }
}

// ---------------- bf16 MFMA flash attention (bf16 in / bf16 out) ----------------
__global__ __launch_bounds__(256) void attn_kernel(const __bf16* __restrict__ qkv,
                                                   __bf16* __restrict__ ao) {
  __shared__ __align__(16) __bf16 Qs[64][88];
  __shared__ __align__(16) __bf16 Ks[64][88];
  __shared__ __align__(16) __bf16 Vt[48][88];   // V transposed: [dh][kv]
  __shared__ __align__(16) __bf16 Ps[64][88];   // P probs: [q][kv]
  int hh = blockIdx.x;
  int b  = blockIdx.y;
  int q0 = blockIdx.z * 64;
  int tid = threadIdx.x;
  int wq = tid >> 6;
  int lane = tid & 63;
  int c = lane & 15, g = lane >> 4;
  const float scale = 0.14433756729740643f;     // 1/sqrt(48)

  for (int e = tid; e < 64 * 16; e += 256) {
    int r = e >> 4, col = 48 + (e & 15);
    Qs[r][col] = (__bf16)0.f;
    Ks[r][col] = (__bf16)0.f;
  }
  for (int e = tid; e < 384; e += 256) {        // 64 rows x 6 chunks of 8
    int row = e / 6, cg = (e % 6) * 8;
    *(bf16x8*)&Qs[row][cg] =
        *(const bf16x8*)&qkv[((size_t)(b * SEQ + q0 + row)) * 1152 + hh * 48 + cg];
  }
  __syncthreads();
  bf16x8 qa0 = *(const bf16x8*)&Qs[wq * 16 + c][g * 8];
  bf16x8 qa1 = *(const bf16x8*)&Qs[wq * 16 + c][32 + g * 8];

  f32x4 acc[3];
  float m[4], l[4];
#pragma unroll
  for (int t = 0; t < 3; t++) { acc[t][0] = 0.f; acc[t][1] = 0.f; acc[t][2] = 0.f; acc[t][3] = 0.f; }
#pragma unroll
  for (int r = 0; r < 4; r++) { m[r] = -INFINITY; l[r] = 0.f; }

  for (int kt = 0; kt < 16; kt++) {
    __syncthreads();
    for (int e = tid; e < 384; e += 256) {
      int row = e / 6, cg = (e % 6) * 8;
      size_t bbase = ((size_t)(b * SEQ + kt * 64 + row)) * 1152 + hh * 48 + cg;
      *(bf16x8*)&Ks[row][cg] = *(const bf16x8*)&qkv[bbase + 384];
      bf16x8 vv = *(const bf16x8*)&qkv[bbase + 768];
#pragma unroll
      for (int j = 0; j < 8; j++) Vt[cg + j][row] = vv[j];
    }
    __syncthreads();

    f32x4 s[4];
#pragma unroll
    for (int f = 0; f < 4; f++) {
      s[f][0] = 0.f; s[f][1] = 0.f; s[f][2] = 0.f; s[f][3] = 0.f;
      bf16x8 kb0 = *(const bf16x8*)&Ks[f * 16 + c][g * 8];
      bf16x8 kb1 = *(const bf16x8*)&Ks[f * 16 + c][32 + g * 8];
      s[f] = __builtin_amdgcn_mfma_f32_16x16x32_bf16(qa0, kb0, s[f], 0, 0, 0);
      s[f] = __builtin_amdgcn_mfma_f32_16x16x32_bf16(qa1, kb1, s[f], 0, 0, 0);
    }
    float sv[4][4];
#pragma unroll
    for (int f = 0; f < 4; f++)
#pragma unroll
      for (int r = 0; r < 4; r++) sv[f][r] = s[f][r] * scale;
    float alpha[4];
#pragma unroll
    for (int r = 0; r < 4; r++) {
      float t0 = fmaxf(fmaxf(sv[0][r], sv[1][r]), fmaxf(sv[2][r], sv[3][r]));
      t0 = fmaxf(t0, __shfl_xor(t0, 1));
      t0 = fmaxf(t0, __shfl_xor(t0, 2));
      t0 = fmaxf(t0, __shfl_xor(t0, 4));
      t0 = fmaxf(t0, __shfl_xor(t0, 8));
      float mnew = fmaxf(m[r], t0);
      alpha[r] = __expf(m[r] - mnew);
      m[r] = mnew;
    }
    float p[4][4], ps[4];
#pragma unroll
    for (int r = 0; r < 4; r++) ps[r] = 0.f;
#pragma unroll
    for (int f = 0; f < 4; f++)
#pragma unroll
      for (int r = 0; r < 4; r++) { p[f][r] = __expf(sv[f][r] - m[r]); ps[r] += p[f][r]; }
#pragma unroll
    for (int r = 0; r < 4; r++) {
      float t0 = ps[r];
      t0 += __shfl_xor(t0, 1);
      t0 += __shfl_xor(t0, 2);
      t0 += __shfl_xor(t0, 4);
      t0 += __shfl_xor(t0, 8);
      l[r] = l[r] * alpha[r] + t0;
    }
#pragma unroll
    for (int t = 0; t < 3; t++)
#pragma unroll
      for (int r = 0; r < 4; r++) acc[t][r] *= alpha[r];
#pragma unroll
    for (int f = 0; f < 4; f++)
#pragma unroll
      for (int r = 0; r < 4; r++)
        Ps[wq * 16 + 4 * g + r][f * 16 + c] = (__bf16)p[f][r];
    bf16x8 pa0 = *(const bf16x8*)&Ps[wq * 16 + c][g * 8];
    bf16x8 pa1 = *(const bf16x8*)&Ps[wq * 16 + c][32 + g * 8];
#pragma unroll
    for (int t = 0; t < 3; t++) {
      bf16x8 vb0 = *(const bf16x8*)&Vt[t * 16 + c][g * 8];
      bf16x8 vb1 = *(const bf16x8*)&Vt[t * 16 + c][32 + g * 8];
      acc[t] = __builtin_amdgcn_mfma_f32_16x16x32_bf16(pa0, vb0, acc[t], 0, 0, 0);
      acc[t] = __builtin_amdgcn_mfma_f32_16x16x32_bf16(pa1, vb1, acc[t], 0, 0, 0);
    }
  }
  float invl[4];
#pragma unroll
  for (int r = 0; r < 4; r++) invl[r] = 1.f / l[r];
#pragma unroll
  for (int t = 0; t < 3; t++)
#pragma unroll
    for (int r = 0; r < 4; r++)
      ao[((size_t)(b * SEQ + q0 + wq * 16 + 4 * g + r)) * DMODEL + hh * 48 + t * 16 + c] =
          (__bf16)(acc[t][r] * invl[r]);
}

// ---------------- gating: block = 256 tokens, block-aggregated atomics ----------------
__global__ __launch_bounds__(256) void gate_kernel(const __bf16* __restrict__ xnb,
    const float* __restrict__ gw, int* __restrict__ counts, float* __restrict__ sum_probs,
    int* __restrict__ tok_list, float* __restrict__ gate_list) {
  __shared__ float Gs[NEXP][DMODEL];
  __shared__ float simp[NEXP];
  __shared__ int hist[NEXP], basep[NEXP];
  __shared__ unsigned char tokE[256][2];
  __shared__ float tokG[256][2];
  __shared__ short rankS[256][2];
  int tid = threadIdx.x;
  for (int i = tid; i < DMODEL * NEXP; i += 256) {
    int d = i >> 3, e2 = i & 7;
    Gs[e2][d] = gw[i];
  }
  if (tid < NEXP) { simp[tid] = 0.f; hist[tid] = 0; }
  __syncthreads();
  int w = tid >> 6, lane = tid & 63;
  int tbase = blockIdx.x * 256 + w * 64;
  float impacc[NEXP] = {};
  for (int tt = 0; tt < 64; tt++) {
    int t = tbase + tt;
    float p[NEXP] = {};
#pragma unroll
    for (int j = 0; j < 6; j++) {
      int d = lane + 64 * j;
      float xv = (float)xnb[(size_t)t * DMODEL + d];
#pragma unroll
      for (int e2 = 0; e2 < NEXP; e2++) p[e2] += xv * Gs[e2][d];
    }
#pragma unroll
    for (int off = 32; off; off >>= 1)
#pragma unroll
      for (int e2 = 0; e2 < NEXP; e2++) p[e2] += __shfl_xor(p[e2], off);
    // all lanes now hold identical full sums
    float mx = p[0];
#pragma unroll
    for (int e2 = 1; e2 < NEXP; e2++) mx = fmaxf(mx, p[e2]);
    float s = 0.f;
#pragma unroll
    for (int e2 = 0; e2 < NEXP; e2++) { p[e2] = __expf(p[e2] - mx); s += p[e2]; }
    float inv = 1.f / s;
#pragma unroll
    for (int e2 = 0; e2 < NEXP; e2++) { p[e2] *= inv; impacc[e2] += p[e2]; }
    int i0 = 0; float v0 = p[0];
#pragma unroll
    for (int e2 = 1; e2 < NEXP; e2++) if (p[e2] > v0) { v0 = p[e2]; i0 = e2; }
    int i1 = -1; float v1 = -INFINITY;
#pragma unroll
    for (int e2 = 0; e2 < NEXP; e2++) if (e2 != i0 && p[e2] > v1) { v1 = p[e2]; i1 = e2; }
    if (lane == 0) {
      float gsum = v0 + v1;
      int r0 = atomicAdd(&hist[i0], 1);
      int r1 = atomicAdd(&hist[i1], 1);
      int sl = w * 64 + tt;
      tokE[sl][0] = (unsigned char)i0; tokE[sl][1] = (unsigned char)i1;
      tokG[sl][0] = v0 / gsum;         tokG[sl][1] = v1 / gsum;
      rankS[sl][0] = (short)r0;        rankS[sl][1] = (short)r1;
    }
  }
  if (lane == 0)
#pragma unroll
    for (int e2 = 0; e2 < NEXP; e2++) atomicAdd(&simp[e2], impacc[e2]);
  __syncthreads();
  if (tid < NEXP) {
    basep[tid] = atomicAdd(&counts[tid], hist[tid]);
    atomicAdd(&sum_probs[tid], simp[tid]);
  }
  __syncthreads();
  int t0 = blockIdx.x * 256;
  for (int i = tid; i < 512; i += 256) {
    int sl = i >> 1, a = i & 1;
    int e2 = tokE[sl][a];
    int pos = basep[e2] + rankS[sl][a];
    tok_list[e2 * TOKENS + pos] = t0 + sl;
    gate_list[e2 * TOKENS + pos] = tokG[sl][a];
  }
}

// prefix offsets (64-padded) + aux loss contribution
__global__ void aux_kernel(const int* __restrict__ counts, int* __restrict__ offs,
                           const float* __restrict__ sum_probs, float* __restrict__ total_moe) {
  int off = 0;
  float tm = 0.f;
  for (int e = 0; e < NEXP; e++) {
    offs[e] = off;
    off += ((counts[e] + 63) >> 6) << 6;
    tm += sum_probs[e] * (float)counts[e];
  }
  offs[NEXP] = off;
  *total_moe += (float)NEXP * tm / ((float)TOKENS * (float)TOKENS);
}

// ---------------- attention-pool head: one block per batch ----------------
__global__ __launch_bounds__(256) void head_kernel(const float* __restrict__ h,
    const float* __restrict__ att_w, const float* __restrict__ att_b,
    const float* __restrict__ head_w, const float* __restrict__ head_b,
    float* __restrict__ out) {
  int b = blockIdx.x, tid = threadIdx.x;
  __shared__ float wl[SEQ];
  __shared__ float red[4];
  __shared__ float pooled[DMODEL];
  float ab = att_b[0];
  float lv[4];
  float lmax = -INFINITY;
#pragma unroll
  for (int i = 0; i < 4; i++) {
    int s = tid + 256 * i;
    const float* hr = h + (size_t)(b * SEQ + s) * DMODEL;
    float acc = 0.f;
    for (int d = 0; d < DMODEL; d++) acc += hr[d] * att_w[d];
    lv[i] = acc + ab;
    lmax = fmaxf(lmax, lv[i]);
  }
#pragma unroll
  for (int off = 32; off; off >>= 1) lmax = fmaxf(lmax, __shfl_xor(lmax, off));
  int wid = tid >> 6;
  if ((tid & 63) == 0) red[wid] = lmax;
  __syncthreads();
  lmax = fmaxf(fmaxf(red[0], red[1]), fmaxf(red[2], red[3]));
  __syncthreads();
  float ls = 0.f;
#pragma unroll
  for (int i = 0; i < 4; i++) {
    float p = expf(lv[i] - lmax);
    wl[tid + 256 * i] = p;
    ls += p;
  }
#pragma unroll
  for (int off = 32; off; off >>= 1) ls += __shfl_xor(ls, off);
  if ((tid & 63) == 0) red[wid] = ls;
  __syncthreads();
  float invs = 1.f / (red[0] + red[1] + red[2] + red[3]);
  for (int d = tid; d < DMODEL; d += 256) {
    float acc = 0.f;
    for (int s = 0; s < SEQ; s++) acc += wl[s] * h[(size_t)(b * SEQ + s) * DMODEL + d];
    pooled[d] = acc * invs;
  }
  __syncthreads();
  float part = 0.f;
  for (int d = tid; d < DMODEL; d += 256) part += pooled[d] * head_w[d];
#pragma unroll
  for (int off = 32; off; off >>= 1) part += __shfl_xor(part, off);
  __syncthreads();
  if ((tid & 63) == 0) red[wid] = part;
  __syncthreads();
  if (tid == 0) out[b] = red[0] + red[1] + red[2] + red[3] + head_b[0];
}

// ---------------- launch ----------------
extern "C" void kernel_launch(void* const* d_in, const int* in_sizes, int n_in,
                              void* d_out, int out_size, void* d_ws, size_t ws_size,
                              hipStream_t stream) {
  (void)in_sizes; (void)n_in; (void)out_size; (void)ws_size;
  const float* x      = (const float*)d_in[0];
  const float* proj_w = (const float*)d_in[1];
  const float* proj_b = (const float*)d_in[2];
  const float* qkv_w  = (const float*)d_in[3];
  const float* qkv_b  = (const float*)d_in[4];
  const float* out_w  = (const float*)d_in[5];
  const float* out_b  = (const float*)d_in[6];
  const float* n1_s   = (const float*)d_in[7];
  const float* n1_b   = (const float*)d_in[8];
  const float* n2_s   = (const float*)d_in[9];
  const float* n2_b   = (const float*)d_in[10];
  const float* gate_w = (const float*)d_in[11];
  const float* e_w1   = (const float*)d_in[12];
  const float* e_b1   = (const float*)d_in[13];
  const float* e_w2   = (const float*)d_in[14];
  const float* e_b2   = (const float*)d_in[15];
  const float* att_w  = (const float*)d_in[16];
  const float* att_b  = (const float*)d_in[17];
  const float* head_w = (const float*)d_in[18];
  const float* head_b = (const float*)d_in[19];
  float* out = (float*)d_out;

  // workspace layout (bytes):
  // h fp32 25.2MB | xnb bf16 12.6MB | aob bf16 12.6MB | uni (qkvb 37.7MB | a1b 51.1MB)
  // | Wt bf16 31.9MB | control
  char* wsb = (char*)d_ws;
  float*  h    = (float*)(wsb);
  __bf16* xnb  = (__bf16*)(wsb + 25165824);
  __bf16* aob  = (__bf16*)(wsb + 37748736);
  __bf16* uni  = (__bf16*)(wsb + 50331648);
  __bf16* qkvWt = (__bf16*)(wsb + 101449728);   // [3][1152][384]
  __bf16* outWt = (__bf16*)(wsb + 104103936);   // [3][384][384]
  __bf16* e1Wt  = (__bf16*)(wsb + 104988672);   // [3*8][768][384]
  __bf16* e2Wt  = (__bf16*)(wsb + 119144448);   // [3*8][384][768]
  char* sm = wsb + 133300224;
  int*   counts    = (int*)(sm);
  int*   offs      = (int*)(sm + 64);
  float* sum_probs = (float*)(sm + 128);
  float* total_moe = (float*)(sm + 192);
  int*   tok_list  = (int*)(sm + 256);
  float* gate_list = (float*)(sm + 256 + 524288);

  // one-shot weight transpose+cast (runs every call; deterministic)
  convw_kernel<<<dim3(36, 12, 3), 256, 0, stream>>>(qkv_w, qkvWt, 384, 1152);
  convw_kernel<<<dim3(12, 12, 3), 256, 0, stream>>>(out_w, outWt, 384, 384);
  convw_kernel<<<dim3(24, 12, 24), 256, 0, stream>>>(e_w1, e1Wt, 384, 768);
  convw_kernel<<<dim3(12, 24, 24), 256, 0, stream>>>(e_w2, e2Wt, 768, 384);

  init_kernel<<<1, 1, 0, stream>>>(total_moe);
  proj_kernel<<<TOKENS * DMODEL / 256, 256, 0, stream>>>(x, proj_w, proj_b, h);

  for (int l = 0; l < NL; l++) {
    ln_kernel<<<TOKENS, 384, 0, stream>>>(h, xnb, n1_s + l * DMODEL, n1_b + l * DMODEL);
    mgemm_kernel<0><<<dim3(18, 128), 256, 0, stream>>>(
        xnb, qkvWt + (size_t)l * 1152 * 384, qkv_b + l * 1152, nullptr, uni,
        nullptr, nullptr, nullptr, nullptr, 1152, 384);
    attn_kernel<<<dim3(NHEAD, 16, 16), 256, 0, stream>>>(uni, aob);
    mgemm_kernel<1><<<dim3(6, 128), 256, 0, stream>>>(
        aob, outWt + (size_t)l * 384 * 384, out_b + l * 384, h, nullptr,
        nullptr, nullptr, nullptr, nullptr, 384, 384);
    ln_kernel<<<TOKENS, 384, 0, stream>>>(h, xnb, n2_s + l * DMODEL, n2_b + l * DMODEL);
    zero_cnt_kernel<<<1, 64, 0, stream>>>(counts, sum_probs);
    gate_kernel<<<64, 256, 0, stream>>>(xnb, gate_w + (size_t)l * DMODEL * NEXP,
                                        counts, sum_probs, tok_list, gate_list);
    aux_kernel<<<1, 1, 0, stream>>>(counts, offs, sum_probs, total_moe);
    mgemm_kernel<2><<<dim3(12, 128, 8), 256, 0, stream>>>(
        xnb, e1Wt + (size_t)l * 8 * 768 * 384, e_b1 + l * 8 * FFDIM, nullptr, uni,
        counts, offs, tok_list, nullptr, 768, 384);
    mgemm_kernel<3><<<dim3(6, 128, 8), 256, 0, stream>>>(
        uni, e2Wt + (size_t)l * 8 * 384 * 768, e_b2 + l * 8 * DMODEL, h, nullptr,
        counts, offs, tok_list, gate_list, 384, 768);
  }

  head_kernel<<<16, 256, 0, stream>>>(h, att_w, att_b, head_w, head_b, out);
  finalize_kernel<<<1, 1, 0, stream>>>(total_moe, out);
}

// Round 5
// 1605.472 us; speedup vs baseline: 4.6214x; 1.0587x over previous
//
#include <hip/hip_runtime.h>
#include <hip/hip_bf16.h>
#include <math.h>

// RULPredictionModel: B=16 S=1024 D=384 H=8 DH=48 L=3 E=8 FF=768 TOP_K=2
#define TOKENS 16384
#define DMODEL 384
#define SEQ 1024
#define NHEAD 8
#define DHEAD 48
#define NEXP 8
#define FFDIM 768
#define NL 3

typedef __bf16 bf16x8 __attribute__((ext_vector_type(8)));
typedef __bf16 bf16x4 __attribute__((ext_vector_type(4)));
typedef float f32x4 __attribute__((ext_vector_type(4)));

// ---------------- tiny kernels ----------------
__global__ void init_kernel(float* total_moe) { *total_moe = 0.f; }

__global__ void zero_cnt_kernel(int* counts, float* sum_probs) {
  int t = threadIdx.x;
  if (t < NEXP) { counts[t] = 0; sum_probs[t] = 0.f; }
}

__global__ void finalize_kernel(const float* total_moe, float* out) { out[16] = *total_moe; }

__global__ __launch_bounds__(256) void proj_kernel(const float* __restrict__ x,
    const float* __restrict__ pw, const float* __restrict__ pb, float* __restrict__ h) {
  int i = blockIdx.x * 256 + threadIdx.x;
  int t = i / DMODEL;
  int d = i - t * DMODEL;
  h[i] = x[t] * pw[d] + pb[d];
}

// weight transpose + cast: src fp32 [K][N] (batched) -> dst bf16 [N][K]
__global__ __launch_bounds__(256) void convw_kernel(const float* __restrict__ src,
    __bf16* __restrict__ dst, int K, int N) {
  __shared__ float t[32][33];
  size_t boff = (size_t)blockIdx.z * K * N;
  src += boff; dst += boff;
  int k0 = blockIdx.y * 32, n0 = blockIdx.x * 32;
  int tx = threadIdx.x & 31, ty = threadIdx.x >> 5;   // 32 x 8
#pragma unroll
  for (int i = 0; i < 32; i += 8) t[ty + i][tx] = src[(size_t)(k0 + ty + i) * N + n0 + tx];
  __syncthreads();
#pragma unroll
  for (int i = 0; i < 32; i += 8)
    dst[(size_t)(n0 + ty + i) * K + k0 + tx] = (__bf16)t[tx][ty + i];
}

// one block (384 threads) per row; bf16 output
__global__ __launch_bounds__(384) void ln_kernel(const float* __restrict__ src,
    __bf16* __restrict__ dst, const float* __restrict__ gs, const float* __restrict__ gb) {
  int row = blockIdx.x, tid = threadIdx.x;
  float v = src[(size_t)row * DMODEL + tid];
  float sum = v, sq = v * v;
#pragma unroll
  for (int off = 32; off; off >>= 1) { sum += __shfl_xor(sum, off); sq += __shfl_xor(sq, off); }
  __shared__ float rs[6], rq[6];
  __shared__ float smean, sinv;
  int wid = tid >> 6;
  if ((tid & 63) == 0) { rs[wid] = sum; rq[wid] = sq; }
  __syncthreads();
  if (tid == 0) {
    float S = 0.f, Q = 0.f;
    for (int w = 0; w < 6; w++) { S += rs[w]; Q += rq[w]; }
    float mean = S / (float)DMODEL;
    float var = Q / (float)DMODEL - mean * mean;
    smean = mean; sinv = rsqrtf(var + 1e-5f);
  }
  __syncthreads();
  dst[(size_t)row * DMODEL + tid] = (__bf16)((v - smean) * sinv * gs[tid] + gb[tid]);
}

// ---------------- bf16 MFMA GEMM: C = A @ Wt^T + bias, tile 128x64x64 ----------------
// MODE 0: qkv   (A=xnb, writes head-major Qh/Kh + transposed VTh)
// MODE 1: out   (A=aob,  Cf += acc+bias)   [residual]
// MODE 2: moe1  (A=gather(xnb) via tok_list, relu, out bf16 a1)
// MODE 3: moe2  (A=a1b rows base+m, atomicAdd gate*(acc+bias) into Cf)
template<int MODE>
__global__ __launch_bounds__(256) void mgemm_kernel(
    const __bf16* __restrict__ Abf, const __bf16* __restrict__ Wt,
    const float* __restrict__ bias, float* __restrict__ Cf, __bf16* __restrict__ Cb,
    __bf16* __restrict__ pQ, __bf16* __restrict__ pK, __bf16* __restrict__ pV,
    const int* __restrict__ counts, const int* __restrict__ offs,
    const int* __restrict__ tok_list, const float* __restrict__ gate_list,
    int N, int K) {
  int e = 0, cnt = 0, base = 0;
  const int* tl = nullptr;
  int m0 = blockIdx.y * 128;
  if constexpr (MODE == 2 || MODE == 3) {
    e = blockIdx.z;
    cnt = counts[e];
    if (m0 >= cnt) return;
    base = offs[e];
    tl = tok_list + e * TOKENS;
    Wt += (size_t)e * N * K;
    bias += (size_t)e * N;
  }
  __shared__ __align__(16) __bf16 As[128][72];
  __shared__ __align__(16) __bf16 Bs[64][72];
  int tid = threadIdx.x;
  int n0 = blockIdx.x * 64;
  int w = tid >> 6, lane = tid & 63, c = lane & 15, g = lane >> 4;
  int arow[4], acol[4];
  long tok[4];
#pragma unroll
  for (int i = 0; i < 4; i++) {
    int chunk = tid + 256 * i;
    arow[i] = chunk >> 3;
    acol[i] = (chunk & 7) * 8;
    int mr = m0 + arow[i];
    if constexpr (MODE == 2)      tok[i] = (mr < cnt) ? (long)tl[mr] : -1;
    else if constexpr (MODE == 3) tok[i] = (mr < cnt) ? (long)(base + mr) : -1;
    else                          tok[i] = mr;
  }
  f32x4 acc[2][4];
#pragma unroll
  for (int m = 0; m < 2; m++)
#pragma unroll
    for (int n = 0; n < 4; n++) { acc[m][n][0] = 0.f; acc[m][n][1] = 0.f; acc[m][n][2] = 0.f; acc[m][n][3] = 0.f; }

  for (int k0 = 0; k0 < K; k0 += 64) {
#pragma unroll
    for (int i = 0; i < 4; i++) {
      bf16x8 v = {};
      if (tok[i] >= 0) v = *(const bf16x8*)&Abf[(size_t)tok[i] * K + k0 + acol[i]];
      *(bf16x8*)&As[arow[i]][acol[i]] = v;
    }
#pragma unroll
    for (int i = 0; i < 2; i++) {
      int chunk = tid + 256 * i;
      int br = chunk >> 3, bc = (chunk & 7) * 8;
      *(bf16x8*)&Bs[br][bc] = *(const bf16x8*)&Wt[(size_t)(n0 + br) * K + k0 + bc];
    }
    __syncthreads();
#pragma unroll
    for (int kk = 0; kk < 2; kk++) {
      bf16x8 a0 = *(const bf16x8*)&As[w * 32 + c][kk * 32 + g * 8];
      bf16x8 a1 = *(const bf16x8*)&As[w * 32 + 16 + c][kk * 32 + g * 8];
#pragma unroll
      for (int n = 0; n < 4; n++) {
        bf16x8 b = *(const bf16x8*)&Bs[n * 16 + c][kk * 32 + g * 8];
        acc[0][n] = __builtin_amdgcn_mfma_f32_16x16x32_bf16(a0, b, acc[0][n], 0, 0, 0);
        acc[1][n] = __builtin_amdgcn_mfma_f32_16x16x32_bf16(a1, b, acc[1][n], 0, 0, 0);
      }
    }
    __syncthreads();
  }
#pragma unroll
  for (int m = 0; m < 2; m++) {
    int row = w * 32 + m * 16 + 4 * g;                // local row (+r)
#pragma unroll
    for (int n = 0; n < 4; n++) {
      int col = n0 + n * 16 + c;
      float bv = bias[col];
#pragma unroll
      for (int r = 0; r < 4; r++) {
        float v = acc[m][n][r] + bv;
        int lr = row + r;
        if constexpr (MODE == 0) {
          int t = m0 + lr;
          int b = t >> 10, s = t & 1023;
          int which = col / 384;
          int rem = col - which * 384;
          int hd = rem / 48;
          int d = rem - hd * 48;
          size_t bh = (size_t)(b * 8 + hd);
          if (which == 0)      pQ[(bh * 1024 + s) * 48 + d] = (__bf16)v;
          else if (which == 1) pK[(bh * 1024 + s) * 48 + d] = (__bf16)v;
          else                 pV[(bh * 48 + d) * 1024 + s] = (__bf16)v;
        } else if constexpr (MODE == 1) {
          Cf[(size_t)(m0 + lr) * N + col] += v;
        } else if constexpr (MODE == 2) {
          if (m0 + lr < cnt) Cb[(size_t)(base + m0 + lr) * N + col] = (__bf16)fmaxf(v, 0.f);
        } else {
          if (m0 + lr < cnt) {
            int t = tl[m0 + lr];
            float gv = gate_list[e * TOKENS + m0 + lr];
            atomicAdd(&Cf[(size_t)t * DMODEL + col], gv * v);
          }
        }
      }
    }
  }
}

// ---------------- bf16 MFMA flash attention, swapped-QK in-register softmax ----
// grid (bh=128, q0blk=16); 4 waves, wave w owns q rows q0+w*16 .. +15.
// Q/K head-major [bh][s][48]; V pre-transposed [bh][48][s].
__global__ __launch_bounds__(256) void attn_kernel(const __bf16* __restrict__ Qh,
    const __bf16* __restrict__ Kh, const __bf16* __restrict__ VTh,
    __bf16* __restrict__ ao) {
  __shared__ __align__(16) __bf16 Ks[64][56];
  __shared__ __align__(16) __bf16 Vt[48][72];
  __shared__ __align__(16) __bf16 Ps[4][16][72];
  int bh = blockIdx.x;
  int q0 = blockIdx.y * 64;
  int tid = threadIdx.x;
  int w = tid >> 6, lane = tid & 63, c = lane & 15, g = lane >> 4;
  const float scale = 0.14433756729740643f;     // 1/sqrt(48)

  // Q fragments straight from global (B-operand: Q[q=c][k])
  const __bf16* qrow = Qh + ((size_t)bh * 1024 + q0 + w * 16 + c) * 48;
  bf16x8 qb0 = *(const bf16x8*)&qrow[g * 8];
  bf16x8 qb1 = {};
  if (g < 2) qb1 = *(const bf16x8*)&qrow[32 + g * 8];

  f32x4 acc[3];
#pragma unroll
  for (int t = 0; t < 3; t++) { acc[t][0] = 0.f; acc[t][1] = 0.f; acc[t][2] = 0.f; acc[t][3] = 0.f; }
  float m = -INFINITY, l = 0.f;

  const __bf16* kb = Kh + (size_t)bh * 1024 * 48;
  const __bf16* vb = VTh + (size_t)bh * 48 * 1024;

  for (int kt = 0; kt < 16; kt++) {
    __syncthreads();
    {   // stage K tile [64][48] and V^T tile [48][64]
      const __bf16* kbase = kb + (size_t)kt * 64 * 48;
      const __bf16* vbase = vb + kt * 64;
      for (int e = tid; e < 768; e += 256) {
        if (e < 384) {
          int row = e / 6, part = e - row * 6;
          *(bf16x8*)&Ks[row][part * 8] = *(const bf16x8*)&kbase[row * 48 + part * 8];
        } else {
          int i = e - 384;
          int d = i >> 3, part = i & 7;
          *(bf16x8*)&Vt[d][part * 8] = *(const bf16x8*)&vbase[(size_t)d * 1024 + part * 8];
        }
      }
    }
    __syncthreads();

    // S^T = K Q^T : lane (c,g) gets S[q=c][kv=f*16+4g+r]
    f32x4 s4[4];
#pragma unroll
    for (int f = 0; f < 4; f++) {
      bf16x8 ka0 = *(const bf16x8*)&Ks[f * 16 + c][g * 8];
      bf16x8 ka1 = {};
      if (g < 2) ka1 = *(const bf16x8*)&Ks[f * 16 + c][32 + g * 8];
      f32x4 z = {};
      z = __builtin_amdgcn_mfma_f32_16x16x32_bf16(ka0, qb0, z, 0, 0, 0);
      s4[f] = __builtin_amdgcn_mfma_f32_16x16x32_bf16(ka1, qb1, z, 0, 0, 0);
    }
    float sv[4][4];
#pragma unroll
    for (int f = 0; f < 4; f++)
#pragma unroll
      for (int r = 0; r < 4; r++) sv[f][r] = s4[f][r] * scale;
    // in-register row max (16 vals) + cross-g reduce (lanes c,c+16,c+32,c+48)
    float tmax = sv[0][0];
#pragma unroll
    for (int f = 0; f < 4; f++)
#pragma unroll
      for (int r = 0; r < 4; r++) tmax = fmaxf(tmax, sv[f][r]);
    tmax = fmaxf(tmax, __shfl_xor(tmax, 16, 64));
    tmax = fmaxf(tmax, __shfl_xor(tmax, 32, 64));
    float mnew = fmaxf(m, tmax);
    float al = __expf(m - mnew);
    m = mnew;
    float p[4][4];
    float ps = 0.f;
#pragma unroll
    for (int f = 0; f < 4; f++)
#pragma unroll
      for (int r = 0; r < 4; r++) { p[f][r] = __expf(sv[f][r] - mnew); ps += p[f][r]; }
    ps += __shfl_xor(ps, 16, 64);
    ps += __shfl_xor(ps, 32, 64);
    l = l * al + ps;
    // rescale acc rows (q = 4g+r needs alpha of lane 4g+r)
#pragma unroll
    for (int r = 0; r < 4; r++) {
      float ar = __shfl(al, 4 * g + r, 64);
      acc[0][r] *= ar; acc[1][r] *= ar; acc[2][r] *= ar;
    }
    // P^T -> per-wave LDS in PV-A layout: Ps[w][q=c][kv]
#pragma unroll
    for (int f = 0; f < 4; f++)
#pragma unroll
      for (int r = 0; r < 4; r++)
        Ps[w][c][f * 16 + 4 * g + r] = (__bf16)p[f][r];
    bf16x8 pa0 = *(const bf16x8*)&Ps[w][c][g * 8];
    bf16x8 pa1 = *(const bf16x8*)&Ps[w][c][32 + g * 8];
    // O += P V : B-operand = V^T[dh=c][kv=k] (Vt natural rows)
#pragma unroll
    for (int t = 0; t < 3; t++) {
      bf16x8 vb0 = *(const bf16x8*)&Vt[t * 16 + c][g * 8];
      bf16x8 vb1 = *(const bf16x8*)&Vt[t * 16 + c][32 + g * 8];
      acc[t] = __builtin_amdgcn_mfma_f32_16x16x32_bf16(pa0, vb0, acc[t], 0, 0, 0);
      acc[t] = __builtin_amdgcn_mfma_f32_16x16x32_bf16(pa1, vb1, acc[t], 0, 0, 0);
    }
  }
  float linv[4];
#pragma unroll
  for (int r = 0; r < 4; r++) linv[r] = 1.f / __shfl(l, 4 * g + r, 64);
  int b = bh >> 3, hh = bh & 7;
#pragma unroll
  for (int t = 0; t < 3; t++)
#pragma unroll
    for (int r = 0; r < 4; r++)
      ao[((size_t)(b * SEQ + q0 + w * 16 + 4 * g + r)) * DMODEL + hh * 48 + t * 16 + c] =
          (__bf16)(acc[t][r] * linv[r]);
}

// ---------------- gating: block = 256 tokens, block-aggregated atomics ----------------
__global__ __launch_bounds__(256) void gate_kernel(const __bf16* __restrict__ xnb,
    const float* __restrict__ gw, int* __restrict__ counts, float* __restrict__ sum_probs,
    int* __restrict__ tok_list, float* __restrict__ gate_list) {
  __shared__ float Gs[NEXP][DMODEL];
  __shared__ float simp[NEXP];
  __shared__ int hist[NEXP], basep[NEXP];
  __shared__ unsigned char tokE[256][2];
  __shared__ float tokG[256][2];
  __shared__ short rankS[256][2];
  int tid = threadIdx.x;
  for (int i = tid; i < DMODEL * NEXP; i += 256) {
    int d = i >> 3, e2 = i & 7;
    Gs[e2][d] = gw[i];
  }
  if (tid < NEXP) { simp[tid] = 0.f; hist[tid] = 0; }
  __syncthreads();
  int w = tid >> 6, lane = tid & 63;
  int tbase = blockIdx.x * 256 + w * 64;
  float impacc[NEXP] = {};
  for (int tt = 0; tt < 64; tt++) {
    int t = tbase + tt;
    float p[NEXP] = {};
#pragma unroll
    for (int j = 0; j < 6; j++) {
      int d = lane + 64 * j;
      float xv = (float)xnb[(size_t)t * DMODEL + d];
#pragma unroll
      for (int e2 = 0; e2 < NEXP; e2++) p[e2] += xv * Gs[e2][d];
    }
#pragma unroll
    for (int off = 32; off; off >>= 1)
#pragma unroll
      for (int e2 = 0; e2 < NEXP; e2++) p[e2] += __shfl_xor(p[e2], off);
    float mx = p[0];
#pragma unroll
    for (int e2 = 1; e2 < NEXP; e2++) mx = fmaxf(mx, p[e2]);
    float s = 0.f;
#pragma unroll
    for (int e2 = 0; e2 < NEXP; e2++) { p[e2] = __expf(p[e2] - mx); s += p[e2]; }
    float inv = 1.f / s;
#pragma unroll
    for (int e2 = 0; e2 < NEXP; e2++) { p[e2] *= inv; impacc[e2] += p[e2]; }
    int i0 = 0; float v0 = p[0];
#pragma unroll
    for (int e2 = 1; e2 < NEXP; e2++) if (p[e2] > v0) { v0 = p[e2]; i0 = e2; }
    int i1 = -1; float v1 = -INFINITY;
#pragma unroll
    for (int e2 = 0; e2 < NEXP; e2++) if (e2 != i0 && p[e2] > v1) { v1 = p[e2]; i1 = e2; }
    if (lane == 0) {
      float gsum = v0 + v1;
      int r0 = atomicAdd(&hist[i0], 1);
      int r1 = atomicAdd(&hist[i1], 1);
      int sl = w * 64 + tt;
      tokE[sl][0] = (unsigned char)i0; tokE[sl][1] = (unsigned char)i1;
      tokG[sl][0] = v0 / gsum;         tokG[sl][1] = v1 / gsum;
      rankS[sl][0] = (short)r0;        rankS[sl][1] = (short)r1;
    }
  }
  if (lane == 0)
#pragma unroll
    for (int e2 = 0; e2 < NEXP; e2++) atomicAdd(&simp[e2], impacc[e2]);
  __syncthreads();
  if (tid < NEXP) {
    basep[tid] = atomicAdd(&counts[tid], hist[tid]);
    atomicAdd(&sum_probs[tid], simp[tid]);
  }
  __syncthreads();
  int t0 = blockIdx.x * 256;
  for (int i = tid; i < 512; i += 256) {
    int sl = i >> 1, a = i & 1;
    int e2 = tokE[sl][a];
    int pos = basep[e2] + rankS[sl][a];
    tok_list[e2 * TOKENS + pos] = t0 + sl;
    gate_list[e2 * TOKENS + pos] = tokG[sl][a];
  }
}

// prefix offsets (64-padded) + aux loss contribution
__global__ void aux_kernel(const int* __restrict__ counts, int* __restrict__ offs,
                           const float* __restrict__ sum_probs, float* __restrict__ total_moe) {
  int off = 0;
  float tm = 0.f;
  for (int e = 0; e < NEXP; e++) {
    offs[e] = off;
    off += ((counts[e] + 63) >> 6) << 6;
    tm += sum_probs[e] * (float)counts[e];
  }
  offs[NEXP] = off;
  *total_moe += (float)NEXP * tm / ((float)TOKENS * (float)TOKENS);
}

// ---------------- attention-pool head: one block per batch ----------------
__global__ __launch_bounds__(256) void head_kernel(const float* __restrict__ h,
    const float* __restrict__ att_w, const float* __restrict__ att_b,
    const float* __restrict__ head_w, const float* __restrict__ head_b,
    float* __restrict__ out) {
  int b = blockIdx.x, tid = threadIdx.x;
  int w = tid >> 6, lane = tid & 63;
  __shared__ float wl[SEQ];
  __shared__ float red[4];
  __shared__ float pooled[DMODEL];
  const float* hb = h + (size_t)b * SEQ * DMODEL;
  float ab = att_b[0];
  // pass 1: logits, wave-per-row (coalesced within row)
  float4 aw0 = *(const float4*)&att_w[lane * 4];
  float2 aw1 = *(const float2*)&att_w[256 + lane * 2];
  for (int s = w; s < SEQ; s += 4) {
    const float* hr = hb + (size_t)s * DMODEL;
    float4 v4 = *(const float4*)&hr[lane * 4];
    float2 v2 = *(const float2*)&hr[256 + lane * 2];
    float dot = v4.x * aw0.x + v4.y * aw0.y + v4.z * aw0.z + v4.w * aw0.w
              + v2.x * aw1.x + v2.y * aw1.y;
#pragma unroll
    for (int off = 32; off; off >>= 1) dot += __shfl_xor(dot, off);
    if (lane == 0) wl[s] = dot + ab;
  }
  __syncthreads();
  float lmax = -INFINITY;
  for (int s = tid; s < SEQ; s += 256) lmax = fmaxf(lmax, wl[s]);
#pragma unroll
  for (int off = 32; off; off >>= 1) lmax = fmaxf(lmax, __shfl_xor(lmax, off));
  if (lane == 0) red[w] = lmax;
  __syncthreads();
  lmax = fmaxf(fmaxf(red[0], red[1]), fmaxf(red[2], red[3]));
  __syncthreads();
  float ls = 0.f;
  for (int s = tid; s < SEQ; s += 256) { float p = __expf(wl[s] - lmax); wl[s] = p; ls += p; }
#pragma unroll
  for (int off = 32; off; off >>= 1) ls += __shfl_xor(ls, off);
  if (lane == 0) red[w] = ls;
  __syncthreads();
  float invs = 1.f / (red[0] + red[1] + red[2] + red[3]);
  for (int d = tid; d < DMODEL; d += 256) {
    float acc = 0.f;
    for (int s = 0; s < SEQ; s++) acc += wl[s] * hb[(size_t)s * DMODEL + d];
    pooled[d] = acc * invs;
  }
  __syncthreads();
  float part = 0.f;
  for (int d = tid; d < DMODEL; d += 256) part += pooled[d] * head_w[d];
#pragma unroll
  for (int off = 32; off; off >>= 1) part += __shfl_xor(part, off);
  __syncthreads();
  if ((tid & 63) == 0) red[w] = part;
  __syncthreads();
  if (tid == 0) out[b] = red[0] + red[1] + red[2] + red[3] + head_b[0];
}

// ---------------- launch ----------------
extern "C" void kernel_launch(void* const* d_in, const int* in_sizes, int n_in,
                              void* d_out, int out_size, void* d_ws, size_t ws_size,
                              hipStream_t stream) {
  (void)in_sizes; (void)n_in; (void)out_size; (void)ws_size;
  const float* x      = (const float*)d_in[0];
  const float* proj_w = (const float*)d_in[1];
  const float* proj_b = (const float*)d_in[2];
  const float* qkv_w  = (const float*)d_in[3];
  const float* qkv_b  = (const float*)d_in[4];
  const float* out_w  = (const float*)d_in[5];
  const float* out_b  = (const float*)d_in[6];
  const float* n1_s   = (const float*)d_in[7];
  const float* n1_b   = (const float*)d_in[8];
  const float* n2_s   = (const float*)d_in[9];
  const float* n2_b   = (const float*)d_in[10];
  const float* gate_w = (const float*)d_in[11];
  const float* e_w1   = (const float*)d_in[12];
  const float* e_b1   = (const float*)d_in[13];
  const float* e_w2   = (const float*)d_in[14];
  const float* e_b2   = (const float*)d_in[15];
  const float* att_w  = (const float*)d_in[16];
  const float* att_b  = (const float*)d_in[17];
  const float* head_w = (const float*)d_in[18];
  const float* head_b = (const float*)d_in[19];
  float* out = (float*)d_out;

  // workspace layout (bytes):
  // h fp32 25.2MB | xnb bf16 12.6MB | aob bf16 12.6MB
  // | uni region 51.1MB: {Qh 12.6 | Kh 12.6 | VTh 12.6} during attn, a1b during MoE
  // | Wt bf16 31.9MB | control
  char* wsb = (char*)d_ws;
  float*  h    = (float*)(wsb);
  __bf16* xnb  = (__bf16*)(wsb + 25165824);
  __bf16* aob  = (__bf16*)(wsb + 37748736);
  __bf16* uni  = (__bf16*)(wsb + 50331648);
  __bf16* Qh   = uni;                              // [128][1024][48] = 12,582,912 B
  __bf16* Khd  = (__bf16*)(wsb + 62914560);        // 50331648 + 12582912
  __bf16* VTh  = (__bf16*)(wsb + 75497472);        // + 2*12582912
  __bf16* qkvWt = (__bf16*)(wsb + 101449728);   // [3][1152][384]
  __bf16* outWt = (__bf16*)(wsb + 104103936);   // [3][384][384]
  __bf16* e1Wt  = (__bf16*)(wsb + 104988672);   // [3*8][768][384]
  __bf16* e2Wt  = (__bf16*)(wsb + 119144448);   // [3*8][384][768]
  char* sm = wsb + 133300224;
  int*   counts    = (int*)(sm);
  int*   offs      = (int*)(sm + 64);
  float* sum_probs = (float*)(sm + 128);
  float* total_moe = (float*)(sm + 192);
  int*   tok_list  = (int*)(sm + 256);
  float* gate_list = (float*)(sm + 256 + 524288);

  // one-shot weight transpose+cast (runs every call; deterministic)
  convw_kernel<<<dim3(36, 12, 3), 256, 0, stream>>>(qkv_w, qkvWt, 384, 1152);
  convw_kernel<<<dim3(12, 12, 3), 256, 0, stream>>>(out_w, outWt, 384, 384);
  convw_kernel<<<dim3(24, 12, 24), 256, 0, stream>>>(e_w1, e1Wt, 384, 768);
  convw_kernel<<<dim3(12, 24, 24), 256, 0, stream>>>(e_w2, e2Wt, 768, 384);

  init_kernel<<<1, 1, 0, stream>>>(total_moe);
  proj_kernel<<<TOKENS * DMODEL / 256, 256, 0, stream>>>(x, proj_w, proj_b, h);

  for (int l = 0; l < NL; l++) {
    ln_kernel<<<TOKENS, 384, 0, stream>>>(h, xnb, n1_s + l * DMODEL, n1_b + l * DMODEL);
    mgemm_kernel<0><<<dim3(18, 128), 256, 0, stream>>>(
        xnb, qkvWt + (size_t)l * 1152 * 384, qkv_b + l * 1152, nullptr, nullptr,
        Qh, Khd, VTh, nullptr, nullptr, nullptr, nullptr, 1152, 384);
    attn_kernel<<<dim3(128, 16), 256, 0, stream>>>(Qh, Khd, VTh, aob);
    mgemm_kernel<1><<<dim3(6, 128), 256, 0, stream>>>(
        aob, outWt + (size_t)l * 384 * 384, out_b + l * 384, h, nullptr,
        nullptr, nullptr, nullptr, nullptr, nullptr, nullptr, nullptr, 384, 384);
    ln_kernel<<<TOKENS, 384, 0, stream>>>(h, xnb, n2_s + l * DMODEL, n2_b + l * DMODEL);
    zero_cnt_kernel<<<1, 64, 0, stream>>>(counts, sum_probs);
    gate_kernel<<<64, 256, 0, stream>>>(xnb, gate_w + (size_t)l * DMODEL * NEXP,
                                        counts, sum_probs, tok_list, gate_list);
    aux_kernel<<<1, 1, 0, stream>>>(counts, offs, sum_probs, total_moe);
    mgemm_kernel<2><<<dim3(12, 128, 8), 256, 0, stream>>>(
        xnb, e1Wt + (size_t)l * 8 * 768 * 384, e_b1 + l * 8 * FFDIM, nullptr, uni,
        nullptr, nullptr, nullptr, counts, offs, tok_list, nullptr, 768, 384);
    mgemm_kernel<3><<<dim3(6, 128, 8), 256, 0, stream>>>(
        uni, e2Wt + (size_t)l * 8 * 384 * 768, e_b2 + l * 8 * DMODEL, h, nullptr,
        nullptr, nullptr, nullptr, counts, offs, tok_list, gate_list, 384, 768);
  }

  head_kernel<<<16, 256, 0, stream>>>(h, att_w, att_b, head_w, head_b, out);
  finalize_kernel<<<1, 1, 0, stream>>>(total_moe, out);
}

// Round 6
// 1576.000 us; speedup vs baseline: 4.7078x; 1.0187x over previous
//
#include <hip/hip_runtime.h>
#include <hip/hip_bf16.h>
#include <math.h>

// RULPredictionModel: B=16 S=1024 D=384 H=8 DH=48 L=3 E=8 FF=768 TOP_K=2
#define TOKENS 16384
#define DMODEL 384
#define SEQ 1024
#define NHEAD 8
#define DHEAD 48
#define NEXP 8
#define FFDIM 768
#define NL 3

typedef __bf16 bf16x8 __attribute__((ext_vector_type(8)));
typedef __bf16 bf16x4 __attribute__((ext_vector_type(4)));
typedef float f32x4 __attribute__((ext_vector_type(4)));

// ---------------- tiny kernels ----------------
__global__ void init_kernel(float* total_moe) { *total_moe = 0.f; }

__global__ void zero_cnt_kernel(int* counts, float* sum_probs) {
  int t = threadIdx.x;
  if (t < NEXP) { counts[t] = 0; sum_probs[t] = 0.f; }
}

__global__ void finalize_kernel(const float* total_moe, float* out) { out[16] = *total_moe; }

__global__ __launch_bounds__(256) void proj_kernel(const float* __restrict__ x,
    const float* __restrict__ pw, const float* __restrict__ pb, float* __restrict__ h) {
  int i = blockIdx.x * 256 + threadIdx.x;
  int t = i / DMODEL;
  int d = i - t * DMODEL;
  h[i] = x[t] * pw[d] + pb[d];
}

// weight transpose + cast: src fp32 [K][N] (batched) -> dst bf16 [N][K]
__global__ __launch_bounds__(256) void convw_kernel(const float* __restrict__ src,
    __bf16* __restrict__ dst, int K, int N) {
  __shared__ float t[32][33];
  size_t boff = (size_t)blockIdx.z * K * N;
  src += boff; dst += boff;
  int k0 = blockIdx.y * 32, n0 = blockIdx.x * 32;
  int tx = threadIdx.x & 31, ty = threadIdx.x >> 5;   // 32 x 8
#pragma unroll
  for (int i = 0; i < 32; i += 8) t[ty + i][tx] = src[(size_t)(k0 + ty + i) * N + n0 + tx];
  __syncthreads();
#pragma unroll
  for (int i = 0; i < 32; i += 8)
    dst[(size_t)(n0 + ty + i) * K + k0 + tx] = (__bf16)t[tx][ty + i];
}

// one block (384 threads) per row; bf16 output
__global__ __launch_bounds__(384) void ln_kernel(const float* __restrict__ src,
    __bf16* __restrict__ dst, const float* __restrict__ gs, const float* __restrict__ gb) {
  int row = blockIdx.x, tid = threadIdx.x;
  float v = src[(size_t)row * DMODEL + tid];
  float sum = v, sq = v * v;
#pragma unroll
  for (int off = 32; off; off >>= 1) { sum += __shfl_xor(sum, off); sq += __shfl_xor(sq, off); }
  __shared__ float rs[6], rq[6];
  __shared__ float smean, sinv;
  int wid = tid >> 6;
  if ((tid & 63) == 0) { rs[wid] = sum; rq[wid] = sq; }
  __syncthreads();
  if (tid == 0) {
    float S = 0.f, Q = 0.f;
    for (int w = 0; w < 6; w++) { S += rs[w]; Q += rq[w]; }
    float mean = S / (float)DMODEL;
    float var = Q / (float)DMODEL - mean * mean;
    smean = mean; sinv = rsqrtf(var + 1e-5f);
  }
  __syncthreads();
  dst[(size_t)row * DMODEL + tid] = (__bf16)((v - smean) * sinv * gs[tid] + gb[tid]);
}

// ---------------- bf16 MFMA GEMM: C = A @ Wt^T + bias, tile 128x128x64 ----------------
// MODE 0: qkv   (A=xnb, writes head-major Qh/Kh + transposed VTh)
// MODE 1: out   (A=aob,  Cf += acc+bias)   [residual]
// MODE 2: moe1  (A=gather(xnb) via tok_list, relu, out bf16 a1)
// MODE 3: moe2  (A=a1b rows base+m, atomicAdd gate*(acc+bias) into Cf)
template<int MODE>
__global__ __launch_bounds__(256) void mgemm_kernel(
    const __bf16* __restrict__ Abf, const __bf16* __restrict__ Wt,
    const float* __restrict__ bias, float* __restrict__ Cf, __bf16* __restrict__ Cb,
    __bf16* __restrict__ pQ, __bf16* __restrict__ pK, __bf16* __restrict__ pV,
    const int* __restrict__ counts, const int* __restrict__ offs,
    const int* __restrict__ tok_list, const float* __restrict__ gate_list,
    int N, int K) {
  int e = 0, cnt = 0, base = 0;
  const int* tl = nullptr;
  int m0 = blockIdx.y * 128;
  if constexpr (MODE == 2 || MODE == 3) {
    e = blockIdx.z;
    cnt = counts[e];
    if (m0 >= cnt) return;
    base = offs[e];
    tl = tok_list + e * TOKENS;
    Wt += (size_t)e * N * K;
    bias += (size_t)e * N;
  }
  __shared__ __align__(16) __bf16 As[128][72];
  __shared__ __align__(16) __bf16 Bs[128][72];
  int tid = threadIdx.x;
  int n0 = blockIdx.x * 128;
  int w = tid >> 6, lane = tid & 63, c = lane & 15, g = lane >> 4;
  int arow[4], acol[4];
  long tok[4];
#pragma unroll
  for (int i = 0; i < 4; i++) {
    int chunk = tid + 256 * i;
    arow[i] = chunk >> 3;
    acol[i] = (chunk & 7) * 8;
    int mr = m0 + arow[i];
    if constexpr (MODE == 2)      tok[i] = (mr < cnt) ? (long)tl[mr] : -1;
    else if constexpr (MODE == 3) tok[i] = (mr < cnt) ? (long)(base + mr) : -1;
    else                          tok[i] = mr;
  }
  f32x4 acc[2][8];
#pragma unroll
  for (int m = 0; m < 2; m++)
#pragma unroll
    for (int n = 0; n < 8; n++) { acc[m][n][0] = 0.f; acc[m][n][1] = 0.f; acc[m][n][2] = 0.f; acc[m][n][3] = 0.f; }

  for (int k0 = 0; k0 < K; k0 += 64) {
#pragma unroll
    for (int i = 0; i < 4; i++) {
      bf16x8 v = {};
      if (tok[i] >= 0) v = *(const bf16x8*)&Abf[(size_t)tok[i] * K + k0 + acol[i]];
      *(bf16x8*)&As[arow[i]][acol[i]] = v;
    }
#pragma unroll
    for (int i = 0; i < 4; i++) {
      int chunk = tid + 256 * i;
      int br = chunk >> 3, bc = (chunk & 7) * 8;
      *(bf16x8*)&Bs[br][bc] = *(const bf16x8*)&Wt[(size_t)(n0 + br) * K + k0 + bc];
    }
    __syncthreads();
#pragma unroll
    for (int kk = 0; kk < 2; kk++) {
      bf16x8 a0 = *(const bf16x8*)&As[w * 32 + c][kk * 32 + g * 8];
      bf16x8 a1 = *(const bf16x8*)&As[w * 32 + 16 + c][kk * 32 + g * 8];
#pragma unroll
      for (int n = 0; n < 8; n++) {
        bf16x8 b = *(const bf16x8*)&Bs[n * 16 + c][kk * 32 + g * 8];
        acc[0][n] = __builtin_amdgcn_mfma_f32_16x16x32_bf16(a0, b, acc[0][n], 0, 0, 0);
        acc[1][n] = __builtin_amdgcn_mfma_f32_16x16x32_bf16(a1, b, acc[1][n], 0, 0, 0);
      }
    }
    __syncthreads();
  }
#pragma unroll
  for (int m = 0; m < 2; m++) {
    int row = w * 32 + m * 16 + 4 * g;                // local row (+r)
#pragma unroll
    for (int n = 0; n < 8; n++) {
      int col = n0 + n * 16 + c;
      float bv = bias[col];
#pragma unroll
      for (int r = 0; r < 4; r++) {
        float v = acc[m][n][r] + bv;
        int lr = row + r;
        if constexpr (MODE == 0) {
          int t = m0 + lr;
          int b = t >> 10, s = t & 1023;
          int which = col / 384;
          int rem = col - which * 384;
          int hd = rem / 48;
          int d = rem - hd * 48;
          size_t bh = (size_t)(b * 8 + hd);
          if (which == 0)      pQ[(bh * 1024 + s) * 48 + d] = (__bf16)v;
          else if (which == 1) pK[(bh * 1024 + s) * 48 + d] = (__bf16)v;
          else                 pV[(bh * 48 + d) * 1024 + s] = (__bf16)v;
        } else if constexpr (MODE == 1) {
          Cf[(size_t)(m0 + lr) * N + col] += v;
        } else if constexpr (MODE == 2) {
          if (m0 + lr < cnt) Cb[(size_t)(base + m0 + lr) * N + col] = (__bf16)fmaxf(v, 0.f);
        } else {
          if (m0 + lr < cnt) {
            int t = tl[m0 + lr];
            float gv = gate_list[e * TOKENS + m0 + lr];
            atomicAdd(&Cf[(size_t)t * DMODEL + col], gv * v);
          }
        }
      }
    }
  }
}

// ---------------- bf16 MFMA flash attention, swapped-QK in-register softmax ----
// grid (bh=128, q0blk=16); 4 waves, wave w owns q rows q0+w*16 .. +15.
// Q/K head-major [bh][s][48]; V pre-transposed [bh][48][s].
__global__ __launch_bounds__(256) void attn_kernel(const __bf16* __restrict__ Qh,
    const __bf16* __restrict__ Kh, const __bf16* __restrict__ VTh,
    __bf16* __restrict__ ao) {
  __shared__ __align__(16) __bf16 Ks[64][56];
  __shared__ __align__(16) __bf16 Vt[48][72];
  __shared__ __align__(16) __bf16 Ps[4][16][72];
  int bh = blockIdx.x;
  int q0 = blockIdx.y * 64;
  int tid = threadIdx.x;
  int w = tid >> 6, lane = tid & 63, c = lane & 15, g = lane >> 4;
  const float scale = 0.14433756729740643f;     // 1/sqrt(48)

  // Q fragments straight from global (B-operand: Q[q=c][k])
  const __bf16* qrow = Qh + ((size_t)bh * 1024 + q0 + w * 16 + c) * 48;
  bf16x8 qb0 = *(const bf16x8*)&qrow[g * 8];
  bf16x8 qb1 = {};
  if (g < 2) qb1 = *(const bf16x8*)&qrow[32 + g * 8];

  f32x4 acc[3];
#pragma unroll
  for (int t = 0; t < 3; t++) { acc[t][0] = 0.f; acc[t][1] = 0.f; acc[t][2] = 0.f; acc[t][3] = 0.f; }
  float m = -INFINITY, l = 0.f;

  const __bf16* kb = Kh + (size_t)bh * 1024 * 48;
  const __bf16* vb = VTh + (size_t)bh * 48 * 1024;

  for (int kt = 0; kt < 16; kt++) {
    __syncthreads();
    {   // stage K tile [64][48] and V^T tile [48][64]
      const __bf16* kbase = kb + (size_t)kt * 64 * 48;
      const __bf16* vbase = vb + kt * 64;
      for (int e = tid; e < 768; e += 256) {
        if (e < 384) {
          int row = e / 6, part = e - row * 6;
          *(bf16x8*)&Ks[row][part * 8] = *(const bf16x8*)&kbase[row * 48 + part * 8];
        } else {
          int i = e - 384;
          int d = i >> 3, part = i & 7;
          *(bf16x8*)&Vt[d][part * 8] = *(const bf16x8*)&vbase[(size_t)d * 1024 + part * 8];
        }
      }
    }
    __syncthreads();

    // S^T = K Q^T : lane (c,g) gets S[q=c][kv=f*16+4g+r]
    f32x4 s4[4];
#pragma unroll
    for (int f = 0; f < 4; f++) {
      bf16x8 ka0 = *(const bf16x8*)&Ks[f * 16 + c][g * 8];
      bf16x8 ka1 = {};
      if (g < 2) ka1 = *(const bf16x8*)&Ks[f * 16 + c][32 + g * 8];
      f32x4 z = {};
      z = __builtin_amdgcn_mfma_f32_16x16x32_bf16(ka0, qb0, z, 0, 0, 0);
      s4[f] = __builtin_amdgcn_mfma_f32_16x16x32_bf16(ka1, qb1, z, 0, 0, 0);
    }
    float sv[4][4];
#pragma unroll
    for (int f = 0; f < 4; f++)
#pragma unroll
      for (int r = 0; r < 4; r++) sv[f][r] = s4[f][r] * scale;
    // in-register row max (16 vals) + cross-g reduce (lanes c,c+16,c+32,c+48)
    float tmax = sv[0][0];
#pragma unroll
    for (int f = 0; f < 4; f++)
#pragma unroll
      for (int r = 0; r < 4; r++) tmax = fmaxf(tmax, sv[f][r]);
    tmax = fmaxf(tmax, __shfl_xor(tmax, 16, 64));
    tmax = fmaxf(tmax, __shfl_xor(tmax, 32, 64));
    float mnew = fmaxf(m, tmax);
    float al = __expf(m - mnew);
    m = mnew;
    float p[4][4];
    float ps = 0.f;
#pragma unroll
    for (int f = 0; f < 4; f++)
#pragma unroll
      for (int r = 0; r < 4; r++) { p[f][r] = __expf(sv[f][r] - mnew); ps += p[f][r]; }
    ps += __shfl_xor(ps, 16, 64);
    ps += __shfl_xor(ps, 32, 64);
    l = l * al + ps;
    // rescale acc rows (q = 4g+r needs alpha of lane 4g+r)
#pragma unroll
    for (int r = 0; r < 4; r++) {
      float ar = __shfl(al, 4 * g + r, 64);
      acc[0][r] *= ar; acc[1][r] *= ar; acc[2][r] *= ar;
    }
    // P^T -> per-wave LDS in PV-A layout: Ps[w][q=c][kv]
#pragma unroll
    for (int f = 0; f < 4; f++)
#pragma unroll
      for (int r = 0; r < 4; r++)
        Ps[w][c][f * 16 + 4 * g + r] = (__bf16)p[f][r];
    bf16x8 pa0 = *(const bf16x8*)&Ps[w][c][g * 8];
    bf16x8 pa1 = *(const bf16x8*)&Ps[w][c][32 + g * 8];
    // O += P V : B-operand = V^T[dh=c][kv=k] (Vt natural rows)
#pragma unroll
    for (int t = 0; t < 3; t++) {
      bf16x8 vb0 = *(const bf16x8*)&Vt[t * 16 + c][g * 8];
      bf16x8 vb1 = *(const bf16x8*)&Vt[t * 16 + c][32 + g * 8];
      acc[t] = __builtin_amdgcn_mfma_f32_16x16x32_bf16(pa0, vb0, acc[t], 0, 0, 0);
      acc[t] = __builtin_amdgcn_mfma_f32_16x16x32_bf16(pa1, vb1, acc[t], 0, 0, 0);
    }
  }
  float linv[4];
#pragma unroll
  for (int r = 0; r < 4; r++) linv[r] = 1.f / __shfl(l, 4 * g + r, 64);
  int b = bh >> 3, hh = bh & 7;
#pragma unroll
  for (int t = 0; t < 3; t++)
#pragma unroll
    for (int r = 0; r < 4; r++)
      ao[((size_t)(b * SEQ + q0 + w * 16 + 4 * g + r)) * DMODEL + hh * 48 + t * 16 + c] =
          (__bf16)(acc[t][r] * linv[r]);
}

// ---------------- gating: block = 256 tokens, block-aggregated atomics ----------------
__global__ __launch_bounds__(256) void gate_kernel(const __bf16* __restrict__ xnb,
    const float* __restrict__ gw, int* __restrict__ counts, float* __restrict__ sum_probs,
    int* __restrict__ tok_list, float* __restrict__ gate_list) {
  __shared__ float Gs[NEXP][DMODEL];
  __shared__ float simp[NEXP];
  __shared__ int hist[NEXP], basep[NEXP];
  __shared__ unsigned char tokE[256][2];
  __shared__ float tokG[256][2];
  __shared__ short rankS[256][2];
  int tid = threadIdx.x;
  for (int i = tid; i < DMODEL * NEXP; i += 256) {
    int d = i >> 3, e2 = i & 7;
    Gs[e2][d] = gw[i];
  }
  if (tid < NEXP) { simp[tid] = 0.f; hist[tid] = 0; }
  __syncthreads();
  int w = tid >> 6, lane = tid & 63;
  int tbase = blockIdx.x * 256 + w * 64;
  float impacc[NEXP] = {};
  for (int tt = 0; tt < 64; tt++) {
    int t = tbase + tt;
    float p[NEXP] = {};
#pragma unroll
    for (int j = 0; j < 6; j++) {
      int d = lane + 64 * j;
      float xv = (float)xnb[(size_t)t * DMODEL + d];
#pragma unroll
      for (int e2 = 0; e2 < NEXP; e2++) p[e2] += xv * Gs[e2][d];
    }
#pragma unroll
    for (int off = 32; off; off >>= 1)
#pragma unroll
      for (int e2 = 0; e2 < NEXP; e2++) p[e2] += __shfl_xor(p[e2], off);
    float mx = p[0];
#pragma unroll
    for (int e2 = 1; e2 < NEXP; e2++) mx = fmaxf(mx, p[e2]);
    float s = 0.f;
#pragma unroll
    for (int e2 = 0; e2 < NEXP; e2++) { p[e2] = __expf(p[e2] - mx); s += p[e2]; }
    float inv = 1.f / s;
#pragma unroll
    for (int e2 = 0; e2 < NEXP; e2++) { p[e2] *= inv; impacc[e2] += p[e2]; }
    int i0 = 0; float v0 = p[0];
#pragma unroll
    for (int e2 = 1; e2 < NEXP; e2++) if (p[e2] > v0) { v0 = p[e2]; i0 = e2; }
    int i1 = -1; float v1 = -INFINITY;
#pragma unroll
    for (int e2 = 0; e2 < NEXP; e2++) if (e2 != i0 && p[e2] > v1) { v1 = p[e2]; i1 = e2; }
    if (lane == 0) {
      float gsum = v0 + v1;
      int r0 = atomicAdd(&hist[i0], 1);
      int r1 = atomicAdd(&hist[i1], 1);
      int sl = w * 64 + tt;
      tokE[sl][0] = (unsigned char)i0; tokE[sl][1] = (unsigned char)i1;
      tokG[sl][0] = v0 / gsum;         tokG[sl][1] = v1 / gsum;
      rankS[sl][0] = (short)r0;        rankS[sl][1] = (short)r1;
    }
  }
  if (lane == 0)
#pragma unroll
    for (int e2 = 0; e2 < NEXP; e2++) atomicAdd(&simp[e2], impacc[e2]);
  __syncthreads();
  if (tid < NEXP) {
    basep[tid] = atomicAdd(&counts[tid], hist[tid]);
    atomicAdd(&sum_probs[tid], simp[tid]);
  }
  __syncthreads();
  int t0 = blockIdx.x * 256;
  for (int i = tid; i < 512; i += 256) {
    int sl = i >> 1, a = i & 1;
    int e2 = tokE[sl][a];
    int pos = basep[e2] + rankS[sl][a];
    tok_list[e2 * TOKENS + pos] = t0 + sl;
    gate_list[e2 * TOKENS + pos] = tokG[sl][a];
  }
}

// prefix offsets (64-padded) + aux loss contribution
__global__ void aux_kernel(const int* __restrict__ counts, int* __restrict__ offs,
                           const float* __restrict__ sum_probs, float* __restrict__ total_moe) {
  int off = 0;
  float tm = 0.f;
  for (int e = 0; e < NEXP; e++) {
    offs[e] = off;
    off += ((counts[e] + 63) >> 6) << 6;
    tm += sum_probs[e] * (float)counts[e];
  }
  offs[NEXP] = off;
  *total_moe += (float)NEXP * tm / ((float)TOKENS * (float)TOKENS);
}

// ---------------- attention-pool head, split for parallelism ----------------
// head1: logits[t] = h[t]·att_w + att_b  (128 blocks, wave-per-row)
__global__ __launch_bounds__(256) void head1_kernel(const float* __restrict__ h,
    const float* __restrict__ att_w, const float* __restrict__ att_b,
    float* __restrict__ logits) {
  int tid = threadIdx.x;
  int w = tid >> 6, lane = tid & 63;
  float4 aw0 = *(const float4*)&att_w[lane * 4];
  float2 aw1 = *(const float2*)&att_w[256 + lane * 2];
  float ab = att_b[0];
  for (int i = w; i < 128; i += 4) {
    int t = blockIdx.x * 128 + i;
    const float* hr = h + (size_t)t * DMODEL;
    float4 v4 = *(const float4*)&hr[lane * 4];
    float2 v2 = *(const float2*)&hr[256 + lane * 2];
    float dot = v4.x * aw0.x + v4.y * aw0.y + v4.z * aw0.z + v4.w * aw0.w
              + v2.x * aw1.x + v2.y * aw1.y;
#pragma unroll
    for (int off = 32; off; off >>= 1) dot += __shfl_xor(dot, off);
    if (lane == 0) logits[t] = dot + ab;
  }
}

// head2: in-place softmax over s per batch (16 blocks)
__global__ __launch_bounds__(256) void head2_kernel(float* __restrict__ logits) {
  int b = blockIdx.x, tid = threadIdx.x;
  int w = tid >> 6, lane = tid & 63;
  float* lb = logits + b * SEQ;
  __shared__ float red[4];
  float lv[4];
  float mx = -INFINITY;
#pragma unroll
  for (int i = 0; i < 4; i++) { lv[i] = lb[tid + 256 * i]; mx = fmaxf(mx, lv[i]); }
#pragma unroll
  for (int off = 32; off; off >>= 1) mx = fmaxf(mx, __shfl_xor(mx, off));
  if (lane == 0) red[w] = mx;
  __syncthreads();
  mx = fmaxf(fmaxf(red[0], red[1]), fmaxf(red[2], red[3]));
  __syncthreads();
  float s = 0.f;
#pragma unroll
  for (int i = 0; i < 4; i++) { lv[i] = __expf(lv[i] - mx); s += lv[i]; }
#pragma unroll
  for (int off = 32; off; off >>= 1) s += __shfl_xor(s, off);
  if (lane == 0) red[w] = s;
  __syncthreads();
  float inv = 1.f / (red[0] + red[1] + red[2] + red[3]);
#pragma unroll
  for (int i = 0; i < 4; i++) lb[tid + 256 * i] = lv[i] * inv;
}

// head3: block (b, dc): pooled 64-col slab + partial dot -> part[b][dc]
__global__ __launch_bounds__(256) void head3_kernel(const float* __restrict__ h,
    const float* __restrict__ wnorm, const float* __restrict__ head_w,
    float* __restrict__ part) {
  int b = blockIdx.x, dc = blockIdx.y;
  int tid = threadIdx.x;
  int d = tid & 63, sg = tid >> 6;
  const float* hb = h + (size_t)b * SEQ * DMODEL + dc * 64 + d;
  const float* wb = wnorm + b * SEQ;
  float acc = 0.f;
  for (int s = sg * 256; s < sg * 256 + 256; s++)
    acc += wb[s] * hb[(size_t)s * DMODEL];
  __shared__ float red[256];
  red[tid] = acc;
  __syncthreads();
  if (sg == 0) {
    float pooled = red[d] + red[64 + d] + red[128 + d] + red[192 + d];
    float pd = pooled * head_w[dc * 64 + d];
#pragma unroll
    for (int off = 32; off; off >>= 1) pd += __shfl_xor(pd, off);
    if (d == 0) part[b * 6 + dc] = pd;
  }
}

// head4: out[b] = sum(part[b][:]) + head_b
__global__ void head4_kernel(const float* __restrict__ part,
                             const float* __restrict__ head_b, float* __restrict__ out) {
  int b = threadIdx.x;
  if (b < 16) {
    float s = head_b[0];
#pragma unroll
    for (int dc = 0; dc < 6; dc++) s += part[b * 6 + dc];
    out[b] = s;
  }
}

// ---------------- launch ----------------
extern "C" void kernel_launch(void* const* d_in, const int* in_sizes, int n_in,
                              void* d_out, int out_size, void* d_ws, size_t ws_size,
                              hipStream_t stream) {
  (void)in_sizes; (void)n_in; (void)out_size; (void)ws_size;
  const float* x      = (const float*)d_in[0];
  const float* proj_w = (const float*)d_in[1];
  const float* proj_b = (const float*)d_in[2];
  const float* qkv_w  = (const float*)d_in[3];
  const float* qkv_b  = (const float*)d_in[4];
  const float* out_w  = (const float*)d_in[5];
  const float* out_b  = (const float*)d_in[6];
  const float* n1_s   = (const float*)d_in[7];
  const float* n1_b   = (const float*)d_in[8];
  const float* n2_s   = (const float*)d_in[9];
  const float* n2_b   = (const float*)d_in[10];
  const float* gate_w = (const float*)d_in[11];
  const float* e_w1   = (const float*)d_in[12];
  const float* e_b1   = (const float*)d_in[13];
  const float* e_w2   = (const float*)d_in[14];
  const float* e_b2   = (const float*)d_in[15];
  const float* att_w  = (const float*)d_in[16];
  const float* att_b  = (const float*)d_in[17];
  const float* head_w = (const float*)d_in[18];
  const float* head_b = (const float*)d_in[19];
  float* out = (float*)d_out;

  // workspace layout (bytes):
  // h fp32 25.2MB | xnb bf16 12.6MB | aob bf16 12.6MB
  // | uni region 51.1MB: {Qh 12.6 | Kh 12.6 | VTh 12.6} during attn, a1b during MoE
  // | Wt bf16 31.9MB | control | logits 64KB | part
  char* wsb = (char*)d_ws;
  float*  h    = (float*)(wsb);
  __bf16* xnb  = (__bf16*)(wsb + 25165824);
  __bf16* aob  = (__bf16*)(wsb + 37748736);
  __bf16* uni  = (__bf16*)(wsb + 50331648);
  __bf16* Qh   = uni;                              // [128][1024][48] = 12,582,912 B
  __bf16* Khd  = (__bf16*)(wsb + 62914560);        // 50331648 + 12582912
  __bf16* VTh  = (__bf16*)(wsb + 75497472);        // + 2*12582912
  __bf16* qkvWt = (__bf16*)(wsb + 101449728);   // [3][1152][384]
  __bf16* outWt = (__bf16*)(wsb + 104103936);   // [3][384][384]
  __bf16* e1Wt  = (__bf16*)(wsb + 104988672);   // [3*8][768][384]
  __bf16* e2Wt  = (__bf16*)(wsb + 119144448);   // [3*8][384][768]
  char* sm = wsb + 133300224;
  int*   counts    = (int*)(sm);
  int*   offs      = (int*)(sm + 64);
  float* sum_probs = (float*)(sm + 128);
  float* total_moe = (float*)(sm + 192);
  int*   tok_list  = (int*)(sm + 256);
  float* gate_list = (float*)(sm + 256 + 524288);
  float* logits    = (float*)(sm + 1048832);
  float* part      = (float*)(sm + 1048832 + 65536);

  // one-shot weight transpose+cast (runs every call; deterministic)
  convw_kernel<<<dim3(36, 12, 3), 256, 0, stream>>>(qkv_w, qkvWt, 384, 1152);
  convw_kernel<<<dim3(12, 12, 3), 256, 0, stream>>>(out_w, outWt, 384, 384);
  convw_kernel<<<dim3(24, 12, 24), 256, 0, stream>>>(e_w1, e1Wt, 384, 768);
  convw_kernel<<<dim3(12, 24, 24), 256, 0, stream>>>(e_w2, e2Wt, 768, 384);

  init_kernel<<<1, 1, 0, stream>>>(total_moe);
  proj_kernel<<<TOKENS * DMODEL / 256, 256, 0, stream>>>(x, proj_w, proj_b, h);

  for (int l = 0; l < NL; l++) {
    ln_kernel<<<TOKENS, 384, 0, stream>>>(h, xnb, n1_s + l * DMODEL, n1_b + l * DMODEL);
    mgemm_kernel<0><<<dim3(9, 128), 256, 0, stream>>>(
        xnb, qkvWt + (size_t)l * 1152 * 384, qkv_b + l * 1152, nullptr, nullptr,
        Qh, Khd, VTh, nullptr, nullptr, nullptr, nullptr, 1152, 384);
    attn_kernel<<<dim3(128, 16), 256, 0, stream>>>(Qh, Khd, VTh, aob);
    mgemm_kernel<1><<<dim3(3, 128), 256, 0, stream>>>(
        aob, outWt + (size_t)l * 384 * 384, out_b + l * 384, h, nullptr,
        nullptr, nullptr, nullptr, nullptr, nullptr, nullptr, nullptr, 384, 384);
    ln_kernel<<<TOKENS, 384, 0, stream>>>(h, xnb, n2_s + l * DMODEL, n2_b + l * DMODEL);
    zero_cnt_kernel<<<1, 64, 0, stream>>>(counts, sum_probs);
    gate_kernel<<<64, 256, 0, stream>>>(xnb, gate_w + (size_t)l * DMODEL * NEXP,
                                        counts, sum_probs, tok_list, gate_list);
    aux_kernel<<<1, 1, 0, stream>>>(counts, offs, sum_probs, total_moe);
    mgemm_kernel<2><<<dim3(6, 128, 8), 256, 0, stream>>>(
        xnb, e1Wt + (size_t)l * 8 * 768 * 384, e_b1 + l * 8 * FFDIM, nullptr, uni,
        nullptr, nullptr, nullptr, counts, offs, tok_list, nullptr, 768, 384);
    mgemm_kernel<3><<<dim3(3, 128, 8), 256, 0, stream>>>(
        uni, e2Wt + (size_t)l * 8 * 384 * 768, e_b2 + l * 8 * DMODEL, h, nullptr,
        nullptr, nullptr, nullptr, counts, offs, tok_list, gate_list, 384, 768);
  }

  head1_kernel<<<128, 256, 0, stream>>>(h, att_w, att_b, logits);
  head2_kernel<<<16, 256, 0, stream>>>(logits);
  head3_kernel<<<dim3(16, 6), 256, 0, stream>>>(h, logits, head_w, part);
  head4_kernel<<<1, 64, 0, stream>>>(part, head_b, out);
  finalize_kernel<<<1, 1, 0, stream>>>(total_moe, out);
}

// Round 7
// 1414.184 us; speedup vs baseline: 5.2465x; 1.1144x over previous
//
#include <hip/hip_runtime.h>
#include <hip/hip_bf16.h>
#include <math.h>

// RULPredictionModel: B=16 S=1024 D=384 H=8 DH=48 L=3 E=8 FF=768 TOP_K=2
#define TOKENS 16384
#define DMODEL 384
#define SEQ 1024
#define NHEAD 8
#define DHEAD 48
#define NEXP 8
#define FFDIM 768
#define NL 3

typedef __bf16 bf16x8 __attribute__((ext_vector_type(8)));
typedef __bf16 bf16x4 __attribute__((ext_vector_type(4)));
typedef float f32x4 __attribute__((ext_vector_type(4)));

// ---------------- tiny kernels ----------------
__global__ void init_kernel(float* total_moe) { *total_moe = 0.f; }

__global__ void zero_cnt_kernel(int* counts, float* sum_probs) {
  int t = threadIdx.x;
  if (t < NEXP) { counts[t] = 0; sum_probs[t] = 0.f; }
}

__global__ void finalize_kernel(const float* total_moe, float* out) { out[16] = *total_moe; }

__global__ __launch_bounds__(256) void proj_kernel(const float* __restrict__ x,
    const float* __restrict__ pw, const float* __restrict__ pb, float* __restrict__ h) {
  int i = blockIdx.x * 256 + threadIdx.x;
  int t = i / DMODEL;
  int d = i - t * DMODEL;
  h[i] = x[t] * pw[d] + pb[d];
}

// weight transpose + cast: src fp32 [K][N] (batched) -> dst bf16 [N][K]
__global__ __launch_bounds__(256) void convw_kernel(const float* __restrict__ src,
    __bf16* __restrict__ dst, int K, int N) {
  __shared__ float t[32][33];
  size_t boff = (size_t)blockIdx.z * K * N;
  src += boff; dst += boff;
  int k0 = blockIdx.y * 32, n0 = blockIdx.x * 32;
  int tx = threadIdx.x & 31, ty = threadIdx.x >> 5;   // 32 x 8
#pragma unroll
  for (int i = 0; i < 32; i += 8) t[ty + i][tx] = src[(size_t)(k0 + ty + i) * N + n0 + tx];
  __syncthreads();
#pragma unroll
  for (int i = 0; i < 32; i += 8)
    dst[(size_t)(n0 + ty + i) * K + k0 + tx] = (__bf16)t[tx][ty + i];
}

// one block (384 threads) per row; bf16 output
__global__ __launch_bounds__(384) void ln_kernel(const float* __restrict__ src,
    __bf16* __restrict__ dst, const float* __restrict__ gs, const float* __restrict__ gb) {
  int row = blockIdx.x, tid = threadIdx.x;
  float v = src[(size_t)row * DMODEL + tid];
  float sum = v, sq = v * v;
#pragma unroll
  for (int off = 32; off; off >>= 1) { sum += __shfl_xor(sum, off); sq += __shfl_xor(sq, off); }
  __shared__ float rs[6], rq[6];
  __shared__ float smean, sinv;
  int wid = tid >> 6;
  if ((tid & 63) == 0) { rs[wid] = sum; rq[wid] = sq; }
  __syncthreads();
  if (tid == 0) {
    float S = 0.f, Q = 0.f;
    for (int w = 0; w < 6; w++) { S += rs[w]; Q += rq[w]; }
    float mean = S / (float)DMODEL;
    float var = Q / (float)DMODEL - mean * mean;
    smean = mean; sinv = rsqrtf(var + 1e-5f);
  }
  __syncthreads();
  dst[(size_t)row * DMODEL + tid] = (__bf16)((v - smean) * sinv * gs[tid] + gb[tid]);
}

// ---------------- bf16 MFMA GEMM: C = A @ Wt^T + bias, tile 128x128x64 ----------------
// async-split staging: k-step t+1 global loads issued while computing t.
// MODE 0: qkv   (A=xnb, writes head-major Qh/Kh + transposed VTh)
// MODE 1: out   (A=aob,  Cf += acc+bias)   [residual]
// MODE 2: moe1  (A=gather(xnb) via tok_list&0xFFFF, relu, out bf16 a1)
// MODE 3: moe2  (A=a1b rows base+m, store gate*(acc+bias) to ab[a][t] bf16)
template<int MODE>
__global__ __launch_bounds__(256) void mgemm_kernel(
    const __bf16* __restrict__ Abf, const __bf16* __restrict__ Wt,
    const float* __restrict__ bias, float* __restrict__ Cf, __bf16* __restrict__ Cb,
    __bf16* __restrict__ pQ, __bf16* __restrict__ pK, __bf16* __restrict__ pV,
    const int* __restrict__ counts, const int* __restrict__ offs,
    const int* __restrict__ tok_list, const float* __restrict__ gate_list,
    int N, int K) {
  int e = 0, cnt = 0, base = 0;
  const int* tl = nullptr;
  int m0 = blockIdx.y * 128;
  if constexpr (MODE == 2 || MODE == 3) {
    e = blockIdx.z;
    cnt = counts[e];
    if (m0 >= cnt) return;
    base = offs[e];
    tl = tok_list + e * TOKENS;
    Wt += (size_t)e * N * K;
    bias += (size_t)e * N;
  }
  __shared__ __align__(16) __bf16 As[128][72];
  __shared__ __align__(16) __bf16 Bs[128][72];
  int tid = threadIdx.x;
  int n0 = blockIdx.x * 128;
  int w = tid >> 6, lane = tid & 63, c = lane & 15, g = lane >> 4;
  int arow[4], acol[4], brow[4], bcol4[4];
  long tok[4];
#pragma unroll
  for (int i = 0; i < 4; i++) {
    int chunk = tid + 256 * i;
    arow[i] = chunk >> 3;
    acol[i] = (chunk & 7) * 8;
    brow[i] = chunk >> 3;
    bcol4[i] = (chunk & 7) * 8;
    int mr = m0 + arow[i];
    if constexpr (MODE == 2)      tok[i] = (mr < cnt) ? (long)(tl[mr] & 0xFFFF) : -1;
    else if constexpr (MODE == 3) tok[i] = (mr < cnt) ? (long)(base + mr) : -1;
    else                          tok[i] = mr;
  }
  f32x4 acc[2][8];
#pragma unroll
  for (int m = 0; m < 2; m++)
#pragma unroll
    for (int n = 0; n < 8; n++) { acc[m][n][0] = 0.f; acc[m][n][1] = 0.f; acc[m][n][2] = 0.f; acc[m][n][3] = 0.f; }

  bf16x8 ra[4], rb[4];
  int nk = K >> 6;
  // prologue: load k-step 0 into regs
#pragma unroll
  for (int i = 0; i < 4; i++) {
    bf16x8 v = {};
    if (tok[i] >= 0) v = *(const bf16x8*)&Abf[(size_t)tok[i] * K + acol[i]];
    ra[i] = v;
    rb[i] = *(const bf16x8*)&Wt[(size_t)(n0 + brow[i]) * K + bcol4[i]];
  }
  for (int kt = 0; kt < nk; kt++) {
    // commit staged regs to LDS (prev consumers done via barrier at loop end)
#pragma unroll
    for (int i = 0; i < 4; i++) {
      *(bf16x8*)&As[arow[i]][acol[i]] = ra[i];
      *(bf16x8*)&Bs[brow[i]][bcol4[i]] = rb[i];
    }
    __syncthreads();
    // issue next k-step loads early; they fly during the MFMA phase
    if (kt + 1 < nk) {
      int k0 = (kt + 1) << 6;
#pragma unroll
      for (int i = 0; i < 4; i++) {
        bf16x8 v = {};
        if (tok[i] >= 0) v = *(const bf16x8*)&Abf[(size_t)tok[i] * K + k0 + acol[i]];
        ra[i] = v;
        rb[i] = *(const bf16x8*)&Wt[(size_t)(n0 + brow[i]) * K + k0 + bcol4[i]];
      }
    }
#pragma unroll
    for (int kk = 0; kk < 2; kk++) {
      bf16x8 a0 = *(const bf16x8*)&As[w * 32 + c][kk * 32 + g * 8];
      bf16x8 a1 = *(const bf16x8*)&As[w * 32 + 16 + c][kk * 32 + g * 8];
#pragma unroll
      for (int n = 0; n < 8; n++) {
        bf16x8 b = *(const bf16x8*)&Bs[n * 16 + c][kk * 32 + g * 8];
        acc[0][n] = __builtin_amdgcn_mfma_f32_16x16x32_bf16(a0, b, acc[0][n], 0, 0, 0);
        acc[1][n] = __builtin_amdgcn_mfma_f32_16x16x32_bf16(a1, b, acc[1][n], 0, 0, 0);
      }
    }
    __syncthreads();
  }
#pragma unroll
  for (int m = 0; m < 2; m++) {
    int row = w * 32 + m * 16 + 4 * g;                // local row (+r)
#pragma unroll
    for (int n = 0; n < 8; n++) {
      int col = n0 + n * 16 + c;
      float bv = bias[col];
#pragma unroll
      for (int r = 0; r < 4; r++) {
        float v = acc[m][n][r] + bv;
        int lr = row + r;
        if constexpr (MODE == 0) {
          int t = m0 + lr;
          int b = t >> 10, s = t & 1023;
          int which = col / 384;
          int rem = col - which * 384;
          int hd = rem / 48;
          int d = rem - hd * 48;
          size_t bh = (size_t)(b * 8 + hd);
          if (which == 0)      pQ[(bh * 1024 + s) * 48 + d] = (__bf16)v;
          else if (which == 1) pK[(bh * 1024 + s) * 48 + d] = (__bf16)v;
          else                 pV[(bh * 48 + d) * 1024 + s] = (__bf16)v;
        } else if constexpr (MODE == 1) {
          Cf[(size_t)(m0 + lr) * N + col] += v;
        } else if constexpr (MODE == 2) {
          if (m0 + lr < cnt) Cb[(size_t)(base + m0 + lr) * N + col] = (__bf16)fmaxf(v, 0.f);
        } else {
          if (m0 + lr < cnt) {
            int entry = tl[m0 + lr];
            int t = entry & 0xFFFF, a = entry >> 16;
            float gv = gate_list[e * TOKENS + m0 + lr];
            Cb[((size_t)a * TOKENS + t) * DMODEL + col] = (__bf16)(gv * v);
          }
        }
      }
    }
  }
}

// combine: h += ab[0] + ab[1]   (dense elementwise, 8 elems/thread)
__global__ __launch_bounds__(256) void combine_kernel(float* __restrict__ h,
    const __bf16* __restrict__ ab) {
  size_t i = ((size_t)blockIdx.x * 256 + threadIdx.x) * 8;
  bf16x8 a0 = *(const bf16x8*)&ab[i];
  bf16x8 a1 = *(const bf16x8*)&ab[(size_t)TOKENS * DMODEL + i];
  float* hp = h + i;
#pragma unroll
  for (int j = 0; j < 8; j++) hp[j] += (float)a0[j] + (float)a1[j];
}

// ---------------- bf16 MFMA flash attention, swapped-QK in-register softmax ----
// grid (bh=128, q0blk=16); 4 waves, wave w owns q rows q0+w*16 .. +15.
// Q/K head-major [bh][s][48]; V pre-transposed [bh][48][s].
__global__ __launch_bounds__(256) void attn_kernel(const __bf16* __restrict__ Qh,
    const __bf16* __restrict__ Kh, const __bf16* __restrict__ VTh,
    __bf16* __restrict__ ao) {
  __shared__ __align__(16) __bf16 Ks[64][56];
  __shared__ __align__(16) __bf16 Vt[48][72];
  __shared__ __align__(16) __bf16 Ps[4][16][72];
  int bh = blockIdx.x;
  int q0 = blockIdx.y * 64;
  int tid = threadIdx.x;
  int w = tid >> 6, lane = tid & 63, c = lane & 15, g = lane >> 4;
  const float scale = 0.14433756729740643f;     // 1/sqrt(48)

  // Q fragments straight from global (B-operand: Q[q=c][k])
  const __bf16* qrow = Qh + ((size_t)bh * 1024 + q0 + w * 16 + c) * 48;
  bf16x8 qb0 = *(const bf16x8*)&qrow[g * 8];
  bf16x8 qb1 = {};
  if (g < 2) qb1 = *(const bf16x8*)&qrow[32 + g * 8];

  f32x4 acc[3];
#pragma unroll
  for (int t = 0; t < 3; t++) { acc[t][0] = 0.f; acc[t][1] = 0.f; acc[t][2] = 0.f; acc[t][3] = 0.f; }
  float m = -INFINITY, l = 0.f;

  const __bf16* kb = Kh + (size_t)bh * 1024 * 48;
  const __bf16* vb = VTh + (size_t)bh * 48 * 1024;

  for (int kt = 0; kt < 16; kt++) {
    __syncthreads();
    {   // stage K tile [64][48] and V^T tile [48][64]
      const __bf16* kbase = kb + (size_t)kt * 64 * 48;
      const __bf16* vbase = vb + kt * 64;
      for (int e = tid; e < 768; e += 256) {
        if (e < 384) {
          int row = e / 6, part = e - row * 6;
          *(bf16x8*)&Ks[row][part * 8] = *(const bf16x8*)&kbase[row * 48 + part * 8];
        } else {
          int i = e - 384;
          int d = i >> 3, part = i & 7;
          *(bf16x8*)&Vt[d][part * 8] = *(const bf16x8*)&vbase[(size_t)d * 1024 + part * 8];
        }
      }
    }
    __syncthreads();

    // S^T = K Q^T : lane (c,g) gets S[q=c][kv=f*16+4g+r]
    f32x4 s4[4];
#pragma unroll
    for (int f = 0; f < 4; f++) {
      bf16x8 ka0 = *(const bf16x8*)&Ks[f * 16 + c][g * 8];
      bf16x8 ka1 = {};
      if (g < 2) ka1 = *(const bf16x8*)&Ks[f * 16 + c][32 + g * 8];
      f32x4 z = {};
      z = __builtin_amdgcn_mfma_f32_16x16x32_bf16(ka0, qb0, z, 0, 0, 0);
      s4[f] = __builtin_amdgcn_mfma_f32_16x16x32_bf16(ka1, qb1, z, 0, 0, 0);
    }
    float sv[4][4];
#pragma unroll
    for (int f = 0; f < 4; f++)
#pragma unroll
      for (int r = 0; r < 4; r++) sv[f][r] = s4[f][r] * scale;
    // in-register row max (16 vals) + cross-g reduce (lanes c,c+16,c+32,c+48)
    float tmax = sv[0][0];
#pragma unroll
    for (int f = 0; f < 4; f++)
#pragma unroll
      for (int r = 0; r < 4; r++) tmax = fmaxf(tmax, sv[f][r]);
    tmax = fmaxf(tmax, __shfl_xor(tmax, 16, 64));
    tmax = fmaxf(tmax, __shfl_xor(tmax, 32, 64));
    float mnew = fmaxf(m, tmax);
    float al = __expf(m - mnew);
    m = mnew;
    float p[4][4];
    float ps = 0.f;
#pragma unroll
    for (int f = 0; f < 4; f++)
#pragma unroll
      for (int r = 0; r < 4; r++) { p[f][r] = __expf(sv[f][r] - mnew); ps += p[f][r]; }
    ps += __shfl_xor(ps, 16, 64);
    ps += __shfl_xor(ps, 32, 64);
    l = l * al + ps;
    // rescale acc rows (q = 4g+r needs alpha of lane 4g+r)
#pragma unroll
    for (int r = 0; r < 4; r++) {
      float ar = __shfl(al, 4 * g + r, 64);
      acc[0][r] *= ar; acc[1][r] *= ar; acc[2][r] *= ar;
    }
    // P^T -> per-wave LDS in PV-A layout: Ps[w][q=c][kv]
#pragma unroll
    for (int f = 0; f < 4; f++)
#pragma unroll
      for (int r = 0; r < 4; r++)
        Ps[w][c][f * 16 + 4 * g + r] = (__bf16)p[f][r];
    bf16x8 pa0 = *(const bf16x8*)&Ps[w][c][g * 8];
    bf16x8 pa1 = *(const bf16x8*)&Ps[w][c][32 + g * 8];
    // O += P V : B-operand = V^T[dh=c][kv=k] (Vt natural rows)
#pragma unroll
    for (int t = 0; t < 3; t++) {
      bf16x8 vb0 = *(const bf16x8*)&Vt[t * 16 + c][g * 8];
      bf16x8 vb1 = *(const bf16x8*)&Vt[t * 16 + c][32 + g * 8];
      acc[t] = __builtin_amdgcn_mfma_f32_16x16x32_bf16(pa0, vb0, acc[t], 0, 0, 0);
      acc[t] = __builtin_amdgcn_mfma_f32_16x16x32_bf16(pa1, vb1, acc[t], 0, 0, 0);
    }
  }
  float linv[4];
#pragma unroll
  for (int r = 0; r < 4; r++) linv[r] = 1.f / __shfl(l, 4 * g + r, 64);
  int b = bh >> 3, hh = bh & 7;
#pragma unroll
  for (int t = 0; t < 3; t++)
#pragma unroll
    for (int r = 0; r < 4; r++)
      ao[((size_t)(b * SEQ + q0 + w * 16 + 4 * g + r)) * DMODEL + hh * 48 + t * 16 + c] =
          (__bf16)(acc[t][r] * linv[r]);
}

// ---------------- gating: block = 256 tokens, block-aggregated atomics ----------------
__global__ __launch_bounds__(256) void gate_kernel(const __bf16* __restrict__ xnb,
    const float* __restrict__ gw, int* __restrict__ counts, float* __restrict__ sum_probs,
    int* __restrict__ tok_list, float* __restrict__ gate_list) {
  __shared__ float Gs[NEXP][DMODEL];
  __shared__ float simp[NEXP];
  __shared__ int hist[NEXP], basep[NEXP];
  __shared__ unsigned char tokE[256][2];
  __shared__ float tokG[256][2];
  __shared__ short rankS[256][2];
  int tid = threadIdx.x;
  for (int i = tid; i < DMODEL * NEXP; i += 256) {
    int d = i >> 3, e2 = i & 7;
    Gs[e2][d] = gw[i];
  }
  if (tid < NEXP) { simp[tid] = 0.f; hist[tid] = 0; }
  __syncthreads();
  int w = tid >> 6, lane = tid & 63;
  int tbase = blockIdx.x * 256 + w * 64;
  float impacc[NEXP] = {};
  for (int tt = 0; tt < 64; tt++) {
    int t = tbase + tt;
    float p[NEXP] = {};
#pragma unroll
    for (int j = 0; j < 6; j++) {
      int d = lane + 64 * j;
      float xv = (float)xnb[(size_t)t * DMODEL + d];
#pragma unroll
      for (int e2 = 0; e2 < NEXP; e2++) p[e2] += xv * Gs[e2][d];
    }
#pragma unroll
    for (int off = 32; off; off >>= 1)
#pragma unroll
      for (int e2 = 0; e2 < NEXP; e2++) p[e2] += __shfl_xor(p[e2], off);
    float mx = p[0];
#pragma unroll
    for (int e2 = 1; e2 < NEXP; e2++) mx = fmaxf(mx, p[e2]);
    float s = 0.f;
#pragma unroll
    for (int e2 = 0; e2 < NEXP; e2++) { p[e2] = __expf(p[e2] - mx); s += p[e2]; }
    float inv = 1.f / s;
#pragma unroll
    for (int e2 = 0; e2 < NEXP; e2++) { p[e2] *= inv; impacc[e2] += p[e2]; }
    int i0 = 0; float v0 = p[0];
#pragma unroll
    for (int e2 = 1; e2 < NEXP; e2++) if (p[e2] > v0) { v0 = p[e2]; i0 = e2; }
    int i1 = -1; float v1 = -INFINITY;
#pragma unroll
    for (int e2 = 0; e2 < NEXP; e2++) if (e2 != i0 && p[e2] > v1) { v1 = p[e2]; i1 = e2; }
    if (lane == 0) {
      float gsum = v0 + v1;
      int r0 = atomicAdd(&hist[i0], 1);
      int r1 = atomicAdd(&hist[i1], 1);
      int sl = w * 64 + tt;
      tokE[sl][0] = (unsigned char)i0; tokE[sl][1] = (unsigned char)i1;
      tokG[sl][0] = v0 / gsum;         tokG[sl][1] = v1 / gsum;
      rankS[sl][0] = (short)r0;        rankS[sl][1] = (short)r1;
    }
  }
  if (lane == 0)
#pragma unroll
    for (int e2 = 0; e2 < NEXP; e2++) atomicAdd(&simp[e2], impacc[e2]);
  __syncthreads();
  if (tid < NEXP) {
    basep[tid] = atomicAdd(&counts[tid], hist[tid]);
    atomicAdd(&sum_probs[tid], simp[tid]);
  }
  __syncthreads();
  int t0 = blockIdx.x * 256;
  for (int i = tid; i < 512; i += 256) {
    int sl = i >> 1, a = i & 1;
    int e2 = tokE[sl][a];
    int pos = basep[e2] + rankS[sl][a];
    tok_list[e2 * TOKENS + pos] = (t0 + sl) | (a << 16);
    gate_list[e2 * TOKENS + pos] = tokG[sl][a];
  }
}

// prefix offsets (64-padded) + aux loss contribution
__global__ void aux_kernel(const int* __restrict__ counts, int* __restrict__ offs,
                           const float* __restrict__ sum_probs, float* __restrict__ total_moe) {
  int off = 0;
  float tm = 0.f;
  for (int e = 0; e < NEXP; e++) {
    offs[e] = off;
    off += ((counts[e] + 63) >> 6) << 6;
    tm += sum_probs[e] * (float)counts[e];
  }
  offs[NEXP] = off;
  *total_moe += (float)NEXP * tm / ((float)TOKENS * (float)TOKENS);
}

// ---------------- attention-pool head, split for parallelism ----------------
__global__ __launch_bounds__(256) void head1_kernel(const float* __restrict__ h,
    const float* __restrict__ att_w, const float* __restrict__ att_b,
    float* __restrict__ logits) {
  int tid = threadIdx.x;
  int w = tid >> 6, lane = tid & 63;
  float4 aw0 = *(const float4*)&att_w[lane * 4];
  float2 aw1 = *(const float2*)&att_w[256 + lane * 2];
  float ab = att_b[0];
  for (int i = w; i < 128; i += 4) {
    int t = blockIdx.x * 128 + i;
    const float* hr = h + (size_t)t * DMODEL;
    float4 v4 = *(const float4*)&hr[lane * 4];
    float2 v2 = *(const float2*)&hr[256 + lane * 2];
    float dot = v4.x * aw0.x + v4.y * aw0.y + v4.z * aw0.z + v4.w * aw0.w
              + v2.x * aw1.x + v2.y * aw1.y;
#pragma unroll
    for (int off = 32; off; off >>= 1) dot += __shfl_xor(dot, off);
    if (lane == 0) logits[t] = dot + ab;
  }
}

__global__ __launch_bounds__(256) void head2_kernel(float* __restrict__ logits) {
  int b = blockIdx.x, tid = threadIdx.x;
  int w = tid >> 6, lane = tid & 63;
  float* lb = logits + b * SEQ;
  __shared__ float red[4];
  float lv[4];
  float mx = -INFINITY;
#pragma unroll
  for (int i = 0; i < 4; i++) { lv[i] = lb[tid + 256 * i]; mx = fmaxf(mx, lv[i]); }
#pragma unroll
  for (int off = 32; off; off >>= 1) mx = fmaxf(mx, __shfl_xor(mx, off));
  if (lane == 0) red[w] = mx;
  __syncthreads();
  mx = fmaxf(fmaxf(red[0], red[1]), fmaxf(red[2], red[3]));
  __syncthreads();
  float s = 0.f;
#pragma unroll
  for (int i = 0; i < 4; i++) { lv[i] = __expf(lv[i] - mx); s += lv[i]; }
#pragma unroll
  for (int off = 32; off; off >>= 1) s += __shfl_xor(s, off);
  if (lane == 0) red[w] = s;
  __syncthreads();
  float inv = 1.f / (red[0] + red[1] + red[2] + red[3]);
#pragma unroll
  for (int i = 0; i < 4; i++) lb[tid + 256 * i] = lv[i] * inv;
}

__global__ __launch_bounds__(256) void head3_kernel(const float* __restrict__ h,
    const float* __restrict__ wnorm, const float* __restrict__ head_w,
    float* __restrict__ part) {
  int b = blockIdx.x, dc = blockIdx.y;
  int tid = threadIdx.x;
  int d = tid & 63, sg = tid >> 6;
  const float* hb = h + (size_t)b * SEQ * DMODEL + dc * 64 + d;
  const float* wb = wnorm + b * SEQ;
  float acc = 0.f;
  for (int s = sg * 256; s < sg * 256 + 256; s++)
    acc += wb[s] * hb[(size_t)s * DMODEL];
  __shared__ float red[256];
  red[tid] = acc;
  __syncthreads();
  if (sg == 0) {
    float pooled = red[d] + red[64 + d] + red[128 + d] + red[192 + d];
    float pd = pooled * head_w[dc * 64 + d];
#pragma unroll
    for (int off = 32; off; off >>= 1) pd += __shfl_xor(pd, off);
    if (d == 0) part[b * 6 + dc] = pd;
  }
}

__global__ void head4_kernel(const float* __restrict__ part,
                             const float* __restrict__ head_b, float* __restrict__ out) {
  int b = threadIdx.x;
  if (b < 16) {
    float s = head_b[0];
#pragma unroll
    for (int dc = 0; dc < 6; dc++) s += part[b * 6 + dc];
    out[b] = s;
  }
}

// ---------------- launch ----------------
extern "C" void kernel_launch(void* const* d_in, const int* in_sizes, int n_in,
                              void* d_out, int out_size, void* d_ws, size_t ws_size,
                              hipStream_t stream) {
  (void)in_sizes; (void)n_in; (void)out_size; (void)ws_size;
  const float* x      = (const float*)d_in[0];
  const float* proj_w = (const float*)d_in[1];
  const float* proj_b = (const float*)d_in[2];
  const float* qkv_w  = (const float*)d_in[3];
  const float* qkv_b  = (const float*)d_in[4];
  const float* out_w  = (const float*)d_in[5];
  const float* out_b  = (const float*)d_in[6];
  const float* n1_s   = (const float*)d_in[7];
  const float* n1_b   = (const float*)d_in[8];
  const float* n2_s   = (const float*)d_in[9];
  const float* n2_b   = (const float*)d_in[10];
  const float* gate_w = (const float*)d_in[11];
  const float* e_w1   = (const float*)d_in[12];
  const float* e_b1   = (const float*)d_in[13];
  const float* e_w2   = (const float*)d_in[14];
  const float* e_b2   = (const float*)d_in[15];
  const float* att_w  = (const float*)d_in[16];
  const float* att_b  = (const float*)d_in[17];
  const float* head_w = (const float*)d_in[18];
  const float* head_b = (const float*)d_in[19];
  float* out = (float*)d_out;

  // workspace layout (bytes):
  // h fp32 25.2MB | {xnb 12.6 | aob 12.6}MB (reused as ab[2][16384][384] during moe2)
  // | uni region 51.1MB: {Qh 12.6 | Kh 12.6 | VTh 12.6} during attn, a1b during MoE
  // | Wt bf16 31.9MB | control
  char* wsb = (char*)d_ws;
  float*  h    = (float*)(wsb);
  __bf16* xnb  = (__bf16*)(wsb + 25165824);
  __bf16* aob  = (__bf16*)(wsb + 37748736);
  __bf16* ab   = (__bf16*)(wsb + 25165824);        // [2][16384][384] aliases xnb+aob
  __bf16* uni  = (__bf16*)(wsb + 50331648);
  __bf16* Qh   = uni;                              // [128][1024][48] = 12,582,912 B
  __bf16* Khd  = (__bf16*)(wsb + 62914560);
  __bf16* VTh  = (__bf16*)(wsb + 75497472);
  __bf16* qkvWt = (__bf16*)(wsb + 101449728);   // [3][1152][384]
  __bf16* outWt = (__bf16*)(wsb + 104103936);   // [3][384][384]
  __bf16* e1Wt  = (__bf16*)(wsb + 104988672);   // [3*8][768][384]
  __bf16* e2Wt  = (__bf16*)(wsb + 119144448);   // [3*8][384][768]
  char* sm = wsb + 133300224;
  int*   counts    = (int*)(sm);
  int*   offs      = (int*)(sm + 64);
  float* sum_probs = (float*)(sm + 128);
  float* total_moe = (float*)(sm + 192);
  int*   tok_list  = (int*)(sm + 256);
  float* gate_list = (float*)(sm + 256 + 524288);
  float* logits    = (float*)(sm + 1048832);
  float* part      = (float*)(sm + 1048832 + 65536);

  // one-shot weight transpose+cast (runs every call; deterministic)
  convw_kernel<<<dim3(36, 12, 3), 256, 0, stream>>>(qkv_w, qkvWt, 384, 1152);
  convw_kernel<<<dim3(12, 12, 3), 256, 0, stream>>>(out_w, outWt, 384, 384);
  convw_kernel<<<dim3(24, 12, 24), 256, 0, stream>>>(e_w1, e1Wt, 384, 768);
  convw_kernel<<<dim3(12, 24, 24), 256, 0, stream>>>(e_w2, e2Wt, 768, 384);

  init_kernel<<<1, 1, 0, stream>>>(total_moe);
  proj_kernel<<<TOKENS * DMODEL / 256, 256, 0, stream>>>(x, proj_w, proj_b, h);

  for (int l = 0; l < NL; l++) {
    ln_kernel<<<TOKENS, 384, 0, stream>>>(h, xnb, n1_s + l * DMODEL, n1_b + l * DMODEL);
    mgemm_kernel<0><<<dim3(9, 128), 256, 0, stream>>>(
        xnb, qkvWt + (size_t)l * 1152 * 384, qkv_b + l * 1152, nullptr, nullptr,
        Qh, Khd, VTh, nullptr, nullptr, nullptr, nullptr, 1152, 384);
    attn_kernel<<<dim3(128, 16), 256, 0, stream>>>(Qh, Khd, VTh, aob);
    mgemm_kernel<1><<<dim3(3, 128), 256, 0, stream>>>(
        aob, outWt + (size_t)l * 384 * 384, out_b + l * 384, h, nullptr,
        nullptr, nullptr, nullptr, nullptr, nullptr, nullptr, nullptr, 384, 384);
    ln_kernel<<<TOKENS, 384, 0, stream>>>(h, xnb, n2_s + l * DMODEL, n2_b + l * DMODEL);
    zero_cnt_kernel<<<1, 64, 0, stream>>>(counts, sum_probs);
    gate_kernel<<<64, 256, 0, stream>>>(xnb, gate_w + (size_t)l * DMODEL * NEXP,
                                        counts, sum_probs, tok_list, gate_list);
    aux_kernel<<<1, 1, 0, stream>>>(counts, offs, sum_probs, total_moe);
    mgemm_kernel<2><<<dim3(6, 128, 8), 256, 0, stream>>>(
        xnb, e1Wt + (size_t)l * 8 * 768 * 384, e_b1 + l * 8 * FFDIM, nullptr, uni,
        nullptr, nullptr, nullptr, counts, offs, tok_list, nullptr, 768, 384);
    mgemm_kernel<3><<<dim3(3, 128, 8), 256, 0, stream>>>(
        uni, e2Wt + (size_t)l * 8 * 384 * 768, e_b2 + l * 8 * DMODEL, nullptr, ab,
        nullptr, nullptr, nullptr, counts, offs, tok_list, gate_list, 384, 768);
    combine_kernel<<<TOKENS * DMODEL / (256 * 8), 256, 0, stream>>>(h, ab);
  }

  head1_kernel<<<128, 256, 0, stream>>>(h, att_w, att_b, logits);
  head2_kernel<<<16, 256, 0, stream>>>(logits);
  head3_kernel<<<dim3(16, 6), 256, 0, stream>>>(h, logits, head_w, part);
  head4_kernel<<<1, 64, 0, stream>>>(part, head_b, out);
  finalize_kernel<<<1, 1, 0, stream>>>(total_moe, out);
}

// Round 8
// 1222.719 us; speedup vs baseline: 6.0681x; 1.1566x over previous
//
#include <hip/hip_runtime.h>
#include <hip/hip_bf16.h>
#include <math.h>

// RULPredictionModel: B=16 S=1024 D=384 H=8 DH=48 L=3 E=8 FF=768 TOP_K=2
#define TOKENS 16384
#define DMODEL 384
#define SEQ 1024
#define NHEAD 8
#define DHEAD 48
#define NEXP 8
#define FFDIM 768
#define NL 3

typedef __bf16 bf16x8 __attribute__((ext_vector_type(8)));
typedef __bf16 bf16x4 __attribute__((ext_vector_type(4)));
typedef float f32x4 __attribute__((ext_vector_type(4)));

// ---------------- tiny kernels ----------------
__global__ void init_kernel(float* total_moe) { *total_moe = 0.f; }

__global__ void zero_cnt_kernel(int* counts, float* sum_probs) {
  int t = threadIdx.x;
  if (t < NEXP) { counts[t] = 0; sum_probs[t] = 0.f; }
}

__global__ void finalize_kernel(const float* total_moe, float* out) { out[16] = *total_moe; }

__global__ __launch_bounds__(256) void proj_kernel(const float* __restrict__ x,
    const float* __restrict__ pw, const float* __restrict__ pb, float* __restrict__ h) {
  int i = blockIdx.x * 256 + threadIdx.x;
  int t = i / DMODEL;
  int d = i - t * DMODEL;
  h[i] = x[t] * pw[d] + pb[d];
}

// weight transpose + cast: src fp32 [K][N] (batched) -> dst bf16 [N][K]
__global__ __launch_bounds__(256) void convw_kernel(const float* __restrict__ src,
    __bf16* __restrict__ dst, int K, int N) {
  __shared__ float t[32][33];
  size_t boff = (size_t)blockIdx.z * K * N;
  src += boff; dst += boff;
  int k0 = blockIdx.y * 32, n0 = blockIdx.x * 32;
  int tx = threadIdx.x & 31, ty = threadIdx.x >> 5;   // 32 x 8
#pragma unroll
  for (int i = 0; i < 32; i += 8) t[ty + i][tx] = src[(size_t)(k0 + ty + i) * N + n0 + tx];
  __syncthreads();
#pragma unroll
  for (int i = 0; i < 32; i += 8)
    dst[(size_t)(n0 + ty + i) * K + k0 + tx] = (__bf16)t[tx][ty + i];
}

// one block (384 threads) per row; bf16 output
__global__ __launch_bounds__(384) void ln_kernel(const float* __restrict__ src,
    __bf16* __restrict__ dst, const float* __restrict__ gs, const float* __restrict__ gb) {
  int row = blockIdx.x, tid = threadIdx.x;
  float v = src[(size_t)row * DMODEL + tid];
  float sum = v, sq = v * v;
#pragma unroll
  for (int off = 32; off; off >>= 1) { sum += __shfl_xor(sum, off); sq += __shfl_xor(sq, off); }
  __shared__ float rs[6], rq[6];
  __shared__ float smean, sinv;
  int wid = tid >> 6;
  if ((tid & 63) == 0) { rs[wid] = sum; rq[wid] = sq; }
  __syncthreads();
  if (tid == 0) {
    float S = 0.f, Q = 0.f;
    for (int w = 0; w < 6; w++) { S += rs[w]; Q += rq[w]; }
    float mean = S / (float)DMODEL;
    float var = Q / (float)DMODEL - mean * mean;
    smean = mean; sinv = rsqrtf(var + 1e-5f);
  }
  __syncthreads();
  dst[(size_t)row * DMODEL + tid] = (__bf16)((v - smean) * sinv * gs[tid] + gb[tid]);
}

// ---------------- bf16 MFMA GEMM: C = A @ Wt^T + bias, tile 128x128x64 ----------------
// async-split staging: k-step t+1 global loads issued while computing t.
// MODE 0: qkv   (A=xnb, writes head-major Qh/Kh + transposed VTh)
// MODE 1: out   (A=aob,  Cf += acc+bias)   [residual]
// MODE 2: moe1  (A=gather(xnb) via tok_list&0xFFFF, relu, out bf16 a1)
// MODE 3: moe2  (A=a1b rows base+m, store gate*(acc+bias) to ab[a][t] bf16)
template<int MODE>
__global__ __launch_bounds__(256) void mgemm_kernel(
    const __bf16* __restrict__ Abf, const __bf16* __restrict__ Wt,
    const float* __restrict__ bias, float* __restrict__ Cf, __bf16* __restrict__ Cb,
    __bf16* __restrict__ pQ, __bf16* __restrict__ pK, __bf16* __restrict__ pV,
    const int* __restrict__ counts, const int* __restrict__ offs,
    const int* __restrict__ tok_list, const float* __restrict__ gate_list,
    int N, int K) {
  int e = 0, cnt = 0, base = 0;
  const int* tl = nullptr;
  int m0 = blockIdx.y * 128;
  if constexpr (MODE == 2 || MODE == 3) {
    e = blockIdx.z;
    cnt = counts[e];
    if (m0 >= cnt) return;
    base = offs[e];
    tl = tok_list + e * TOKENS;
    Wt += (size_t)e * N * K;
    bias += (size_t)e * N;
  }
  __shared__ __align__(16) __bf16 As[128][72];
  __shared__ __align__(16) __bf16 Bs[128][72];
  int tid = threadIdx.x;
  int n0 = blockIdx.x * 128;
  int w = tid >> 6, lane = tid & 63, c = lane & 15, g = lane >> 4;
  int arow[4], acol[4], brow[4], bcol4[4];
  long tok[4];
#pragma unroll
  for (int i = 0; i < 4; i++) {
    int chunk = tid + 256 * i;
    arow[i] = chunk >> 3;
    acol[i] = (chunk & 7) * 8;
    brow[i] = chunk >> 3;
    bcol4[i] = (chunk & 7) * 8;
    int mr = m0 + arow[i];
    if constexpr (MODE == 2)      tok[i] = (mr < cnt) ? (long)(tl[mr] & 0xFFFF) : -1;
    else if constexpr (MODE == 3) tok[i] = (mr < cnt) ? (long)(base + mr) : -1;
    else                          tok[i] = mr;
  }
  f32x4 acc[2][8];
#pragma unroll
  for (int m = 0; m < 2; m++)
#pragma unroll
    for (int n = 0; n < 8; n++) { acc[m][n][0] = 0.f; acc[m][n][1] = 0.f; acc[m][n][2] = 0.f; acc[m][n][3] = 0.f; }

  bf16x8 ra[4], rb[4];
  int nk = K >> 6;
  // prologue: load k-step 0 into regs
#pragma unroll
  for (int i = 0; i < 4; i++) {
    bf16x8 v = {};
    if (tok[i] >= 0) v = *(const bf16x8*)&Abf[(size_t)tok[i] * K + acol[i]];
    ra[i] = v;
    rb[i] = *(const bf16x8*)&Wt[(size_t)(n0 + brow[i]) * K + bcol4[i]];
  }
  for (int kt = 0; kt < nk; kt++) {
    // commit staged regs to LDS (prev consumers done via barrier at loop end)
#pragma unroll
    for (int i = 0; i < 4; i++) {
      *(bf16x8*)&As[arow[i]][acol[i]] = ra[i];
      *(bf16x8*)&Bs[brow[i]][bcol4[i]] = rb[i];
    }
    __syncthreads();
    // issue next k-step loads early; they fly during the MFMA phase
    if (kt + 1 < nk) {
      int k0 = (kt + 1) << 6;
#pragma unroll
      for (int i = 0; i < 4; i++) {
        bf16x8 v = {};
        if (tok[i] >= 0) v = *(const bf16x8*)&Abf[(size_t)tok[i] * K + k0 + acol[i]];
        ra[i] = v;
        rb[i] = *(const bf16x8*)&Wt[(size_t)(n0 + brow[i]) * K + k0 + bcol4[i]];
      }
    }
#pragma unroll
    for (int kk = 0; kk < 2; kk++) {
      bf16x8 a0 = *(const bf16x8*)&As[w * 32 + c][kk * 32 + g * 8];
      bf16x8 a1 = *(const bf16x8*)&As[w * 32 + 16 + c][kk * 32 + g * 8];
#pragma unroll
      for (int n = 0; n < 8; n++) {
        bf16x8 b = *(const bf16x8*)&Bs[n * 16 + c][kk * 32 + g * 8];
        acc[0][n] = __builtin_amdgcn_mfma_f32_16x16x32_bf16(a0, b, acc[0][n], 0, 0, 0);
        acc[1][n] = __builtin_amdgcn_mfma_f32_16x16x32_bf16(a1, b, acc[1][n], 0, 0, 0);
      }
    }
    __syncthreads();
  }
#pragma unroll
  for (int m = 0; m < 2; m++) {
    int row = w * 32 + m * 16 + 4 * g;                // local row (+r)
#pragma unroll
    for (int n = 0; n < 8; n++) {
      int col = n0 + n * 16 + c;
      float bv = bias[col];
#pragma unroll
      for (int r = 0; r < 4; r++) {
        float v = acc[m][n][r] + bv;
        int lr = row + r;
        if constexpr (MODE == 0) {
          int t = m0 + lr;
          int b = t >> 10, s = t & 1023;
          int which = col / 384;
          int rem = col - which * 384;
          int hd = rem / 48;
          int d = rem - hd * 48;
          size_t bh = (size_t)(b * 8 + hd);
          if (which == 0)      pQ[(bh * 1024 + s) * 48 + d] = (__bf16)v;
          else if (which == 1) pK[(bh * 1024 + s) * 48 + d] = (__bf16)v;
          else                 pV[(bh * 48 + d) * 1024 + s] = (__bf16)v;
        } else if constexpr (MODE == 1) {
          Cf[(size_t)(m0 + lr) * N + col] += v;
        } else if constexpr (MODE == 2) {
          if (m0 + lr < cnt) Cb[(size_t)(base + m0 + lr) * N + col] = (__bf16)fmaxf(v, 0.f);
        } else {
          if (m0 + lr < cnt) {
            int entry = tl[m0 + lr];
            int t = entry & 0xFFFF, a = entry >> 16;
            float gv = gate_list[e * TOKENS + m0 + lr];
            Cb[((size_t)a * TOKENS + t) * DMODEL + col] = (__bf16)(gv * v);
          }
        }
      }
    }
  }
}

// combine: h += ab[0] + ab[1]   (dense elementwise, 8 elems/thread)
__global__ __launch_bounds__(256) void combine_kernel(float* __restrict__ h,
    const __bf16* __restrict__ ab) {
  size_t i = ((size_t)blockIdx.x * 256 + threadIdx.x) * 8;
  bf16x8 a0 = *(const bf16x8*)&ab[i];
  bf16x8 a1 = *(const bf16x8*)&ab[(size_t)TOKENS * DMODEL + i];
  float* hp = h + i;
#pragma unroll
  for (int j = 0; j < 8; j++) hp[j] += (float)a0[j] + (float)a1[j];
}

// ---------------- bf16 MFMA flash attention, swapped-QK in-register softmax ----
// grid (bh=128, q0blk=16); 4 waves, wave w owns q rows q0+w*16 .. +15.
// Q/K head-major [bh][s][48]; V pre-transposed [bh][48][s].
__global__ __launch_bounds__(256) void attn_kernel(const __bf16* __restrict__ Qh,
    const __bf16* __restrict__ Kh, const __bf16* __restrict__ VTh,
    __bf16* __restrict__ ao) {
  __shared__ __align__(16) __bf16 Ks[64][56];
  __shared__ __align__(16) __bf16 Vt[48][72];
  __shared__ __align__(16) __bf16 Ps[4][16][72];
  int bh = blockIdx.x;
  int q0 = blockIdx.y * 64;
  int tid = threadIdx.x;
  int w = tid >> 6, lane = tid & 63, c = lane & 15, g = lane >> 4;
  const float scale = 0.14433756729740643f;     // 1/sqrt(48)

  // Q fragments straight from global (B-operand: Q[q=c][k])
  const __bf16* qrow = Qh + ((size_t)bh * 1024 + q0 + w * 16 + c) * 48;
  bf16x8 qb0 = *(const bf16x8*)&qrow[g * 8];
  bf16x8 qb1 = {};
  if (g < 2) qb1 = *(const bf16x8*)&qrow[32 + g * 8];

  f32x4 acc[3];
#pragma unroll
  for (int t = 0; t < 3; t++) { acc[t][0] = 0.f; acc[t][1] = 0.f; acc[t][2] = 0.f; acc[t][3] = 0.f; }
  float m = -INFINITY, l = 0.f;

  const __bf16* kb = Kh + (size_t)bh * 1024 * 48;
  const __bf16* vb = VTh + (size_t)bh * 48 * 1024;

  for (int kt = 0; kt < 16; kt++) {
    __syncthreads();
    {   // stage K tile [64][48] and V^T tile [48][64]
      const __bf16* kbase = kb + (size_t)kt * 64 * 48;
      const __bf16* vbase = vb + kt * 64;
      for (int e = tid; e < 768; e += 256) {
        if (e < 384) {
          int row = e / 6, part = e - row * 6;
          *(bf16x8*)&Ks[row][part * 8] = *(const bf16x8*)&kbase[row * 48 + part * 8];
        } else {
          int i = e - 384;
          int d = i >> 3, part = i & 7;
          *(bf16x8*)&Vt[d][part * 8] = *(const bf16x8*)&vbase[(size_t)d * 1024 + part * 8];
        }
      }
    }
    __syncthreads();

    // S^T = K Q^T : lane (c,g) gets S[q=c][kv=f*16+4g+r]
    f32x4 s4[4];
#pragma unroll
    for (int f = 0; f < 4; f++) {
      bf16x8 ka0 = *(const bf16x8*)&Ks[f * 16 + c][g * 8];
      bf16x8 ka1 = {};
      if (g < 2) ka1 = *(const bf16x8*)&Ks[f * 16 + c][32 + g * 8];
      f32x4 z = {};
      z = __builtin_amdgcn_mfma_f32_16x16x32_bf16(ka0, qb0, z, 0, 0, 0);
      s4[f] = __builtin_amdgcn_mfma_f32_16x16x32_bf16(ka1, qb1, z, 0, 0, 0);
    }
    float sv[4][4];
#pragma unroll
    for (int f = 0; f < 4; f++)
#pragma unroll
      for (int r = 0; r < 4; r++) sv[f][r] = s4[f][r] * scale;
    // in-register row max (16 vals) + cross-g reduce (lanes c,c+16,c+32,c+48)
    float tmax = sv[0][0];
#pragma unroll
    for (int f = 0; f < 4; f++)
#pragma unroll
      for (int r = 0; r < 4; r++) tmax = fmaxf(tmax, sv[f][r]);
    tmax = fmaxf(tmax, __shfl_xor(tmax, 16, 64));
    tmax = fmaxf(tmax, __shfl_xor(tmax, 32, 64));
    float mnew = fmaxf(m, tmax);
    float al = __expf(m - mnew);
    m = mnew;
    float p[4][4];
    float ps = 0.f;
#pragma unroll
    for (int f = 0; f < 4; f++)
#pragma unroll
      for (int r = 0; r < 4; r++) { p[f][r] = __expf(sv[f][r] - mnew); ps += p[f][r]; }
    ps += __shfl_xor(ps, 16, 64);
    ps += __shfl_xor(ps, 32, 64);
    l = l * al + ps;
    // rescale acc rows (q = 4g+r needs alpha of lane 4g+r)
#pragma unroll
    for (int r = 0; r < 4; r++) {
      float ar = __shfl(al, 4 * g + r, 64);
      acc[0][r] *= ar; acc[1][r] *= ar; acc[2][r] *= ar;
    }
    // P^T -> per-wave LDS in PV-A layout: Ps[w][q=c][kv]
#pragma unroll
    for (int f = 0; f < 4; f++)
#pragma unroll
      for (int r = 0; r < 4; r++)
        Ps[w][c][f * 16 + 4 * g + r] = (__bf16)p[f][r];
    bf16x8 pa0 = *(const bf16x8*)&Ps[w][c][g * 8];
    bf16x8 pa1 = *(const bf16x8*)&Ps[w][c][32 + g * 8];
    // O += P V : B-operand = V^T[dh=c][kv=k] (Vt natural rows)
#pragma unroll
    for (int t = 0; t < 3; t++) {
      bf16x8 vb0 = *(const bf16x8*)&Vt[t * 16 + c][g * 8];
      bf16x8 vb1 = *(const bf16x8*)&Vt[t * 16 + c][32 + g * 8];
      acc[t] = __builtin_amdgcn_mfma_f32_16x16x32_bf16(pa0, vb0, acc[t], 0, 0, 0);
      acc[t] = __builtin_amdgcn_mfma_f32_16x16x32_bf16(pa1, vb1, acc[t], 0, 0, 0);
    }
  }
  float linv[4];
#pragma unroll
  for (int r = 0; r < 4; r++) linv[r] = 1.f / __shfl(l, 4 * g + r, 64);
  int b = bh >> 3, hh = bh & 7;
#pragma unroll
  for (int t = 0; t < 3; t++)
#pragma unroll
    for (int r = 0; r < 4; r++)
      ao[((size_t)(b * SEQ + q0 + w * 16 + 4 * g + r)) * DMODEL + hh * 48 + t * 16 + c] =
          (__bf16)(acc[t][r] * linv[r]);
}

// ---------------- gating: block = 32 tokens (512 blocks), block-aggregated atomics ----
__global__ __launch_bounds__(256) void gate_kernel(const __bf16* __restrict__ xnb,
    const float* __restrict__ gw, int* __restrict__ counts, float* __restrict__ sum_probs,
    int* __restrict__ tok_list, float* __restrict__ gate_list) {
  __shared__ float Gs[NEXP][DMODEL];
  __shared__ float simp[NEXP];
  __shared__ int hist[NEXP], basep[NEXP];
  __shared__ unsigned char tokE[32][2];
  __shared__ float tokG[32][2];
  __shared__ short rankS[32][2];
  int tid = threadIdx.x;
  for (int i = tid; i < DMODEL * NEXP; i += 256) {
    int d = i >> 3, e2 = i & 7;
    Gs[e2][d] = gw[i];
  }
  if (tid < NEXP) { simp[tid] = 0.f; hist[tid] = 0; }
  __syncthreads();
  int w = tid >> 6, lane = tid & 63;
  int tbase = blockIdx.x * 32 + w * 8;
  float impacc[NEXP] = {};
  for (int tt = 0; tt < 8; tt++) {
    int t = tbase + tt;
    float p[NEXP] = {};
#pragma unroll
    for (int j = 0; j < 6; j++) {
      int d = lane + 64 * j;
      float xv = (float)xnb[(size_t)t * DMODEL + d];
#pragma unroll
      for (int e2 = 0; e2 < NEXP; e2++) p[e2] += xv * Gs[e2][d];
    }
#pragma unroll
    for (int off = 32; off; off >>= 1)
#pragma unroll
      for (int e2 = 0; e2 < NEXP; e2++) p[e2] += __shfl_xor(p[e2], off);
    float mx = p[0];
#pragma unroll
    for (int e2 = 1; e2 < NEXP; e2++) mx = fmaxf(mx, p[e2]);
    float s = 0.f;
#pragma unroll
    for (int e2 = 0; e2 < NEXP; e2++) { p[e2] = __expf(p[e2] - mx); s += p[e2]; }
    float inv = 1.f / s;
#pragma unroll
    for (int e2 = 0; e2 < NEXP; e2++) { p[e2] *= inv; impacc[e2] += p[e2]; }
    int i0 = 0; float v0 = p[0];
#pragma unroll
    for (int e2 = 1; e2 < NEXP; e2++) if (p[e2] > v0) { v0 = p[e2]; i0 = e2; }
    int i1 = -1; float v1 = -INFINITY;
#pragma unroll
    for (int e2 = 0; e2 < NEXP; e2++) if (e2 != i0 && p[e2] > v1) { v1 = p[e2]; i1 = e2; }
    if (lane == 0) {
      float gsum = v0 + v1;
      int r0 = atomicAdd(&hist[i0], 1);
      int r1 = atomicAdd(&hist[i1], 1);
      int sl = w * 8 + tt;
      tokE[sl][0] = (unsigned char)i0; tokE[sl][1] = (unsigned char)i1;
      tokG[sl][0] = v0 / gsum;         tokG[sl][1] = v1 / gsum;
      rankS[sl][0] = (short)r0;        rankS[sl][1] = (short)r1;
    }
  }
  if (lane == 0)
#pragma unroll
    for (int e2 = 0; e2 < NEXP; e2++) atomicAdd(&simp[e2], impacc[e2]);
  __syncthreads();
  if (tid < NEXP) {
    basep[tid] = atomicAdd(&counts[tid], hist[tid]);
    atomicAdd(&sum_probs[tid], simp[tid]);
  }
  __syncthreads();
  int t0 = blockIdx.x * 32;
  if (tid < 64) {
    int sl = tid >> 1, a = tid & 1;
    int e2 = tokE[sl][a];
    int pos = basep[e2] + rankS[sl][a];
    tok_list[e2 * TOKENS + pos] = (t0 + sl) | (a << 16);
    gate_list[e2 * TOKENS + pos] = tokG[sl][a];
  }
}

// prefix offsets (64-padded) + aux loss contribution
__global__ void aux_kernel(const int* __restrict__ counts, int* __restrict__ offs,
                           const float* __restrict__ sum_probs, float* __restrict__ total_moe) {
  int off = 0;
  float tm = 0.f;
  for (int e = 0; e < NEXP; e++) {
    offs[e] = off;
    off += ((counts[e] + 63) >> 6) << 6;
    tm += sum_probs[e] * (float)counts[e];
  }
  offs[NEXP] = off;
  *total_moe += (float)NEXP * tm / ((float)TOKENS * (float)TOKENS);
}

// ---------------- attention-pool head, split for parallelism ----------------
__global__ __launch_bounds__(256) void head1_kernel(const float* __restrict__ h,
    const float* __restrict__ att_w, const float* __restrict__ att_b,
    float* __restrict__ logits) {
  int tid = threadIdx.x;
  int w = tid >> 6, lane = tid & 63;
  float4 aw0 = *(const float4*)&att_w[lane * 4];
  float2 aw1 = *(const float2*)&att_w[256 + lane * 2];
  float ab = att_b[0];
  for (int i = w; i < 128; i += 4) {
    int t = blockIdx.x * 128 + i;
    const float* hr = h + (size_t)t * DMODEL;
    float4 v4 = *(const float4*)&hr[lane * 4];
    float2 v2 = *(const float2*)&hr[256 + lane * 2];
    float dot = v4.x * aw0.x + v4.y * aw0.y + v4.z * aw0.z + v4.w * aw0.w
              + v2.x * aw1.x + v2.y * aw1.y;
#pragma unroll
    for (int off = 32; off; off >>= 1) dot += __shfl_xor(dot, off);
    if (lane == 0) logits[t] = dot + ab;
  }
}

__global__ __launch_bounds__(256) void head2_kernel(float* __restrict__ logits) {
  int b = blockIdx.x, tid = threadIdx.x;
  int w = tid >> 6, lane = tid & 63;
  float* lb = logits + b * SEQ;
  __shared__ float red[4];
  float lv[4];
  float mx = -INFINITY;
#pragma unroll
  for (int i = 0; i < 4; i++) { lv[i] = lb[tid + 256 * i]; mx = fmaxf(mx, lv[i]); }
#pragma unroll
  for (int off = 32; off; off >>= 1) mx = fmaxf(mx, __shfl_xor(mx, off));
  if (lane == 0) red[w] = mx;
  __syncthreads();
  mx = fmaxf(fmaxf(red[0], red[1]), fmaxf(red[2], red[3]));
  __syncthreads();
  float s = 0.f;
#pragma unroll
  for (int i = 0; i < 4; i++) { lv[i] = __expf(lv[i] - mx); s += lv[i]; }
#pragma unroll
  for (int off = 32; off; off >>= 1) s += __shfl_xor(s, off);
  if (lane == 0) red[w] = s;
  __syncthreads();
  float inv = 1.f / (red[0] + red[1] + red[2] + red[3]);
#pragma unroll
  for (int i = 0; i < 4; i++) lb[tid + 256 * i] = lv[i] * inv;
}

__global__ __launch_bounds__(256) void head3_kernel(const float* __restrict__ h,
    const float* __restrict__ wnorm, const float* __restrict__ head_w,
    float* __restrict__ part) {
  int b = blockIdx.x, dc = blockIdx.y;
  int tid = threadIdx.x;
  int d = tid & 63, sg = tid >> 6;
  const float* hb = h + (size_t)b * SEQ * DMODEL + dc * 64 + d;
  const float* wb = wnorm + b * SEQ;
  float acc = 0.f;
  for (int s = sg * 256; s < sg * 256 + 256; s++)
    acc += wb[s] * hb[(size_t)s * DMODEL];
  __shared__ float red[256];
  red[tid] = acc;
  __syncthreads();
  if (sg == 0) {
    float pooled = red[d] + red[64 + d] + red[128 + d] + red[192 + d];
    float pd = pooled * head_w[dc * 64 + d];
#pragma unroll
    for (int off = 32; off; off >>= 1) pd += __shfl_xor(pd, off);
    if (d == 0) part[b * 6 + dc] = pd;
  }
}

__global__ void head4_kernel(const float* __restrict__ part,
                             const float* __restrict__ head_b, float* __restrict__ out) {
  int b = threadIdx.x;
  if (b < 16) {
    float s = head_b[0];
#pragma unroll
    for (int dc = 0; dc < 6; dc++) s += part[b * 6 + dc];
    out[b] = s;
  }
}

// ---------------- launch ----------------
extern "C" void kernel_launch(void* const* d_in, const int* in_sizes, int n_in,
                              void* d_out, int out_size, void* d_ws, size_t ws_size,
                              hipStream_t stream) {
  (void)in_sizes; (void)n_in; (void)out_size; (void)ws_size;
  const float* x      = (const float*)d_in[0];
  const float* proj_w = (const float*)d_in[1];
  const float* proj_b = (const float*)d_in[2];
  const float* qkv_w  = (const float*)d_in[3];
  const float* qkv_b  = (const float*)d_in[4];
  const float* out_w  = (const float*)d_in[5];
  const float* out_b  = (const float*)d_in[6];
  const float* n1_s   = (const float*)d_in[7];
  const float* n1_b   = (const float*)d_in[8];
  const float* n2_s   = (const float*)d_in[9];
  const float* n2_b   = (const float*)d_in[10];
  const float* gate_w = (const float*)d_in[11];
  const float* e_w1   = (const float*)d_in[12];
  const float* e_b1   = (const float*)d_in[13];
  const float* e_w2   = (const float*)d_in[14];
  const float* e_b2   = (const float*)d_in[15];
  const float* att_w  = (const float*)d_in[16];
  const float* att_b  = (const float*)d_in[17];
  const float* head_w = (const float*)d_in[18];
  const float* head_b = (const float*)d_in[19];
  float* out = (float*)d_out;

  // workspace layout (bytes):
  // h fp32 25.2MB | {xnb 12.6 | aob 12.6}MB (reused as ab[2][16384][384] during moe2)
  // | uni region 51.1MB: {Qh 12.6 | Kh 12.6 | VTh 12.6} during attn, a1b during MoE
  // | Wt bf16 31.9MB | control
  char* wsb = (char*)d_ws;
  float*  h    = (float*)(wsb);
  __bf16* xnb  = (__bf16*)(wsb + 25165824);
  __bf16* aob  = (__bf16*)(wsb + 37748736);
  __bf16* ab   = (__bf16*)(wsb + 25165824);        // [2][16384][384] aliases xnb+aob
  __bf16* uni  = (__bf16*)(wsb + 50331648);
  __bf16* Qh   = uni;                              // [128][1024][48] = 12,582,912 B
  __bf16* Khd  = (__bf16*)(wsb + 62914560);
  __bf16* VTh  = (__bf16*)(wsb + 75497472);
  __bf16* qkvWt = (__bf16*)(wsb + 101449728);   // [3][1152][384]
  __bf16* outWt = (__bf16*)(wsb + 104103936);   // [3][384][384]
  __bf16* e1Wt  = (__bf16*)(wsb + 104988672);   // [3*8][768][384]
  __bf16* e2Wt  = (__bf16*)(wsb + 119144448);   // [3*8][384][768]
  char* sm = wsb + 133300224;
  int*   counts    = (int*)(sm);
  int*   offs      = (int*)(sm + 64);
  float* sum_probs = (float*)(sm + 128);
  float* total_moe = (float*)(sm + 192);
  int*   tok_list  = (int*)(sm + 256);
  float* gate_list = (float*)(sm + 256 + 524288);
  float* logits    = (float*)(sm + 1048832);
  float* part      = (float*)(sm + 1048832 + 65536);

  // one-shot weight transpose+cast (runs every call; deterministic)
  convw_kernel<<<dim3(36, 12, 3), 256, 0, stream>>>(qkv_w, qkvWt, 384, 1152);
  convw_kernel<<<dim3(12, 12, 3), 256, 0, stream>>>(out_w, outWt, 384, 384);
  convw_kernel<<<dim3(24, 12, 24), 256, 0, stream>>>(e_w1, e1Wt, 384, 768);
  convw_kernel<<<dim3(12, 24, 24), 256, 0, stream>>>(e_w2, e2Wt, 768, 384);

  init_kernel<<<1, 1, 0, stream>>>(total_moe);
  proj_kernel<<<TOKENS * DMODEL / 256, 256, 0, stream>>>(x, proj_w, proj_b, h);

  for (int l = 0; l < NL; l++) {
    ln_kernel<<<TOKENS, 384, 0, stream>>>(h, xnb, n1_s + l * DMODEL, n1_b + l * DMODEL);
    mgemm_kernel<0><<<dim3(9, 128), 256, 0, stream>>>(
        xnb, qkvWt + (size_t)l * 1152 * 384, qkv_b + l * 1152, nullptr, nullptr,
        Qh, Khd, VTh, nullptr, nullptr, nullptr, nullptr, 1152, 384);
    attn_kernel<<<dim3(128, 16), 256, 0, stream>>>(Qh, Khd, VTh, aob);
    mgemm_kernel<1><<<dim3(3, 128), 256, 0, stream>>>(
        aob, outWt + (size_t)l * 384 * 384, out_b + l * 384, h, nullptr,
        nullptr, nullptr, nullptr, nullptr, nullptr, nullptr, nullptr, 384, 384);
    ln_kernel<<<TOKENS, 384, 0, stream>>>(h, xnb, n2_s + l * DMODEL, n2_b + l * DMODEL);
    zero_cnt_kernel<<<1, 64, 0, stream>>>(counts, sum_probs);
    gate_kernel<<<512, 256, 0, stream>>>(xnb, gate_w + (size_t)l * DMODEL * NEXP,
                                         counts, sum_probs, tok_list, gate_list);
    aux_kernel<<<1, 1, 0, stream>>>(counts, offs, sum_probs, total_moe);
    mgemm_kernel<2><<<dim3(6, 128, 8), 256, 0, stream>>>(
        xnb, e1Wt + (size_t)l * 8 * 768 * 384, e_b1 + l * 8 * FFDIM, nullptr, uni,
        nullptr, nullptr, nullptr, counts, offs, tok_list, nullptr, 768, 384);
    mgemm_kernel<3><<<dim3(3, 128, 8), 256, 0, stream>>>(
        uni, e2Wt + (size_t)l * 8 * 384 * 768, e_b2 + l * 8 * DMODEL, nullptr, ab,
        nullptr, nullptr, nullptr, counts, offs, tok_list, gate_list, 384, 768);
    combine_kernel<<<TOKENS * DMODEL / (256 * 8), 256, 0, stream>>>(h, ab);
  }

  head1_kernel<<<128, 256, 0, stream>>>(h, att_w, att_b, logits);
  head2_kernel<<<16, 256, 0, stream>>>(logits);
  head3_kernel<<<dim3(16, 6), 256, 0, stream>>>(h, logits, head_w, part);
  head4_kernel<<<1, 64, 0, stream>>>(part, head_b, out);
  finalize_kernel<<<1, 1, 0, stream>>>(total_moe, out);
}

// Round 9
// 1152.863 us; speedup vs baseline: 6.4358x; 1.0606x over previous
//
#include <hip/hip_runtime.h>
#include <hip/hip_bf16.h>
#include <math.h>

// RULPredictionModel: B=16 S=1024 D=384 H=8 DH=48 L=3 E=8 FF=768 TOP_K=2
#define TOKENS 16384
#define DMODEL 384
#define SEQ 1024
#define NHEAD 8
#define DHEAD 48
#define NEXP 8
#define FFDIM 768
#define NL 3

typedef __bf16 bf16x8 __attribute__((ext_vector_type(8)));
typedef __bf16 bf16x4 __attribute__((ext_vector_type(4)));
typedef float f32x4 __attribute__((ext_vector_type(4)));

// ---------------- tiny kernels ----------------
__global__ void init_kernel(float* total_moe) { *total_moe = 0.f; }

__global__ void zero_cnt_kernel(int* counts, float* sum_probs) {
  int t = threadIdx.x;
  if (t < NEXP) { counts[t] = 0; sum_probs[t] = 0.f; }
}

__global__ void finalize_kernel(const float* total_moe, float* out) { out[16] = *total_moe; }

__global__ __launch_bounds__(256) void proj_kernel(const float* __restrict__ x,
    const float* __restrict__ pw, const float* __restrict__ pb, float* __restrict__ h) {
  int i = blockIdx.x * 256 + threadIdx.x;
  int t = i / DMODEL;
  int d = i - t * DMODEL;
  h[i] = x[t] * pw[d] + pb[d];
}

// weight transpose + cast: src fp32 [K][N] (batched) -> dst bf16 [N][K]
__global__ __launch_bounds__(256) void convw_kernel(const float* __restrict__ src,
    __bf16* __restrict__ dst, int K, int N) {
  __shared__ float t[32][33];
  size_t boff = (size_t)blockIdx.z * K * N;
  src += boff; dst += boff;
  int k0 = blockIdx.y * 32, n0 = blockIdx.x * 32;
  int tx = threadIdx.x & 31, ty = threadIdx.x >> 5;   // 32 x 8
#pragma unroll
  for (int i = 0; i < 32; i += 8) t[ty + i][tx] = src[(size_t)(k0 + ty + i) * N + n0 + tx];
  __syncthreads();
#pragma unroll
  for (int i = 0; i < 32; i += 8)
    dst[(size_t)(n0 + ty + i) * K + k0 + tx] = (__bf16)t[tx][ty + i];
}

// one block (384 threads) per row; bf16 output
__global__ __launch_bounds__(384) void ln_kernel(const float* __restrict__ src,
    __bf16* __restrict__ dst, const float* __restrict__ gs, const float* __restrict__ gb) {
  int row = blockIdx.x, tid = threadIdx.x;
  float v = src[(size_t)row * DMODEL + tid];
  float sum = v, sq = v * v;
#pragma unroll
  for (int off = 32; off; off >>= 1) { sum += __shfl_xor(sum, off); sq += __shfl_xor(sq, off); }
  __shared__ float rs[6], rq[6];
  __shared__ float smean, sinv;
  int wid = tid >> 6;
  if ((tid & 63) == 0) { rs[wid] = sum; rq[wid] = sq; }
  __syncthreads();
  if (tid == 0) {
    float S = 0.f, Q = 0.f;
    for (int w = 0; w < 6; w++) { S += rs[w]; Q += rq[w]; }
    float mean = S / (float)DMODEL;
    float var = Q / (float)DMODEL - mean * mean;
    smean = mean; sinv = rsqrtf(var + 1e-5f);
  }
  __syncthreads();
  dst[(size_t)row * DMODEL + tid] = (__bf16)((v - smean) * sinv * gs[tid] + gb[tid]);
}

// ---------------- bf16 MFMA GEMM: C = A @ Wt^T + bias, tile 128x128x64 ----------------
// async-split staging: k-step t+1 global loads issued while computing t.
// MODE 0: qkv   (A=xnb, writes head-major scale*Qh / Kh + transposed VTh)
// MODE 1: out   (A=aob,  Cf += acc+bias)   [residual]
// MODE 2: moe1  (A=gather(xnb) via tok_list&0xFFFF, relu, out bf16 a1)
// MODE 3: moe2  (A=a1b rows base+m, store gate*(acc+bias) to ab[a][t] bf16)
template<int MODE>
__global__ __launch_bounds__(256) void mgemm_kernel(
    const __bf16* __restrict__ Abf, const __bf16* __restrict__ Wt,
    const float* __restrict__ bias, float* __restrict__ Cf, __bf16* __restrict__ Cb,
    __bf16* __restrict__ pQ, __bf16* __restrict__ pK, __bf16* __restrict__ pV,
    const int* __restrict__ counts, const int* __restrict__ offs,
    const int* __restrict__ tok_list, const float* __restrict__ gate_list,
    int N, int K) {
  int e = 0, cnt = 0, base = 0;
  const int* tl = nullptr;
  int m0 = blockIdx.y * 128;
  if constexpr (MODE == 2 || MODE == 3) {
    e = blockIdx.z;
    cnt = counts[e];
    if (m0 >= cnt) return;
    base = offs[e];
    tl = tok_list + e * TOKENS;
    Wt += (size_t)e * N * K;
    bias += (size_t)e * N;
  }
  __shared__ __align__(16) __bf16 As[128][72];
  __shared__ __align__(16) __bf16 Bs[128][72];
  int tid = threadIdx.x;
  int n0 = blockIdx.x * 128;
  int w = tid >> 6, lane = tid & 63, c = lane & 15, g = lane >> 4;
  int arow[4], acol[4], brow[4], bcol4[4];
  long tok[4];
#pragma unroll
  for (int i = 0; i < 4; i++) {
    int chunk = tid + 256 * i;
    arow[i] = chunk >> 3;
    acol[i] = (chunk & 7) * 8;
    brow[i] = chunk >> 3;
    bcol4[i] = (chunk & 7) * 8;
    int mr = m0 + arow[i];
    if constexpr (MODE == 2)      tok[i] = (mr < cnt) ? (long)(tl[mr] & 0xFFFF) : -1;
    else if constexpr (MODE == 3) tok[i] = (mr < cnt) ? (long)(base + mr) : -1;
    else                          tok[i] = mr;
  }
  f32x4 acc[2][8];
#pragma unroll
  for (int m = 0; m < 2; m++)
#pragma unroll
    for (int n = 0; n < 8; n++) { acc[m][n][0] = 0.f; acc[m][n][1] = 0.f; acc[m][n][2] = 0.f; acc[m][n][3] = 0.f; }

  bf16x8 ra[4], rb[4];
  int nk = K >> 6;
  // prologue: load k-step 0 into regs
#pragma unroll
  for (int i = 0; i < 4; i++) {
    bf16x8 v = {};
    if (tok[i] >= 0) v = *(const bf16x8*)&Abf[(size_t)tok[i] * K + acol[i]];
    ra[i] = v;
    rb[i] = *(const bf16x8*)&Wt[(size_t)(n0 + brow[i]) * K + bcol4[i]];
  }
  for (int kt = 0; kt < nk; kt++) {
    // commit staged regs to LDS (prev consumers done via barrier at loop end)
#pragma unroll
    for (int i = 0; i < 4; i++) {
      *(bf16x8*)&As[arow[i]][acol[i]] = ra[i];
      *(bf16x8*)&Bs[brow[i]][bcol4[i]] = rb[i];
    }
    __syncthreads();
    // issue next k-step loads early; they fly during the MFMA phase
    if (kt + 1 < nk) {
      int k0 = (kt + 1) << 6;
#pragma unroll
      for (int i = 0; i < 4; i++) {
        bf16x8 v = {};
        if (tok[i] >= 0) v = *(const bf16x8*)&Abf[(size_t)tok[i] * K + k0 + acol[i]];
        ra[i] = v;
        rb[i] = *(const bf16x8*)&Wt[(size_t)(n0 + brow[i]) * K + k0 + bcol4[i]];
      }
    }
#pragma unroll
    for (int kk = 0; kk < 2; kk++) {
      bf16x8 a0 = *(const bf16x8*)&As[w * 32 + c][kk * 32 + g * 8];
      bf16x8 a1 = *(const bf16x8*)&As[w * 32 + 16 + c][kk * 32 + g * 8];
#pragma unroll
      for (int n = 0; n < 8; n++) {
        bf16x8 b = *(const bf16x8*)&Bs[n * 16 + c][kk * 32 + g * 8];
        acc[0][n] = __builtin_amdgcn_mfma_f32_16x16x32_bf16(a0, b, acc[0][n], 0, 0, 0);
        acc[1][n] = __builtin_amdgcn_mfma_f32_16x16x32_bf16(a1, b, acc[1][n], 0, 0, 0);
      }
    }
    __syncthreads();
  }
#pragma unroll
  for (int m = 0; m < 2; m++) {
    int row = w * 32 + m * 16 + 4 * g;                // local row (+r)
#pragma unroll
    for (int n = 0; n < 8; n++) {
      int col = n0 + n * 16 + c;
      float bv = bias[col];
#pragma unroll
      for (int r = 0; r < 4; r++) {
        float v = acc[m][n][r] + bv;
        int lr = row + r;
        if constexpr (MODE == 0) {
          int t = m0 + lr;
          int b = t >> 10, s = t & 1023;
          int which = col / 384;
          int rem = col - which * 384;
          int hd = rem / 48;
          int d = rem - hd * 48;
          size_t bh = (size_t)(b * 8 + hd);
          if (which == 0)      pQ[(bh * 1024 + s) * 48 + d] = (__bf16)(v * 0.14433756729740643f);
          else if (which == 1) pK[(bh * 1024 + s) * 48 + d] = (__bf16)v;
          else                 pV[(bh * 48 + d) * 1024 + s] = (__bf16)v;
        } else if constexpr (MODE == 1) {
          Cf[(size_t)(m0 + lr) * N + col] += v;
        } else if constexpr (MODE == 2) {
          if (m0 + lr < cnt) Cb[(size_t)(base + m0 + lr) * N + col] = (__bf16)fmaxf(v, 0.f);
        } else {
          if (m0 + lr < cnt) {
            int entry = tl[m0 + lr];
            int t = entry & 0xFFFF, a = entry >> 16;
            float gv = gate_list[e * TOKENS + m0 + lr];
            Cb[((size_t)a * TOKENS + t) * DMODEL + col] = (__bf16)(gv * v);
          }
        }
      }
    }
  }
}

// combine: h += ab[0] + ab[1]   (dense elementwise, 8 elems/thread)
__global__ __launch_bounds__(256) void combine_kernel(float* __restrict__ h,
    const __bf16* __restrict__ ab) {
  size_t i = ((size_t)blockIdx.x * 256 + threadIdx.x) * 8;
  bf16x8 a0 = *(const bf16x8*)&ab[i];
  bf16x8 a1 = *(const bf16x8*)&ab[(size_t)TOKENS * DMODEL + i];
  float* hp = h + i;
#pragma unroll
  for (int j = 0; j < 8; j++) hp[j] += (float)a0[j] + (float)a1[j];
}

// ---------------- bf16 MFMA flash attention, swapped-QK, shift-free softmax ----
// grid (bh=128, q0blk=16); 4 waves, wave w owns q rows q0+w*16 .. +15.
// Q pre-scaled by 1/sqrt(dh); scores bounded -> p = exp(s) directly (no max pass).
__global__ __launch_bounds__(256) void attn_kernel(const __bf16* __restrict__ Qh,
    const __bf16* __restrict__ Kh, const __bf16* __restrict__ VTh,
    __bf16* __restrict__ ao) {
  __shared__ __align__(16) __bf16 Ks[64][56];
  __shared__ __align__(16) __bf16 Vt[48][72];
  __shared__ __align__(16) __bf16 Ps[4][16][72];
  int bh = blockIdx.x;
  int q0 = blockIdx.y * 64;
  int tid = threadIdx.x;
  int w = tid >> 6, lane = tid & 63, c = lane & 15, g = lane >> 4;

  // Q fragments straight from global (B-operand: Q[q=c][k]); pre-scaled
  const __bf16* qrow = Qh + ((size_t)bh * 1024 + q0 + w * 16 + c) * 48;
  bf16x8 qb0 = *(const bf16x8*)&qrow[g * 8];
  bf16x8 qb1 = {};
  if (g < 2) qb1 = *(const bf16x8*)&qrow[32 + g * 8];

  const __bf16* kb = Kh + (size_t)bh * 1024 * 48;
  const __bf16* vb = VTh + (size_t)bh * 48 * 1024;

  // hoisted staging routes: 768 vec8 slots over 3 chunks of 256 threads
  // chunk0 (e=tid): K rows 0..42; chunk1 (e=tid+256): K tail / V head; chunk2: V tail
  int r0 = tid / 6, p0 = tid - r0 * 6;
  __bf16* dst0 = &Ks[r0][p0 * 8];
  int off0 = r0 * 48 + p0 * 8;
  int e1 = tid + 256;
  __bf16* dst1; int off1; bool v1;
  if (e1 < 384) { int r = e1 / 6, p = e1 - r * 6; dst1 = &Ks[r][p * 8]; off1 = r * 48 + p * 8; v1 = false; }
  else          { int i = e1 - 384; int d = i >> 3, p = i & 7; dst1 = &Vt[d][p * 8]; off1 = d * 1024 + p * 8; v1 = true; }
  int i2 = tid + 512 - 384;
  int d2 = i2 >> 3, p2 = i2 & 7;
  __bf16* dst2 = &Vt[d2][p2 * 8];
  int off2 = d2 * 1024 + p2 * 8;

  f32x4 acc[3];
#pragma unroll
  for (int t = 0; t < 3; t++) { acc[t][0] = 0.f; acc[t][1] = 0.f; acc[t][2] = 0.f; acc[t][3] = 0.f; }
  float lsum = 0.f;                              // per-lane partial row-sum

  for (int kt = 0; kt < 16; kt++) {
    __syncthreads();
    const __bf16* kbt = kb + (size_t)kt * 3072;  // 64*48
    const __bf16* vbt = vb + kt * 64;
    *(bf16x8*)dst0 = *(const bf16x8*)(kbt + off0);
    *(bf16x8*)dst1 = *(const bf16x8*)((v1 ? vbt : kbt) + off1);
    *(bf16x8*)dst2 = *(const bf16x8*)(vbt + off2);
    __syncthreads();

    // S^T = K Q^T : lane (c,g) gets S[q=c][kv=16f+4g+r]
    f32x4 s4[4];
#pragma unroll
    for (int f = 0; f < 4; f++) {
      bf16x8 ka0 = *(const bf16x8*)&Ks[f * 16 + c][g * 8];
      bf16x8 ka1 = {};
      if (g < 2) ka1 = *(const bf16x8*)&Ks[f * 16 + c][32 + g * 8];
      f32x4 z = {};
      z = __builtin_amdgcn_mfma_f32_16x16x32_bf16(ka0, qb0, z, 0, 0, 0);
      s4[f] = __builtin_amdgcn_mfma_f32_16x16x32_bf16(ka1, qb1, z, 0, 0, 0);
    }
    // shift-free softmax numerator: p = exp(s); accumulate local partial sum
#pragma unroll
    for (int f = 0; f < 4; f++) {
      float pv0 = __expf(s4[f][0]);
      float pv1 = __expf(s4[f][1]);
      float pv2 = __expf(s4[f][2]);
      float pv3 = __expf(s4[f][3]);
      lsum += (pv0 + pv1) + (pv2 + pv3);
      bf16x4 pk = { (__bf16)pv0, (__bf16)pv1, (__bf16)pv2, (__bf16)pv3 };
      *(bf16x4*)&Ps[w][c][f * 16 + 4 * g] = pk;  // cols 16f+4g..+3 (8B aligned)
    }
    bf16x8 pa0 = *(const bf16x8*)&Ps[w][c][g * 8];
    bf16x8 pa1 = *(const bf16x8*)&Ps[w][c][32 + g * 8];
    // O += P V : B-operand = V^T[dh=c][kv=k] (Vt natural rows)
#pragma unroll
    for (int t = 0; t < 3; t++) {
      bf16x8 vb0 = *(const bf16x8*)&Vt[t * 16 + c][g * 8];
      bf16x8 vb1 = *(const bf16x8*)&Vt[t * 16 + c][32 + g * 8];
      acc[t] = __builtin_amdgcn_mfma_f32_16x16x32_bf16(pa0, vb0, acc[t], 0, 0, 0);
      acc[t] = __builtin_amdgcn_mfma_f32_16x16x32_bf16(pa1, vb1, acc[t], 0, 0, 0);
    }
  }
  // single cross-g reduce of l at the end
  float lt = lsum;
  lt += __shfl_xor(lt, 16, 64);
  lt += __shfl_xor(lt, 32, 64);
  float linv[4];
#pragma unroll
  for (int r = 0; r < 4; r++) linv[r] = 1.f / __shfl(lt, 4 * g + r, 64);
  int b = bh >> 3, hh = bh & 7;
#pragma unroll
  for (int t = 0; t < 3; t++)
#pragma unroll
    for (int r = 0; r < 4; r++)
      ao[((size_t)(b * SEQ + q0 + w * 16 + 4 * g + r)) * DMODEL + hh * 48 + t * 16 + c] =
          (__bf16)(acc[t][r] * linv[r]);
}

// ---------------- gating: block = 32 tokens (512 blocks), block-aggregated atomics ----
__global__ __launch_bounds__(256) void gate_kernel(const __bf16* __restrict__ xnb,
    const float* __restrict__ gw, int* __restrict__ counts, float* __restrict__ sum_probs,
    int* __restrict__ tok_list, float* __restrict__ gate_list) {
  __shared__ float Gs[NEXP][DMODEL];
  __shared__ float simp[NEXP];
  __shared__ int hist[NEXP], basep[NEXP];
  __shared__ unsigned char tokE[32][2];
  __shared__ float tokG[32][2];
  __shared__ short rankS[32][2];
  int tid = threadIdx.x;
  for (int i = tid; i < DMODEL * NEXP; i += 256) {
    int d = i >> 3, e2 = i & 7;
    Gs[e2][d] = gw[i];
  }
  if (tid < NEXP) { simp[tid] = 0.f; hist[tid] = 0; }
  __syncthreads();
  int w = tid >> 6, lane = tid & 63;
  int tbase = blockIdx.x * 32 + w * 8;
  float impacc[NEXP] = {};
  for (int tt = 0; tt < 8; tt++) {
    int t = tbase + tt;
    float p[NEXP] = {};
#pragma unroll
    for (int j = 0; j < 6; j++) {
      int d = lane + 64 * j;
      float xv = (float)xnb[(size_t)t * DMODEL + d];
#pragma unroll
      for (int e2 = 0; e2 < NEXP; e2++) p[e2] += xv * Gs[e2][d];
    }
#pragma unroll
    for (int off = 32; off; off >>= 1)
#pragma unroll
      for (int e2 = 0; e2 < NEXP; e2++) p[e2] += __shfl_xor(p[e2], off);
    float mx = p[0];
#pragma unroll
    for (int e2 = 1; e2 < NEXP; e2++) mx = fmaxf(mx, p[e2]);
    float s = 0.f;
#pragma unroll
    for (int e2 = 0; e2 < NEXP; e2++) { p[e2] = __expf(p[e2] - mx); s += p[e2]; }
    float inv = 1.f / s;
#pragma unroll
    for (int e2 = 0; e2 < NEXP; e2++) { p[e2] *= inv; impacc[e2] += p[e2]; }
    int i0 = 0; float v0 = p[0];
#pragma unroll
    for (int e2 = 1; e2 < NEXP; e2++) if (p[e2] > v0) { v0 = p[e2]; i0 = e2; }
    int i1 = -1; float v1 = -INFINITY;
#pragma unroll
    for (int e2 = 0; e2 < NEXP; e2++) if (e2 != i0 && p[e2] > v1) { v1 = p[e2]; i1 = e2; }
    if (lane == 0) {
      float gsum = v0 + v1;
      int r0 = atomicAdd(&hist[i0], 1);
      int r1 = atomicAdd(&hist[i1], 1);
      int sl = w * 8 + tt;
      tokE[sl][0] = (unsigned char)i0; tokE[sl][1] = (unsigned char)i1;
      tokG[sl][0] = v0 / gsum;         tokG[sl][1] = v1 / gsum;
      rankS[sl][0] = (short)r0;        rankS[sl][1] = (short)r1;
    }
  }
  if (lane == 0)
#pragma unroll
    for (int e2 = 0; e2 < NEXP; e2++) atomicAdd(&simp[e2], impacc[e2]);
  __syncthreads();
  if (tid < NEXP) {
    basep[tid] = atomicAdd(&counts[tid], hist[tid]);
    atomicAdd(&sum_probs[tid], simp[tid]);
  }
  __syncthreads();
  int t0 = blockIdx.x * 32;
  if (tid < 64) {
    int sl = tid >> 1, a = tid & 1;
    int e2 = tokE[sl][a];
    int pos = basep[e2] + rankS[sl][a];
    tok_list[e2 * TOKENS + pos] = (t0 + sl) | (a << 16);
    gate_list[e2 * TOKENS + pos] = tokG[sl][a];
  }
}

// prefix offsets (64-padded) + aux loss contribution
__global__ void aux_kernel(const int* __restrict__ counts, int* __restrict__ offs,
                           const float* __restrict__ sum_probs, float* __restrict__ total_moe) {
  int off = 0;
  float tm = 0.f;
  for (int e = 0; e < NEXP; e++) {
    offs[e] = off;
    off += ((counts[e] + 63) >> 6) << 6;
    tm += sum_probs[e] * (float)counts[e];
  }
  offs[NEXP] = off;
  *total_moe += (float)NEXP * tm / ((float)TOKENS * (float)TOKENS);
}

// ---------------- attention-pool head, split for parallelism ----------------
__global__ __launch_bounds__(256) void head1_kernel(const float* __restrict__ h,
    const float* __restrict__ att_w, const float* __restrict__ att_b,
    float* __restrict__ logits) {
  int tid = threadIdx.x;
  int w = tid >> 6, lane = tid & 63;
  float4 aw0 = *(const float4*)&att_w[lane * 4];
  float2 aw1 = *(const float2*)&att_w[256 + lane * 2];
  float ab = att_b[0];
  for (int i = w; i < 128; i += 4) {
    int t = blockIdx.x * 128 + i;
    const float* hr = h + (size_t)t * DMODEL;
    float4 v4 = *(const float4*)&hr[lane * 4];
    float2 v2 = *(const float2*)&hr[256 + lane * 2];
    float dot = v4.x * aw0.x + v4.y * aw0.y + v4.z * aw0.z + v4.w * aw0.w
              + v2.x * aw1.x + v2.y * aw1.y;
#pragma unroll
    for (int off = 32; off; off >>= 1) dot += __shfl_xor(dot, off);
    if (lane == 0) logits[t] = dot + ab;
  }
}

__global__ __launch_bounds__(256) void head2_kernel(float* __restrict__ logits) {
  int b = blockIdx.x, tid = threadIdx.x;
  int w = tid >> 6, lane = tid & 63;
  float* lb = logits + b * SEQ;
  __shared__ float red[4];
  float lv[4];
  float mx = -INFINITY;
#pragma unroll
  for (int i = 0; i < 4; i++) { lv[i] = lb[tid + 256 * i]; mx = fmaxf(mx, lv[i]); }
#pragma unroll
  for (int off = 32; off; off >>= 1) mx = fmaxf(mx, __shfl_xor(mx, off));
  if (lane == 0) red[w] = mx;
  __syncthreads();
  mx = fmaxf(fmaxf(red[0], red[1]), fmaxf(red[2], red[3]));
  __syncthreads();
  float s = 0.f;
#pragma unroll
  for (int i = 0; i < 4; i++) { lv[i] = __expf(lv[i] - mx); s += lv[i]; }
#pragma unroll
  for (int off = 32; off; off >>= 1) s += __shfl_xor(s, off);
  if (lane == 0) red[w] = s;
  __syncthreads();
  float inv = 1.f / (red[0] + red[1] + red[2] + red[3]);
#pragma unroll
  for (int i = 0; i < 4; i++) lb[tid + 256 * i] = lv[i] * inv;
}

__global__ __launch_bounds__(256) void head3_kernel(const float* __restrict__ h,
    const float* __restrict__ wnorm, const float* __restrict__ head_w,
    float* __restrict__ part) {
  int b = blockIdx.x, dc = blockIdx.y;
  int tid = threadIdx.x;
  int d = tid & 63, sg = tid >> 6;
  const float* hb = h + (size_t)b * SEQ * DMODEL + dc * 64 + d;
  const float* wb = wnorm + b * SEQ;
  float acc = 0.f;
  for (int s = sg * 256; s < sg * 256 + 256; s++)
    acc += wb[s] * hb[(size_t)s * DMODEL];
  __shared__ float red[256];
  red[tid] = acc;
  __syncthreads();
  if (sg == 0) {
    float pooled = red[d] + red[64 + d] + red[128 + d] + red[192 + d];
    float pd = pooled * head_w[dc * 64 + d];
#pragma unroll
    for (int off = 32; off; off >>= 1) pd += __shfl_xor(pd, off);
    if (d == 0) part[b * 6 + dc] = pd;
  }
}

__global__ void head4_kernel(const float* __restrict__ part,
                             const float* __restrict__ head_b, float* __restrict__ out) {
  int b = threadIdx.x;
  if (b < 16) {
    float s = head_b[0];
#pragma unroll
    for (int dc = 0; dc < 6; dc++) s += part[b * 6 + dc];
    out[b] = s;
  }
}

// ---------------- launch ----------------
extern "C" void kernel_launch(void* const* d_in, const int* in_sizes, int n_in,
                              void* d_out, int out_size, void* d_ws, size_t ws_size,
                              hipStream_t stream) {
  (void)in_sizes; (void)n_in; (void)out_size; (void)ws_size;
  const float* x      = (const float*)d_in[0];
  const float* proj_w = (const float*)d_in[1];
  const float* proj_b = (const float*)d_in[2];
  const float* qkv_w  = (const float*)d_in[3];
  const float* qkv_b  = (const float*)d_in[4];
  const float* out_w  = (const float*)d_in[5];
  const float* out_b  = (const float*)d_in[6];
  const float* n1_s   = (const float*)d_in[7];
  const float* n1_b   = (const float*)d_in[8];
  const float* n2_s   = (const float*)d_in[9];
  const float* n2_b   = (const float*)d_in[10];
  const float* gate_w = (const float*)d_in[11];
  const float* e_w1   = (const float*)d_in[12];
  const float* e_b1   = (const float*)d_in[13];
  const float* e_w2   = (const float*)d_in[14];
  const float* e_b2   = (const float*)d_in[15];
  const float* att_w  = (const float*)d_in[16];
  const float* att_b  = (const float*)d_in[17];
  const float* head_w = (const float*)d_in[18];
  const float* head_b = (const float*)d_in[19];
  float* out = (float*)d_out;

  // workspace layout (bytes):
  // h fp32 25.2MB | {xnb 12.6 | aob 12.6}MB (reused as ab[2][16384][384] during moe2)
  // | uni region 51.1MB: {Qh 12.6 | Kh 12.6 | VTh 12.6} during attn, a1b during MoE
  // | Wt bf16 31.9MB | control
  char* wsb = (char*)d_ws;
  float*  h    = (float*)(wsb);
  __bf16* xnb  = (__bf16*)(wsb + 25165824);
  __bf16* aob  = (__bf16*)(wsb + 37748736);
  __bf16* ab   = (__bf16*)(wsb + 25165824);        // [2][16384][384] aliases xnb+aob
  __bf16* uni  = (__bf16*)(wsb + 50331648);
  __bf16* Qh   = uni;                              // [128][1024][48] = 12,582,912 B
  __bf16* Khd  = (__bf16*)(wsb + 62914560);
  __bf16* VTh  = (__bf16*)(wsb + 75497472);
  __bf16* qkvWt = (__bf16*)(wsb + 101449728);   // [3][1152][384]
  __bf16* outWt = (__bf16*)(wsb + 104103936);   // [3][384][384]
  __bf16* e1Wt  = (__bf16*)(wsb + 104988672);   // [3*8][768][384]
  __bf16* e2Wt  = (__bf16*)(wsb + 119144448);   // [3*8][384][768]
  char* sm = wsb + 133300224;
  int*   counts    = (int*)(sm);
  int*   offs      = (int*)(sm + 64);
  float* sum_probs = (float*)(sm + 128);
  float* total_moe = (float*)(sm + 192);
  int*   tok_list  = (int*)(sm + 256);
  float* gate_list = (float*)(sm + 256 + 524288);
  float* logits    = (float*)(sm + 1048832);
  float* part      = (float*)(sm + 1048832 + 65536);

  // one-shot weight transpose+cast (runs every call; deterministic)
  convw_kernel<<<dim3(36, 12, 3), 256, 0, stream>>>(qkv_w, qkvWt, 384, 1152);
  convw_kernel<<<dim3(12, 12, 3), 256, 0, stream>>>(out_w, outWt, 384, 384);
  convw_kernel<<<dim3(24, 12, 24), 256, 0, stream>>>(e_w1, e1Wt, 384, 768);
  convw_kernel<<<dim3(12, 24, 24), 256, 0, stream>>>(e_w2, e2Wt, 768, 384);

  init_kernel<<<1, 1, 0, stream>>>(total_moe);
  proj_kernel<<<TOKENS * DMODEL / 256, 256, 0, stream>>>(x, proj_w, proj_b, h);

  for (int l = 0; l < NL; l++) {
    ln_kernel<<<TOKENS, 384, 0, stream>>>(h, xnb, n1_s + l * DMODEL, n1_b + l * DMODEL);
    mgemm_kernel<0><<<dim3(9, 128), 256, 0, stream>>>(
        xnb, qkvWt + (size_t)l * 1152 * 384, qkv_b + l * 1152, nullptr, nullptr,
        Qh, Khd, VTh, nullptr, nullptr, nullptr, nullptr, 1152, 384);
    attn_kernel<<<dim3(128, 16), 256, 0, stream>>>(Qh, Khd, VTh, aob);
    mgemm_kernel<1><<<dim3(3, 128), 256, 0, stream>>>(
        aob, outWt + (size_t)l * 384 * 384, out_b + l * 384, h, nullptr,
        nullptr, nullptr, nullptr, nullptr, nullptr, nullptr, nullptr, 384, 384);
    ln_kernel<<<TOKENS, 384, 0, stream>>>(h, xnb, n2_s + l * DMODEL, n2_b + l * DMODEL);
    zero_cnt_kernel<<<1, 64, 0, stream>>>(counts, sum_probs);
    gate_kernel<<<512, 256, 0, stream>>>(xnb, gate_w + (size_t)l * DMODEL * NEXP,
                                         counts, sum_probs, tok_list, gate_list);
    aux_kernel<<<1, 1, 0, stream>>>(counts, offs, sum_probs, total_moe);
    mgemm_kernel<2><<<dim3(6, 128, 8), 256, 0, stream>>>(
        xnb, e1Wt + (size_t)l * 8 * 768 * 384, e_b1 + l * 8 * FFDIM, nullptr, uni,
        nullptr, nullptr, nullptr, counts, offs, tok_list, nullptr, 768, 384);
    mgemm_kernel<3><<<dim3(3, 128, 8), 256, 0, stream>>>(
        uni, e2Wt + (size_t)l * 8 * 384 * 768, e_b2 + l * 8 * DMODEL, nullptr, ab,
        nullptr, nullptr, nullptr, counts, offs, tok_list, gate_list, 384, 768);
    combine_kernel<<<TOKENS * DMODEL / (256 * 8), 256, 0, stream>>>(h, ab);
  }

  head1_kernel<<<128, 256, 0, stream>>>(h, att_w, att_b, logits);
  head2_kernel<<<16, 256, 0, stream>>>(logits);
  head3_kernel<<<dim3(16, 6), 256, 0, stream>>>(h, logits, head_w, part);
  head4_kernel<<<1, 64, 0, stream>>>(part, head_b, out);
  finalize_kernel<<<1, 1, 0, stream>>>(total_moe, out);
}

// Round 10
// 1077.797 us; speedup vs baseline: 6.8840x; 1.0696x over previous
//
#include <hip/hip_runtime.h>
#include <hip/hip_bf16.h>
#include <math.h>

// RULPredictionModel: B=16 S=1024 D=384 H=8 DH=48 L=3 E=8 FF=768 TOP_K=2
#define TOKENS 16384
#define DMODEL 384
#define SEQ 1024
#define NHEAD 8
#define DHEAD 48
#define NEXP 8
#define FFDIM 768
#define NL 3

typedef __bf16 bf16x8 __attribute__((ext_vector_type(8)));
typedef __bf16 bf16x4 __attribute__((ext_vector_type(4)));
typedef float f32x4 __attribute__((ext_vector_type(4)));

// ---------------- tiny kernels ----------------
__global__ void init_kernel(float* total_moe) { *total_moe = 0.f; }

__global__ void zero_cnt_kernel(int* counts, float* sum_probs) {
  int t = threadIdx.x;
  if (t < NEXP) { counts[t] = 0; sum_probs[t] = 0.f; }
}

__global__ void finalize_kernel(const float* total_moe, float* out) { out[16] = *total_moe; }

__global__ __launch_bounds__(256) void proj_kernel(const float* __restrict__ x,
    const float* __restrict__ pw, const float* __restrict__ pb, float* __restrict__ h) {
  int i = blockIdx.x * 256 + threadIdx.x;
  int t = i / DMODEL;
  int d = i - t * DMODEL;
  h[i] = x[t] * pw[d] + pb[d];
}

// weight transpose + cast: src fp32 [K][N] (batched) -> dst bf16 [N][K]
__global__ __launch_bounds__(256) void convw_kernel(const float* __restrict__ src,
    __bf16* __restrict__ dst, int K, int N) {
  __shared__ float t[32][33];
  size_t boff = (size_t)blockIdx.z * K * N;
  src += boff; dst += boff;
  int k0 = blockIdx.y * 32, n0 = blockIdx.x * 32;
  int tx = threadIdx.x & 31, ty = threadIdx.x >> 5;   // 32 x 8
#pragma unroll
  for (int i = 0; i < 32; i += 8) t[ty + i][tx] = src[(size_t)(k0 + ty + i) * N + n0 + tx];
  __syncthreads();
#pragma unroll
  for (int i = 0; i < 32; i += 8)
    dst[(size_t)(n0 + ty + i) * K + k0 + tx] = (__bf16)t[tx][ty + i];
}

// one block (384 threads) per row; bf16 output
__global__ __launch_bounds__(384) void ln_kernel(const float* __restrict__ src,
    __bf16* __restrict__ dst, const float* __restrict__ gs, const float* __restrict__ gb) {
  int row = blockIdx.x, tid = threadIdx.x;
  float v = src[(size_t)row * DMODEL + tid];
  float sum = v, sq = v * v;
#pragma unroll
  for (int off = 32; off; off >>= 1) { sum += __shfl_xor(sum, off); sq += __shfl_xor(sq, off); }
  __shared__ float rs[6], rq[6];
  __shared__ float smean, sinv;
  int wid = tid >> 6;
  if ((tid & 63) == 0) { rs[wid] = sum; rq[wid] = sq; }
  __syncthreads();
  if (tid == 0) {
    float S = 0.f, Q = 0.f;
    for (int w = 0; w < 6; w++) { S += rs[w]; Q += rq[w]; }
    float mean = S / (float)DMODEL;
    float var = Q / (float)DMODEL - mean * mean;
    smean = mean; sinv = rsqrtf(var + 1e-5f);
  }
  __syncthreads();
  dst[(size_t)row * DMODEL + tid] = (__bf16)((v - smean) * sinv * gs[tid] + gb[tid]);
}

// ---------------- bf16 MFMA GEMM: C = A @ Wt^T + bias, tile 128x128x64 ----------------
// async-split staging: k-step t+1 global loads issued while computing t.
// MODE 0: qkv   (A=xnb, writes head-major scale*Qh / Kh + transposed VTh)
// MODE 1: out   (A=aob,  Cf += acc+bias)   [residual]
// MODE 2: moe1  (A=gather(xnb) via tok_list&0xFFFF, relu, out bf16 a1)
// MODE 3: moe2  (A=a1b rows base+m, store gate*(acc+bias) to ab[a][t] bf16)
template<int MODE>
__global__ __launch_bounds__(256) void mgemm_kernel(
    const __bf16* __restrict__ Abf, const __bf16* __restrict__ Wt,
    const float* __restrict__ bias, float* __restrict__ Cf, __bf16* __restrict__ Cb,
    __bf16* __restrict__ pQ, __bf16* __restrict__ pK, __bf16* __restrict__ pV,
    const int* __restrict__ counts, const int* __restrict__ offs,
    const int* __restrict__ tok_list, const float* __restrict__ gate_list,
    int N, int K) {
  int e = 0, cnt = 0, base = 0;
  const int* tl = nullptr;
  int m0 = blockIdx.y * 128;
  if constexpr (MODE == 2 || MODE == 3) {
    e = blockIdx.z;
    cnt = counts[e];
    if (m0 >= cnt) return;
    base = offs[e];
    tl = tok_list + e * TOKENS;
    Wt += (size_t)e * N * K;
    bias += (size_t)e * N;
  }
  __shared__ __align__(16) __bf16 As[128][72];
  __shared__ __align__(16) __bf16 Bs[128][72];
  int tid = threadIdx.x;
  int n0 = blockIdx.x * 128;
  int w = tid >> 6, lane = tid & 63, c = lane & 15, g = lane >> 4;
  int arow[4], acol[4], brow[4], bcol4[4];
  long tok[4];
#pragma unroll
  for (int i = 0; i < 4; i++) {
    int chunk = tid + 256 * i;
    arow[i] = chunk >> 3;
    acol[i] = (chunk & 7) * 8;
    brow[i] = chunk >> 3;
    bcol4[i] = (chunk & 7) * 8;
    int mr = m0 + arow[i];
    if constexpr (MODE == 2)      tok[i] = (mr < cnt) ? (long)(tl[mr] & 0xFFFF) : -1;
    else if constexpr (MODE == 3) tok[i] = (mr < cnt) ? (long)(base + mr) : -1;
    else                          tok[i] = mr;
  }
  f32x4 acc[2][8];
#pragma unroll
  for (int m = 0; m < 2; m++)
#pragma unroll
    for (int n = 0; n < 8; n++) { acc[m][n][0] = 0.f; acc[m][n][1] = 0.f; acc[m][n][2] = 0.f; acc[m][n][3] = 0.f; }

  bf16x8 ra[4], rb[4];
  int nk = K >> 6;
  // prologue: load k-step 0 into regs
#pragma unroll
  for (int i = 0; i < 4; i++) {
    bf16x8 v = {};
    if (tok[i] >= 0) v = *(const bf16x8*)&Abf[(size_t)tok[i] * K + acol[i]];
    ra[i] = v;
    rb[i] = *(const bf16x8*)&Wt[(size_t)(n0 + brow[i]) * K + bcol4[i]];
  }
  for (int kt = 0; kt < nk; kt++) {
    // commit staged regs to LDS (prev consumers done via barrier at loop end)
#pragma unroll
    for (int i = 0; i < 4; i++) {
      *(bf16x8*)&As[arow[i]][acol[i]] = ra[i];
      *(bf16x8*)&Bs[brow[i]][bcol4[i]] = rb[i];
    }
    __syncthreads();
    // issue next k-step loads early; they fly during the MFMA phase
    if (kt + 1 < nk) {
      int k0 = (kt + 1) << 6;
#pragma unroll
      for (int i = 0; i < 4; i++) {
        bf16x8 v = {};
        if (tok[i] >= 0) v = *(const bf16x8*)&Abf[(size_t)tok[i] * K + k0 + acol[i]];
        ra[i] = v;
        rb[i] = *(const bf16x8*)&Wt[(size_t)(n0 + brow[i]) * K + k0 + bcol4[i]];
      }
    }
#pragma unroll
    for (int kk = 0; kk < 2; kk++) {
      bf16x8 a0 = *(const bf16x8*)&As[w * 32 + c][kk * 32 + g * 8];
      bf16x8 a1 = *(const bf16x8*)&As[w * 32 + 16 + c][kk * 32 + g * 8];
#pragma unroll
      for (int n = 0; n < 8; n++) {
        bf16x8 b = *(const bf16x8*)&Bs[n * 16 + c][kk * 32 + g * 8];
        acc[0][n] = __builtin_amdgcn_mfma_f32_16x16x32_bf16(a0, b, acc[0][n], 0, 0, 0);
        acc[1][n] = __builtin_amdgcn_mfma_f32_16x16x32_bf16(a1, b, acc[1][n], 0, 0, 0);
      }
    }
    __syncthreads();
  }
#pragma unroll
  for (int m = 0; m < 2; m++) {
    int row = w * 32 + m * 16 + 4 * g;                // local row (+r)
#pragma unroll
    for (int n = 0; n < 8; n++) {
      int col = n0 + n * 16 + c;
      float bv = bias[col];
#pragma unroll
      for (int r = 0; r < 4; r++) {
        float v = acc[m][n][r] + bv;
        int lr = row + r;
        if constexpr (MODE == 0) {
          int t = m0 + lr;
          int b = t >> 10, s = t & 1023;
          int which = col / 384;
          int rem = col - which * 384;
          int hd = rem / 48;
          int d = rem - hd * 48;
          size_t bh = (size_t)(b * 8 + hd);
          if (which == 0)      pQ[(bh * 1024 + s) * 48 + d] = (__bf16)(v * 0.14433756729740643f);
          else if (which == 1) pK[(bh * 1024 + s) * 48 + d] = (__bf16)v;
          else                 pV[(bh * 48 + d) * 1024 + s] = (__bf16)v;
        } else if constexpr (MODE == 1) {
          Cf[(size_t)(m0 + lr) * N + col] += v;
        } else if constexpr (MODE == 2) {
          if (m0 + lr < cnt) Cb[(size_t)(base + m0 + lr) * N + col] = (__bf16)fmaxf(v, 0.f);
        } else {
          if (m0 + lr < cnt) {
            int entry = tl[m0 + lr];
            int t = entry & 0xFFFF, a = entry >> 16;
            float gv = gate_list[e * TOKENS + m0 + lr];
            Cb[((size_t)a * TOKENS + t) * DMODEL + col] = (__bf16)(gv * v);
          }
        }
      }
    }
  }
}

// combine: h += ab[0] + ab[1]   (dense elementwise, 8 elems/thread)
__global__ __launch_bounds__(256) void combine_kernel(float* __restrict__ h,
    const __bf16* __restrict__ ab) {
  size_t i = ((size_t)blockIdx.x * 256 + threadIdx.x) * 8;
  bf16x8 a0 = *(const bf16x8*)&ab[i];
  bf16x8 a1 = *(const bf16x8*)&ab[(size_t)TOKENS * DMODEL + i];
  float* hp = h + i;
#pragma unroll
  for (int j = 0; j < 8; j++) hp[j] += (float)a0[j] + (float)a1[j];
}

// ---------------- bf16 MFMA flash attention, swapped-QK, shift-free softmax ----
// grid (bh=128, q0blk=16); 4 waves, wave w owns q rows q0+w*16 .. +15.
// Q pre-scaled by 1/sqrt(dh); scores bounded -> p = exp(s) directly (no max pass).
__global__ __launch_bounds__(256) void attn_kernel(const __bf16* __restrict__ Qh,
    const __bf16* __restrict__ Kh, const __bf16* __restrict__ VTh,
    __bf16* __restrict__ ao) {
  __shared__ __align__(16) __bf16 Ks[64][56];
  __shared__ __align__(16) __bf16 Vt[48][72];
  __shared__ __align__(16) __bf16 Ps[4][16][72];
  int bh = blockIdx.x;
  int q0 = blockIdx.y * 64;
  int tid = threadIdx.x;
  int w = tid >> 6, lane = tid & 63, c = lane & 15, g = lane >> 4;

  // Q fragments straight from global (B-operand: Q[q=c][k]); pre-scaled
  const __bf16* qrow = Qh + ((size_t)bh * 1024 + q0 + w * 16 + c) * 48;
  bf16x8 qb0 = *(const bf16x8*)&qrow[g * 8];
  bf16x8 qb1 = {};
  if (g < 2) qb1 = *(const bf16x8*)&qrow[32 + g * 8];

  const __bf16* kb = Kh + (size_t)bh * 1024 * 48;
  const __bf16* vb = VTh + (size_t)bh * 48 * 1024;

  // hoisted staging routes: 768 vec8 slots over 3 chunks of 256 threads
  int r0 = tid / 6, p0 = tid - r0 * 6;
  __bf16* dst0 = &Ks[r0][p0 * 8];
  int off0 = r0 * 48 + p0 * 8;
  int e1 = tid + 256;
  __bf16* dst1; int off1; bool v1;
  if (e1 < 384) { int r = e1 / 6, p = e1 - r * 6; dst1 = &Ks[r][p * 8]; off1 = r * 48 + p * 8; v1 = false; }
  else          { int i = e1 - 384; int d = i >> 3, p = i & 7; dst1 = &Vt[d][p * 8]; off1 = d * 1024 + p * 8; v1 = true; }
  int i2 = tid + 512 - 384;
  int d2 = i2 >> 3, p2 = i2 & 7;
  __bf16* dst2 = &Vt[d2][p2 * 8];
  int off2 = d2 * 1024 + p2 * 8;

  f32x4 acc[3];
#pragma unroll
  for (int t = 0; t < 3; t++) { acc[t][0] = 0.f; acc[t][1] = 0.f; acc[t][2] = 0.f; acc[t][3] = 0.f; }
  float lsum = 0.f;                              // per-lane partial row-sum

  for (int kt = 0; kt < 16; kt++) {
    __syncthreads();
    const __bf16* kbt = kb + (size_t)kt * 3072;  // 64*48
    const __bf16* vbt = vb + kt * 64;
    *(bf16x8*)dst0 = *(const bf16x8*)(kbt + off0);
    *(bf16x8*)dst1 = *(const bf16x8*)((v1 ? vbt : kbt) + off1);
    *(bf16x8*)dst2 = *(const bf16x8*)(vbt + off2);
    __syncthreads();

    // S^T = K Q^T : lane (c,g) gets S[q=c][kv=16f+4g+r]
    f32x4 s4[4];
#pragma unroll
    for (int f = 0; f < 4; f++) {
      bf16x8 ka0 = *(const bf16x8*)&Ks[f * 16 + c][g * 8];
      bf16x8 ka1 = {};
      if (g < 2) ka1 = *(const bf16x8*)&Ks[f * 16 + c][32 + g * 8];
      f32x4 z = {};
      z = __builtin_amdgcn_mfma_f32_16x16x32_bf16(ka0, qb0, z, 0, 0, 0);
      s4[f] = __builtin_amdgcn_mfma_f32_16x16x32_bf16(ka1, qb1, z, 0, 0, 0);
    }
    // shift-free softmax numerator: p = exp(s); accumulate local partial sum
#pragma unroll
    for (int f = 0; f < 4; f++) {
      float pv0 = __expf(s4[f][0]);
      float pv1 = __expf(s4[f][1]);
      float pv2 = __expf(s4[f][2]);
      float pv3 = __expf(s4[f][3]);
      lsum += (pv0 + pv1) + (pv2 + pv3);
      bf16x4 pk = { (__bf16)pv0, (__bf16)pv1, (__bf16)pv2, (__bf16)pv3 };
      *(bf16x4*)&Ps[w][c][f * 16 + 4 * g] = pk;  // cols 16f+4g..+3 (8B aligned)
    }
    bf16x8 pa0 = *(const bf16x8*)&Ps[w][c][g * 8];
    bf16x8 pa1 = *(const bf16x8*)&Ps[w][c][32 + g * 8];
    // O += P V : B-operand = V^T[dh=c][kv=k] (Vt natural rows)
#pragma unroll
    for (int t = 0; t < 3; t++) {
      bf16x8 vb0 = *(const bf16x8*)&Vt[t * 16 + c][g * 8];
      bf16x8 vb1 = *(const bf16x8*)&Vt[t * 16 + c][32 + g * 8];
      acc[t] = __builtin_amdgcn_mfma_f32_16x16x32_bf16(pa0, vb0, acc[t], 0, 0, 0);
      acc[t] = __builtin_amdgcn_mfma_f32_16x16x32_bf16(pa1, vb1, acc[t], 0, 0, 0);
    }
  }
  // single cross-g reduce of l at the end
  float lt = lsum;
  lt += __shfl_xor(lt, 16, 64);
  lt += __shfl_xor(lt, 32, 64);
  float linv[4];
#pragma unroll
  for (int r = 0; r < 4; r++) linv[r] = 1.f / __shfl(lt, 4 * g + r, 64);
  int b = bh >> 3, hh = bh & 7;
#pragma unroll
  for (int t = 0; t < 3; t++)
#pragma unroll
    for (int r = 0; r < 4; r++)
      ao[((size_t)(b * SEQ + q0 + w * 16 + 4 * g + r)) * DMODEL + hh * 48 + t * 16 + c] =
          (__bf16)(acc[t][r] * linv[r]);
}

// ---------------- gating: block = 32 tokens (512 blocks), block-aggregated atomics ----
__global__ __launch_bounds__(256) void gate_kernel(const __bf16* __restrict__ xnb,
    const float* __restrict__ gw, int* __restrict__ counts, float* __restrict__ sum_probs,
    int* __restrict__ tok_list, float* __restrict__ gate_list) {
  __shared__ float Gs[NEXP][DMODEL];
  __shared__ float simp[NEXP];
  __shared__ int hist[NEXP], basep[NEXP];
  __shared__ unsigned char tokE[32][2];
  __shared__ float tokG[32][2];
  __shared__ short rankS[32][2];
  int tid = threadIdx.x;
  for (int i = tid; i < DMODEL * NEXP; i += 256) {
    int d = i >> 3, e2 = i & 7;
    Gs[e2][d] = gw[i];
  }
  if (tid < NEXP) { simp[tid] = 0.f; hist[tid] = 0; }
  __syncthreads();
  int w = tid >> 6, lane = tid & 63;
  int tbase = blockIdx.x * 32 + w * 8;
  float impacc[NEXP] = {};
  for (int tt = 0; tt < 8; tt++) {
    int t = tbase + tt;
    float p[NEXP] = {};
#pragma unroll
    for (int j = 0; j < 6; j++) {
      int d = lane + 64 * j;
      float xv = (float)xnb[(size_t)t * DMODEL + d];
#pragma unroll
      for (int e2 = 0; e2 < NEXP; e2++) p[e2] += xv * Gs[e2][d];
    }
#pragma unroll
    for (int off = 32; off; off >>= 1)
#pragma unroll
      for (int e2 = 0; e2 < NEXP; e2++) p[e2] += __shfl_xor(p[e2], off);
    float mx = p[0];
#pragma unroll
    for (int e2 = 1; e2 < NEXP; e2++) mx = fmaxf(mx, p[e2]);
    float s = 0.f;
#pragma unroll
    for (int e2 = 0; e2 < NEXP; e2++) { p[e2] = __expf(p[e2] - mx); s += p[e2]; }
    float inv = 1.f / s;
#pragma unroll
    for (int e2 = 0; e2 < NEXP; e2++) { p[e2] *= inv; impacc[e2] += p[e2]; }
    int i0 = 0; float v0 = p[0];
#pragma unroll
    for (int e2 = 1; e2 < NEXP; e2++) if (p[e2] > v0) { v0 = p[e2]; i0 = e2; }
    int i1 = -1; float v1 = -INFINITY;
#pragma unroll
    for (int e2 = 0; e2 < NEXP; e2++) if (e2 != i0 && p[e2] > v1) { v1 = p[e2]; i1 = e2; }
    if (lane == 0) {
      float gsum = v0 + v1;
      int r0 = atomicAdd(&hist[i0], 1);
      int r1 = atomicAdd(&hist[i1], 1);
      int sl = w * 8 + tt;
      tokE[sl][0] = (unsigned char)i0; tokE[sl][1] = (unsigned char)i1;
      tokG[sl][0] = v0 / gsum;         tokG[sl][1] = v1 / gsum;
      rankS[sl][0] = (short)r0;        rankS[sl][1] = (short)r1;
    }
  }
  if (lane == 0)
#pragma unroll
    for (int e2 = 0; e2 < NEXP; e2++) atomicAdd(&simp[e2], impacc[e2]);
  __syncthreads();
  if (tid < NEXP) {
    basep[tid] = atomicAdd(&counts[tid], hist[tid]);
    atomicAdd(&sum_probs[tid], simp[tid]);
  }
  __syncthreads();
  int t0 = blockIdx.x * 32;
  if (tid < 64) {
    int sl = tid >> 1, a = tid & 1;
    int e2 = tokE[sl][a];
    int pos = basep[e2] + rankS[sl][a];
    tok_list[e2 * TOKENS + pos] = (t0 + sl) | (a << 16);
    gate_list[e2 * TOKENS + pos] = tokG[sl][a];
  }
}

// prefix offsets (64-padded) + aux loss contribution
__global__ void aux_kernel(const int* __restrict__ counts, int* __restrict__ offs,
                           const float* __restrict__ sum_probs, float* __restrict__ total_moe) {
  int off = 0;
  float tm = 0.f;
  for (int e = 0; e < NEXP; e++) {
    offs[e] = off;
    off += ((counts[e] + 63) >> 6) << 6;
    tm += sum_probs[e] * (float)counts[e];
  }
  offs[NEXP] = off;
  *total_moe += (float)NEXP * tm / ((float)TOKENS * (float)TOKENS);
}

// ---------------- attention-pool head, split for parallelism ----------------
// head1: logits (512 blocks x 32 rows)
__global__ __launch_bounds__(256) void head1_kernel(const float* __restrict__ h,
    const float* __restrict__ att_w, const float* __restrict__ att_b,
    float* __restrict__ logits) {
  int tid = threadIdx.x;
  int w = tid >> 6, lane = tid & 63;
  float4 aw0 = *(const float4*)&att_w[lane * 4];
  float2 aw1 = *(const float2*)&att_w[256 + lane * 2];
  float ab = att_b[0];
  for (int i = w; i < 32; i += 4) {
    int t = blockIdx.x * 32 + i;
    const float* hr = h + (size_t)t * DMODEL;
    float4 v4 = *(const float4*)&hr[lane * 4];
    float2 v2 = *(const float2*)&hr[256 + lane * 2];
    float dot = v4.x * aw0.x + v4.y * aw0.y + v4.z * aw0.z + v4.w * aw0.w
              + v2.x * aw1.x + v2.y * aw1.y;
#pragma unroll
    for (int off = 32; off; off >>= 1) dot += __shfl_xor(dot, off);
    if (lane == 0) logits[t] = dot + ab;
  }
}

__global__ __launch_bounds__(256) void head2_kernel(float* __restrict__ logits) {
  int b = blockIdx.x, tid = threadIdx.x;
  int w = tid >> 6, lane = tid & 63;
  float* lb = logits + b * SEQ;
  __shared__ float red[4];
  float lv[4];
  float mx = -INFINITY;
#pragma unroll
  for (int i = 0; i < 4; i++) { lv[i] = lb[tid + 256 * i]; mx = fmaxf(mx, lv[i]); }
#pragma unroll
  for (int off = 32; off; off >>= 1) mx = fmaxf(mx, __shfl_xor(mx, off));
  if (lane == 0) red[w] = mx;
  __syncthreads();
  mx = fmaxf(fmaxf(red[0], red[1]), fmaxf(red[2], red[3]));
  __syncthreads();
  float s = 0.f;
#pragma unroll
  for (int i = 0; i < 4; i++) { lv[i] = __expf(lv[i] - mx); s += lv[i]; }
#pragma unroll
  for (int off = 32; off; off >>= 1) s += __shfl_xor(s, off);
  if (lane == 0) red[w] = s;
  __syncthreads();
  float inv = 1.f / (red[0] + red[1] + red[2] + red[3]);
#pragma unroll
  for (int i = 0; i < 4; i++) lb[tid + 256 * i] = lv[i] * inv;
}

// head3a: block (b, dc, sc): 64-row x 64-col weighted partial sum
__global__ __launch_bounds__(256) void head3a_kernel(const float* __restrict__ h,
    const float* __restrict__ wnorm, float* __restrict__ partial) {
  int b = blockIdx.x, dc = blockIdx.y, sc = blockIdx.z;
  int tid = threadIdx.x;
  int d = tid & 63, sg = tid >> 6;             // 4 s-subgroups of 16
  const float* hb = h + (size_t)b * SEQ * DMODEL + dc * 64 + d;
  const float* wb = wnorm + b * SEQ + sc * 64;
  float acc = 0.f;
  int s0 = sc * 64 + sg * 16;
#pragma unroll
  for (int i = 0; i < 16; i++)
    acc += wb[sg * 16 + i] * hb[(size_t)(s0 + i) * DMODEL];
  __shared__ float red[256];
  red[tid] = acc;
  __syncthreads();
  if (sg == 0)
    partial[(((size_t)b * 6 + dc) * 16 + sc) * 64 + d] =
        red[d] + red[64 + d] + red[128 + d] + red[192 + d];
}

// head3b: reduce 16 partials + head_w dot -> part[b][dc]
__global__ void head3b_kernel(const float* __restrict__ partial,
    const float* __restrict__ head_w, float* __restrict__ part) {
  int b = blockIdx.x, dc = blockIdx.y;
  int d = threadIdx.x;                          // 64 threads
  const float* pp = partial + (((size_t)b * 6 + dc) * 16) * 64 + d;
  float pooled = 0.f;
#pragma unroll
  for (int sc = 0; sc < 16; sc++) pooled += pp[sc * 64];
  float pd = pooled * head_w[dc * 64 + d];
#pragma unroll
  for (int off = 32; off; off >>= 1) pd += __shfl_xor(pd, off);
  if (d == 0) part[b * 6 + dc] = pd;
}

__global__ void head4_kernel(const float* __restrict__ part,
                             const float* __restrict__ head_b, float* __restrict__ out) {
  int b = threadIdx.x;
  if (b < 16) {
    float s = head_b[0];
#pragma unroll
    for (int dc = 0; dc < 6; dc++) s += part[b * 6 + dc];
    out[b] = s;
  }
}

// ---------------- launch ----------------
extern "C" void kernel_launch(void* const* d_in, const int* in_sizes, int n_in,
                              void* d_out, int out_size, void* d_ws, size_t ws_size,
                              hipStream_t stream) {
  (void)in_sizes; (void)n_in; (void)out_size; (void)ws_size;
  const float* x      = (const float*)d_in[0];
  const float* proj_w = (const float*)d_in[1];
  const float* proj_b = (const float*)d_in[2];
  const float* qkv_w  = (const float*)d_in[3];
  const float* qkv_b  = (const float*)d_in[4];
  const float* out_w  = (const float*)d_in[5];
  const float* out_b  = (const float*)d_in[6];
  const float* n1_s   = (const float*)d_in[7];
  const float* n1_b   = (const float*)d_in[8];
  const float* n2_s   = (const float*)d_in[9];
  const float* n2_b   = (const float*)d_in[10];
  const float* gate_w = (const float*)d_in[11];
  const float* e_w1   = (const float*)d_in[12];
  const float* e_b1   = (const float*)d_in[13];
  const float* e_w2   = (const float*)d_in[14];
  const float* e_b2   = (const float*)d_in[15];
  const float* att_w  = (const float*)d_in[16];
  const float* att_b  = (const float*)d_in[17];
  const float* head_w = (const float*)d_in[18];
  const float* head_b = (const float*)d_in[19];
  float* out = (float*)d_out;

  // workspace layout (bytes):
  // h fp32 25.2MB | {xnb 12.6 | aob 12.6}MB (reused as ab[2][16384][384] during moe2)
  // | uni region 51.1MB: {Qh 12.6 | Kh 12.6 | VTh 12.6} during attn, a1b during MoE
  // | Wt bf16 31.9MB | control | logits | part | partial
  char* wsb = (char*)d_ws;
  float*  h    = (float*)(wsb);
  __bf16* xnb  = (__bf16*)(wsb + 25165824);
  __bf16* aob  = (__bf16*)(wsb + 37748736);
  __bf16* ab   = (__bf16*)(wsb + 25165824);        // [2][16384][384] aliases xnb+aob
  __bf16* uni  = (__bf16*)(wsb + 50331648);
  __bf16* Qh   = uni;                              // [128][1024][48] = 12,582,912 B
  __bf16* Khd  = (__bf16*)(wsb + 62914560);
  __bf16* VTh  = (__bf16*)(wsb + 75497472);
  __bf16* qkvWt = (__bf16*)(wsb + 101449728);   // [3][1152][384]
  __bf16* outWt = (__bf16*)(wsb + 104103936);   // [3][384][384]
  __bf16* e1Wt  = (__bf16*)(wsb + 104988672);   // [3*8][768][384]
  __bf16* e2Wt  = (__bf16*)(wsb + 119144448);   // [3*8][384][768]
  char* sm = wsb + 133300224;
  int*   counts    = (int*)(sm);
  int*   offs      = (int*)(sm + 64);
  float* sum_probs = (float*)(sm + 128);
  float* total_moe = (float*)(sm + 192);
  int*   tok_list  = (int*)(sm + 256);
  float* gate_list = (float*)(sm + 256 + 524288);
  float* logits    = (float*)(sm + 1048832);
  float* part      = (float*)(sm + 1048832 + 65536);
  float* partial   = (float*)(sm + 1048832 + 131072);   // [16][6][16][64] = 393 KB

  // one-shot weight transpose+cast (runs every call; deterministic)
  convw_kernel<<<dim3(36, 12, 3), 256, 0, stream>>>(qkv_w, qkvWt, 384, 1152);
  convw_kernel<<<dim3(12, 12, 3), 256, 0, stream>>>(out_w, outWt, 384, 384);
  convw_kernel<<<dim3(24, 12, 24), 256, 0, stream>>>(e_w1, e1Wt, 384, 768);
  convw_kernel<<<dim3(12, 24, 24), 256, 0, stream>>>(e_w2, e2Wt, 768, 384);

  init_kernel<<<1, 1, 0, stream>>>(total_moe);
  proj_kernel<<<TOKENS * DMODEL / 256, 256, 0, stream>>>(x, proj_w, proj_b, h);

  for (int l = 0; l < NL; l++) {
    ln_kernel<<<TOKENS, 384, 0, stream>>>(h, xnb, n1_s + l * DMODEL, n1_b + l * DMODEL);
    mgemm_kernel<0><<<dim3(9, 128), 256, 0, stream>>>(
        xnb, qkvWt + (size_t)l * 1152 * 384, qkv_b + l * 1152, nullptr, nullptr,
        Qh, Khd, VTh, nullptr, nullptr, nullptr, nullptr, 1152, 384);
    attn_kernel<<<dim3(128, 16), 256, 0, stream>>>(Qh, Khd, VTh, aob);
    mgemm_kernel<1><<<dim3(3, 128), 256, 0, stream>>>(
        aob, outWt + (size_t)l * 384 * 384, out_b + l * 384, h, nullptr,
        nullptr, nullptr, nullptr, nullptr, nullptr, nullptr, nullptr, 384, 384);
    ln_kernel<<<TOKENS, 384, 0, stream>>>(h, xnb, n2_s + l * DMODEL, n2_b + l * DMODEL);
    zero_cnt_kernel<<<1, 64, 0, stream>>>(counts, sum_probs);
    gate_kernel<<<512, 256, 0, stream>>>(xnb, gate_w + (size_t)l * DMODEL * NEXP,
                                         counts, sum_probs, tok_list, gate_list);
    aux_kernel<<<1, 1, 0, stream>>>(counts, offs, sum_probs, total_moe);
    mgemm_kernel<2><<<dim3(6, 128, 8), 256, 0, stream>>>(
        xnb, e1Wt + (size_t)l * 8 * 768 * 384, e_b1 + l * 8 * FFDIM, nullptr, uni,
        nullptr, nullptr, nullptr, counts, offs, tok_list, nullptr, 768, 384);
    mgemm_kernel<3><<<dim3(3, 128, 8), 256, 0, stream>>>(
        uni, e2Wt + (size_t)l * 8 * 384 * 768, e_b2 + l * 8 * DMODEL, nullptr, ab,
        nullptr, nullptr, nullptr, counts, offs, tok_list, gate_list, 384, 768);
    combine_kernel<<<TOKENS * DMODEL / (256 * 8), 256, 0, stream>>>(h, ab);
  }

  head1_kernel<<<512, 256, 0, stream>>>(h, att_w, att_b, logits);
  head2_kernel<<<16, 256, 0, stream>>>(logits);
  head3a_kernel<<<dim3(16, 6, 16), 256, 0, stream>>>(h, logits, partial);
  head3b_kernel<<<dim3(16, 6), 64, 0, stream>>>(partial, head_w, part);
  head4_kernel<<<1, 64, 0, stream>>>(part, head_b, out);
  finalize_kernel<<<1, 1, 0, stream>>>(total_moe, out);
}